// Round 11
// baseline (545.867 us; speedup 1.0000x reference)
//
#include <hip/hip_runtime.h>
#include <cstdint>

#define NN 50000
#define NE 512000

typedef unsigned short bf16u;
typedef __attribute__((ext_vector_type(8))) short short8v;
typedef __attribute__((ext_vector_type(4))) float f32x4;

__device__ __forceinline__ bf16u f2bf(float f){
  union { float f; unsigned int u; } v; v.f = f;
  unsigned int r = v.u + 0x7FFFu + ((v.u >> 16) & 1u);
  return (bf16u)(r >> 16);
}
__device__ __forceinline__ float bf2f(bf16u s){
  union { unsigned int u; float f; } v; v.u = ((unsigned int)s) << 16;
  return v.f;
}

// ---------- K0: weight packing into MFMA B-fragments ----------
// B-frag layout (mfma_f32_16x16x32_bf16): elem [((ks*NF+nf)*64+l)*8+j] =
//   W[n][k],  n = nf*16 + (l&15),  k = ks*32 + ((l>>4)<<3) + j
__global__ void k0_pack(const float* __restrict__ E_w, const float* __restrict__ conn1_w,
                        const float* __restrict__ conn2_w, const float* __restrict__ qkv_w,
                        const float* __restrict__ ffn1_w, const float* __restrict__ ffn2_w,
                        bf16u* __restrict__ BpE, bf16u* __restrict__ Bp1,
                        bf16u* __restrict__ Bp2, bf16u* __restrict__ BpQ,
                        bf16u* __restrict__ BpF1, bf16u* __restrict__ BpF2){
  int i = blockIdx.x * 256 + threadIdx.x;   // 0..12287
  int j = i & 7, l = (i >> 3) & 63;
  int nl = l & 15, kl = (l >> 4) << 3;
  if (i < 8192){   // E_w: (128,64), NF=8, KS=2
    int rest = i >> 9, nf = rest & 7, ks = rest >> 3;
    int n = nf * 16 + nl, k = ks * 32 + kl + j;
    BpE[i] = f2bf(E_w[n * 64 + k]);
  }
  if (i < 4096){   // conn1_w/conn2_w: (64,64), NF=4, KS=2
    int rest = i >> 9, nf = rest & 3, ks = rest >> 2;
    int n = nf * 16 + nl, k = ks * 32 + kl + j;
    Bp1[i] = f2bf(conn1_w[n * 64 + k]);
    Bp2[i] = f2bf(conn2_w[n * 64 + k]);
  }
  if (i < 12288){  // qkv_w: (192,64), NF=12, KS=2
    int rest = i >> 9, nf = rest % 12, ks = rest / 12;
    int n = nf * 16 + nl, k = ks * 32 + kl + j;
    BpQ[i] = f2bf(qkv_w[n * 64 + k]);
  }
  if (i < 8192){   // ffn1_w: (128,64), NF=8, KS=2
    int rest = i >> 9, nf = rest & 7, ks = rest >> 3;
    int n = nf * 16 + nl, k = ks * 32 + kl + j;
    BpF1[i] = f2bf(ffn1_w[n * 64 + k]);
  }
  if (i < 8192){   // ffn2_w: (64,128), NF=4, KS=4
    int rest = i >> 9, nf = rest & 3, ks = rest >> 2;
    int n = nf * 16 + nl, k = ks * 32 + kl + j;
    BpF2[i] = f2bf(ffn2_w[n * 128 + k]);
  }
}

// ---------- CSR build ----------
__global__ void k_hist(const int* __restrict__ dst, int* __restrict__ cnt){
  int e = blockIdx.x * 256 + threadIdx.x;
  if (e < NE) atomicAdd(&cnt[dst[e]], 1);
}

#define SCAN_T 1024
#define PER_T 49
__global__ __launch_bounds__(SCAN_T) void k_scan(const int* __restrict__ cnt,
                                                 int* __restrict__ start, int* __restrict__ cursor){
  __shared__ int ls[SCAN_T];
  int t = threadIdx.x;
  int base = t * PER_T;
  int s = 0;
  for (int i = 0; i < PER_T; ++i){ int n = base + i; if (n < NN) s += cnt[n]; }
  ls[t] = s; __syncthreads();
  for (int off = 1; off < SCAN_T; off <<= 1){
    int v = ls[t];
    int add = (t >= off) ? ls[t - off] : 0;
    __syncthreads();
    ls[t] = v + add;
    __syncthreads();
  }
  int run = (t > 0) ? ls[t - 1] : 0;
  for (int i = 0; i < PER_T; ++i){
    int n = base + i;
    if (n < NN){ start[n] = run; cursor[n] = run; run += cnt[n]; }
  }
  if (t == SCAN_T - 1) start[NN] = run;
}

__global__ void k_scatter(const int* __restrict__ dst, const int* __restrict__ src,
                          int* __restrict__ cursor, int* __restrict__ eidx,
                          int* __restrict__ nid, int* __restrict__ sid){
  int e = blockIdx.x * 256 + threadIdx.x;
  if (e < NE){
    int dn = dst[e];
    int p = atomicAdd(&cursor[dn], 1);
    eidx[p] = e;
    nid[p] = dn;
    sid[p] = src[e];
  }
}

// ---------- K1: node QKV — MFMA, split-bf16 A ----------
__global__ __launch_bounds__(256) void k1_qkv(const float* __restrict__ x,
    const bf16u* __restrict__ BpQ, const float* __restrict__ qkv_b,
    float* __restrict__ Q, float* __restrict__ K, float* __restrict__ V){
  int tile = blockIdx.x * 64;
  int w = threadIdx.x >> 6, l = threadIdx.x & 63;
  int lg = l >> 4, li = l & 15;
  const short8v* bpq = (const short8v*)BpQ;
  short8v Bq[3][2];
#pragma unroll
  for (int p = 0; p < 3; ++p)
#pragma unroll
    for (int ks = 0; ks < 2; ++ks)
      Bq[p][ks] = bpq[(ks * 12 + p * 4 + w) * 64 + l];
  f32x4 z = {0.f, 0.f, 0.f, 0.f};
  f32x4 acc[3][4];
#pragma unroll
  for (int p = 0; p < 3; ++p)
#pragma unroll
    for (int mf = 0; mf < 4; ++mf) acc[p][mf] = z;
#pragma unroll
  for (int mf = 0; mf < 4; ++mf){
    int row = tile + mf * 16 + li;
    bool g = row < NN;
    const float* xp = x + (size_t)row * 64 + lg * 8;
#pragma unroll
    for (int ks = 0; ks < 2; ++ks){
      float v[8];
      if (g){
        float4 t0 = *(const float4*)(xp + ks * 32);
        float4 t1 = *(const float4*)(xp + ks * 32 + 4);
        v[0]=t0.x; v[1]=t0.y; v[2]=t0.z; v[3]=t0.w;
        v[4]=t1.x; v[5]=t1.y; v[6]=t1.z; v[7]=t1.w;
      } else {
#pragma unroll
        for (int j = 0; j < 8; ++j) v[j] = 0.f;
      }
      short8v hi, lo;
#pragma unroll
      for (int j = 0; j < 8; ++j){
        bf16u h = f2bf(v[j]);
        hi[j] = (short)h;
        lo[j] = (short)f2bf(v[j] - bf2f(h));
      }
#pragma unroll
      for (int p = 0; p < 3; ++p){
        acc[p][mf] = __builtin_amdgcn_mfma_f32_16x16x32_bf16(hi, Bq[p][ks], acc[p][mf], 0, 0, 0);
        acc[p][mf] = __builtin_amdgcn_mfma_f32_16x16x32_bf16(lo, Bq[p][ks], acc[p][mf], 0, 0, 0);
      }
    }
  }
  float bias[3] = {qkv_b[w*16+li], qkv_b[64+w*16+li], qkv_b[128+w*16+li]};
  float* outs[3] = {Q, K, V};
#pragma unroll
  for (int p = 0; p < 3; ++p)
#pragma unroll
    for (int mf = 0; mf < 4; ++mf)
#pragma unroll
      for (int r = 0; r < 4; ++r){
        int row = tile + mf * 16 + lg * 4 + r;
        if (row < NN) outs[p][(size_t)row * 64 + w * 16 + li] = acc[p][mf][r] + bias[p];
      }
}

// ---------- K2: fused edge kernel — overlay LDS, racc in regs ----------
// LDS plan: [0,9216)=cpre  [9216,18432)=cmid  (phases A..D)
//           [0,17408)=rbuf f32 (phases D1..D2 only, after cpre/cmid dead)
__global__ __launch_bounds__(256, 6) void k2_edge(
    const float* __restrict__ e, const int* __restrict__ eidx,
    const int* __restrict__ nid, const int* __restrict__ sid,
    const bf16u* __restrict__ BpE, const float* __restrict__ E_b,
    const float* __restrict__ Aw, const bf16u* __restrict__ Bp1, const float* __restrict__ conn1_b,
    const float* __restrict__ Q, const float* __restrict__ K,
    const float* __restrict__ g1c, const float* __restrict__ b1c,
    const bf16u* __restrict__ Bp2, const float* __restrict__ conn2_b,
    const float* __restrict__ g2c, const float* __restrict__ b2c,
    bf16u* __restrict__ cm, float* __restrict__ sexp, float* __restrict__ out_conn){
  __shared__ __align__(16) char shmem[18432];
  __shared__ float mu1[64], rs1[64], mu2[64], rs2[64];
  bf16u* cpre = (bf16u*)shmem;            // [64*72] bf16
  bf16u* cmid = (bf16u*)(shmem + 9216);   // [64*72] bf16
  float* rbuf = (float*)shmem;            // [64*68] f32, overlays cpre+cmid
  int tile = blockIdx.x * 64;
  int t = threadIdx.x;
  int w = t >> 6, l = t & 63;
  int lg = l >> 4, li = l & 15;
  int dloc = w * 16 + li;

  float eb0 = E_b[dloc], eb1 = E_b[64 + dloc];
  float awv = Aw[li * 4 + w];
  f32x4 z = {0.f, 0.f, 0.f, 0.f};

  // --- phase A: per-mf Eh MFMA + pointwise ---
  {
    const short8v* bpe = (const short8v*)BpE;
    short8v BW0 = bpe[(0*8 + w)     * 64 + l];
    short8v BW1 = bpe[(1*8 + w)     * 64 + l];
    short8v BB0 = bpe[(0*8 + 4 + w) * 64 + l];
    short8v BB1 = bpe[(1*8 + 4 + w) * 64 + l];
#pragma unroll
    for (int mf = 0; mf < 4; ++mf){
      int eidA = eidx[tile + mf * 16 + li];
      const float* ep = e + (size_t)eidA * 64 + lg * 8;
      f32x4 accW = z, accB = z;
#pragma unroll
      for (int ks = 0; ks < 2; ++ks){
        float4 a0 = *(const float4*)(ep + ks * 32);
        float4 a1 = *(const float4*)(ep + ks * 32 + 4);
        short8v af;
        af[0]=(short)f2bf(a0.x); af[1]=(short)f2bf(a0.y); af[2]=(short)f2bf(a0.z); af[3]=(short)f2bf(a0.w);
        af[4]=(short)f2bf(a1.x); af[5]=(short)f2bf(a1.y); af[6]=(short)f2bf(a1.z); af[7]=(short)f2bf(a1.w);
        accW = __builtin_amdgcn_mfma_f32_16x16x32_bf16(af, ks ? BW1 : BW0, accW, 0, 0, 0);
        accB = __builtin_amdgcn_mfma_f32_16x16x32_bf16(af, ks ? BB1 : BB0, accB, 0, 0, 0);
      }
#pragma unroll
      for (int r = 0; r < 4; ++r){
        int el = mf * 16 + lg * 4 + r;
        int pos = tile + el;
        int dn = nid[pos], sn = sid[pos];
        float qv = Q[(size_t)dn * 64 + dloc];
        float kv = K[(size_t)sn * 64 + dloc];
        float ew  = accW[r] + eb0;
        float ebv = accB[r] + eb1;
        float c1 = (qv + kv) * ew;
        float c2 = copysignf(sqrtf(fabsf(c1)), c1);
        float cpv = fmaxf(c2 + ebv, 0.f);
        float s = cpv * awv;
        s += __shfl_xor(s, 1); s += __shfl_xor(s, 2);
        s += __shfl_xor(s, 4); s += __shfl_xor(s, 8);
        if (li == 0){
          float sc = fminf(fmaxf(s, -5.f), 5.f);
          sexp[(size_t)pos * 4 + w] = __expf(sc);
        }
        cpre[el * 72 + dloc] = f2bf(cpv);
      }
    }
  }
  __syncthreads();

  // --- phase B: conn1 MFMA; store cm global + cmid LDS ---
  {
    float c1b = conn1_b[dloc];
    const short8v* bp1 = (const short8v*)Bp1;
    short8v B10 = bp1[(0*4 + w) * 64 + l];
    short8v B11 = bp1[(1*4 + w) * 64 + l];
#pragma unroll
    for (int mf = 0; mf < 4; ++mf){
      const bf16u* ap = &cpre[(mf * 16 + li) * 72 + lg * 8];
      short8v a0 = *(const short8v*)(ap);
      short8v a1 = *(const short8v*)(ap + 32);
      f32x4 acc = z;
      acc = __builtin_amdgcn_mfma_f32_16x16x32_bf16(a0, B10, acc, 0, 0, 0);
      acc = __builtin_amdgcn_mfma_f32_16x16x32_bf16(a1, B11, acc, 0, 0, 0);
#pragma unroll
      for (int r = 0; r < 4; ++r){
        int el = mf * 16 + lg * 4 + r;
        bf16u vb = f2bf(acc[r] + c1b);
        cm[(size_t)(tile + el) * 64 + dloc] = vb;
        cmid[el * 72 + dloc] = vb;
      }
    }
  }
  __syncthreads();

  // --- phase B2: LN1c stats from cmid, thread = (row, quarter) ---
  {
    int el = t >> 2, q = t & 3;
    const short8v* cp8 = (const short8v*)&cmid[el * 72 + q * 16];
    short8v c0 = cp8[0], c1 = cp8[1];
    float s = 0.f, sq = 0.f;
#pragma unroll
    for (int i = 0; i < 8; ++i){
      float v0 = bf2f((bf16u)c0[i]), v1 = bf2f((bf16u)c1[i]);
      s += v0 + v1; sq += v0*v0 + v1*v1;
    }
    s  += __shfl_xor(s, 1);  s  += __shfl_xor(s, 2);
    sq += __shfl_xor(sq, 1); sq += __shfl_xor(sq, 2);
    if (q == 0){
      float mu = s * (1.f/64.f);
      float var = sq * (1.f/64.f) - mu * mu;
      mu1[el] = mu;
      rs1[el] = rsqrtf(fmaxf(var, 0.f) + 1e-5f);
    }
  }
  __syncthreads();

  // --- phase C: LN1c normalize + relu -> cpre (overwrite) ---
  {
    float g1v = g1c[dloc], b1v = b1c[dloc];
#pragma unroll
    for (int mf = 0; mf < 4; ++mf){
#pragma unroll
      for (int r = 0; r < 4; ++r){
        int el = mf * 16 + lg * 4 + r;
        float cv = bf2f(cmid[el * 72 + dloc]);
        float cn = fmaxf((cv - mu1[el]) * rs1[el] * g1v + b1v, 0.f);
        cpre[el * 72 + dloc] = f2bf(cn);
      }
    }
  }
  __syncthreads();

  // --- phase D: conn2 MFMA + residual -> racc (registers only) ---
  float racc[4][4];
  {
    float c2b = conn2_b[dloc];
    const short8v* bp2 = (const short8v*)Bp2;
    short8v B20 = bp2[(0*4 + w) * 64 + l];
    short8v B21 = bp2[(1*4 + w) * 64 + l];
#pragma unroll
    for (int mf = 0; mf < 4; ++mf){
      const bf16u* ap = &cpre[(mf * 16 + li) * 72 + lg * 8];
      short8v a0 = *(const short8v*)(ap);
      short8v a1 = *(const short8v*)(ap + 32);
      f32x4 acc = z;
      acc = __builtin_amdgcn_mfma_f32_16x16x32_bf16(a0, B20, acc, 0, 0, 0);
      acc = __builtin_amdgcn_mfma_f32_16x16x32_bf16(a1, B21, acc, 0, 0, 0);
#pragma unroll
      for (int r = 0; r < 4; ++r){
        int el = mf * 16 + lg * 4 + r;
        int eid = eidx[tile + el];
        racc[mf][r] = acc[r] + c2b + e[(size_t)eid * 64 + dloc];
      }
    }
  }
  __syncthreads();   // all cpre/cmid use done; rbuf may now overlay

  // --- phase D1: spill racc to rbuf (f32 overlay) for stats ---
#pragma unroll
  for (int mf = 0; mf < 4; ++mf){
#pragma unroll
    for (int r = 0; r < 4; ++r){
      int el = mf * 16 + lg * 4 + r;
      rbuf[el * 68 + dloc] = racc[mf][r];
    }
  }
  __syncthreads();

  // --- phase D2: LN2c stats from rbuf ---
  {
    int el = t >> 2, q = t & 3;
    const float4* rp = (const float4*)&rbuf[el * 68 + q * 16];
    float s = 0.f, sq = 0.f;
#pragma unroll
    for (int c = 0; c < 4; ++c){
      float4 v = rp[c];
      s  += v.x + v.y + v.z + v.w;
      sq += v.x*v.x + v.y*v.y + v.z*v.z + v.w*v.w;
    }
    s  += __shfl_xor(s, 1);  s  += __shfl_xor(s, 2);
    sq += __shfl_xor(sq, 1); sq += __shfl_xor(sq, 2);
    if (q == 0){
      float mu = s * (1.f/64.f);
      float var = sq * (1.f/64.f) - mu * mu;
      mu2[el] = mu;
      rs2[el] = rsqrtf(fmaxf(var, 0.f) + 1e-5f);
    }
  }
  __syncthreads();

  // --- phase E: LN2c from racc (regs) + scatter store by eid ---
  {
    float g2v = g2c[dloc], b2v = b2c[dloc];
#pragma unroll
    for (int mf = 0; mf < 4; ++mf){
#pragma unroll
      for (int r = 0; r < 4; ++r){
        int el = mf * 16 + lg * 4 + r;
        int eid = eidx[tile + el];
        out_conn[(size_t)eid * 64 + dloc] = (racc[mf][r] - mu2[el]) * rs2[el] * g2v + b2v;
      }
    }
  }
}

// ---------- K_agg: wave per node; cm/sexp sequential, V gathered ----------
__global__ __launch_bounds__(256) void k_agg(
    const int* __restrict__ start, const int* __restrict__ sid,
    const float* __restrict__ sexp, const bf16u* __restrict__ cm, const float* __restrict__ V,
    const float* __restrict__ x, float* __restrict__ hpre){
  int wid = (blockIdx.x * 256 + threadIdx.x) >> 6;
  int lane = threadIdx.x & 63;
  if (wid >= NN) return;
  int s0 = start[wid], s1 = start[wid + 1];
  int h = lane >> 4;
  float num = 0.f, den = 0.f;
  for (int i = s0; i < s1; ++i){
    float sx = sexp[(size_t)i * 4 + h];
    int sn = sid[i];
    float v  = V[(size_t)sn * 64 + lane];
    float cc = bf2f(cm[(size_t)i * 64 + lane]);
    num += sx * (v + cc);
    den += sx;
  }
  hpre[(size_t)wid * 64 + lane] = x[(size_t)wid * 64 + lane] + num / (den + 1e-16f);
}

// ---------- K5: node final — LN1h + FFN (MFMA) + LN2h ----------
__global__ __launch_bounds__(256) void k5_node(
    const float* __restrict__ hpre,
    const float* __restrict__ g1, const float* __restrict__ b1,
    const bf16u* __restrict__ BpF1, const float* __restrict__ ffn1_b,
    const bf16u* __restrict__ BpF2, const float* __restrict__ ffn2_b,
    const float* __restrict__ g2, const float* __restrict__ b2,
    float* __restrict__ out_h){
  __shared__ bf16u hlhi[64 * 72];
  __shared__ bf16u hllo[64 * 72];
  __shared__ bf16u g1o[64 * 136];
  __shared__ float reds[64][4];
  __shared__ float redq[64][4];
  int tile = blockIdx.x * 64;
  int t = threadIdx.x;
  {
    int el = t >> 2, q = t & 3;
    int row = tile + el;
    bool g = row < NN;
    float v[16];
    if (g){
      const float4* hp = (const float4*)(hpre + (size_t)row * 64 + q * 16);
#pragma unroll
      for (int c = 0; c < 4; ++c){
        float4 tv = hp[c];
        v[c*4+0]=tv.x; v[c*4+1]=tv.y; v[c*4+2]=tv.z; v[c*4+3]=tv.w;
      }
    } else {
#pragma unroll
      for (int i = 0; i < 16; ++i) v[i] = 0.f;
    }
    float s = 0.f, sq = 0.f;
#pragma unroll
    for (int i = 0; i < 16; ++i){ s += v[i]; sq += v[i]*v[i]; }
    s  += __shfl_xor(s, 1);  s  += __shfl_xor(s, 2);
    sq += __shfl_xor(sq, 1); sq += __shfl_xor(sq, 2);
    float mu = s * (1.f/64.f);
    float var = sq * (1.f/64.f) - mu * mu;
    float rs = rsqrtf(fmaxf(var, 0.f) + 1e-5f);
#pragma unroll
    for (int i = 0; i < 16; ++i){
      int d = q * 16 + i;
      float hv = (v[i] - mu) * rs * g1[d] + b1[d];
      bf16u hb = f2bf(hv);
      hlhi[el * 72 + d] = hb;
      hllo[el * 72 + d] = f2bf(hv - bf2f(hb));
    }
  }
  __syncthreads();
  int w = t >> 6, l = t & 63;
  int lg = l >> 4, li = l & 15;
  const short8v* bpf1 = (const short8v*)BpF1;
  short8v B1f[2][2];
#pragma unroll
  for (int f = 0; f < 2; ++f)
#pragma unroll
    for (int ks = 0; ks < 2; ++ks)
      B1f[f][ks] = bpf1[(ks * 8 + f * 4 + w) * 64 + l];
  f32x4 z = {0.f, 0.f, 0.f, 0.f};
  f32x4 acc1[2][4];
#pragma unroll
  for (int f = 0; f < 2; ++f)
#pragma unroll
    for (int mf = 0; mf < 4; ++mf) acc1[f][mf] = z;
#pragma unroll
  for (int mf = 0; mf < 4; ++mf){
#pragma unroll
    for (int ks = 0; ks < 2; ++ks){
      const bf16u* ah = &hlhi[(mf * 16 + li) * 72 + ks * 32 + lg * 8];
      const bf16u* al = &hllo[(mf * 16 + li) * 72 + ks * 32 + lg * 8];
      short8v Ahi = *(const short8v*)ah;
      short8v Alo = *(const short8v*)al;
#pragma unroll
      for (int f = 0; f < 2; ++f){
        acc1[f][mf] = __builtin_amdgcn_mfma_f32_16x16x32_bf16(Ahi, B1f[f][ks], acc1[f][mf], 0, 0, 0);
        acc1[f][mf] = __builtin_amdgcn_mfma_f32_16x16x32_bf16(Alo, B1f[f][ks], acc1[f][mf], 0, 0, 0);
      }
    }
  }
  float fb[2] = {ffn1_b[w*16+li], ffn1_b[64+w*16+li]};
#pragma unroll
  for (int f = 0; f < 2; ++f)
#pragma unroll
    for (int mf = 0; mf < 4; ++mf)
#pragma unroll
      for (int r = 0; r < 4; ++r){
        int rowl = mf * 16 + lg * 4 + r;
        int col = f * 64 + w * 16 + li;
        g1o[rowl * 136 + col] = f2bf(fmaxf(acc1[f][mf][r] + fb[f], 0.f));
      }
  __syncthreads();
  const short8v* bpf2 = (const short8v*)BpF2;
  short8v B2f[4];
#pragma unroll
  for (int ks = 0; ks < 4; ++ks) B2f[ks] = bpf2[(ks * 4 + w) * 64 + l];
  int o = w * 16 + li;
  float f2b_ = ffn2_b[o];
  float racc[4][4];
#pragma unroll
  for (int mf = 0; mf < 4; ++mf){
    f32x4 acc = z;
#pragma unroll
    for (int ks = 0; ks < 4; ++ks){
      short8v A2 = *(const short8v*)&g1o[(mf * 16 + li) * 136 + ks * 32 + lg * 8];
      acc = __builtin_amdgcn_mfma_f32_16x16x32_bf16(A2, B2f[ks], acc, 0, 0, 0);
    }
#pragma unroll
    for (int r = 0; r < 4; ++r){
      int rowl = mf * 16 + lg * 4 + r;
      int row = tile + rowl;
      float hres = (row < NN) ? hpre[(size_t)row * 64 + o] : 0.f;
      float rv = acc[r] + f2b_ + hres;
      racc[mf][r] = rv;
      float s = rv, q2 = rv * rv;
      s  += __shfl_xor(s, 1);  s  += __shfl_xor(s, 2);  s  += __shfl_xor(s, 4);  s  += __shfl_xor(s, 8);
      q2 += __shfl_xor(q2, 1); q2 += __shfl_xor(q2, 2); q2 += __shfl_xor(q2, 4); q2 += __shfl_xor(q2, 8);
      if (li == 0){ reds[rowl][w] = s; redq[rowl][w] = q2; }
    }
  }
  __syncthreads();
  float g2v = g2[o], b2v = b2[o];
#pragma unroll
  for (int mf = 0; mf < 4; ++mf){
#pragma unroll
    for (int r = 0; r < 4; ++r){
      int rowl = mf * 16 + lg * 4 + r;
      int row = tile + rowl;
      if (row < NN){
        float S  = reds[rowl][0] + reds[rowl][1] + reds[rowl][2] + reds[rowl][3];
        float Qq = redq[rowl][0] + redq[rowl][1] + redq[rowl][2] + redq[rowl][3];
        float mu2 = S * (1.f/64.f);
        float var2 = Qq * (1.f/64.f) - mu2 * mu2;
        float rs2 = rsqrtf(fmaxf(var2, 0.f) + 1e-5f);
        out_h[(size_t)row * 64 + o] = (racc[mf][r] - mu2) * rs2 * g2v + b2v;
      }
    }
  }
}

extern "C" void kernel_launch(void* const* d_in, const int* in_sizes, int n_in,
                              void* d_out, int out_size, void* d_ws, size_t ws_size,
                              hipStream_t stream){
  const float* x       = (const float*)d_in[0];
  const float* e       = (const float*)d_in[1];
  const int*   dst     = (const int*)d_in[2];
  const int*   src     = (const int*)d_in[3];
  const float* qkv_w   = (const float*)d_in[4];
  const float* qkv_b   = (const float*)d_in[5];
  const float* E_w     = (const float*)d_in[6];
  const float* E_b     = (const float*)d_in[7];
  const float* Aw      = (const float*)d_in[8];
  const float* conn1_w = (const float*)d_in[9];
  const float* conn1_b = (const float*)d_in[10];
  const float* conn2_w = (const float*)d_in[11];
  const float* conn2_b = (const float*)d_in[12];
  const float* ffn1_w  = (const float*)d_in[13];
  const float* ffn1_b  = (const float*)d_in[14];
  const float* ffn2_w  = (const float*)d_in[15];
  const float* ffn2_b  = (const float*)d_in[16];
  const float* ln1h_g  = (const float*)d_in[17];
  const float* ln1h_b  = (const float*)d_in[18];
  const float* ln2h_g  = (const float*)d_in[19];
  const float* ln2h_b  = (const float*)d_in[20];
  const float* ln1c_g  = (const float*)d_in[21];
  const float* ln1c_b  = (const float*)d_in[22];
  const float* ln2c_g  = (const float*)d_in[23];
  const float* ln2c_b  = (const float*)d_in[24];

  char* ws = (char*)d_ws;
  size_t off = 0;
  auto alloc = [&](size_t bytes) -> void* {
    void* p = ws + off;
    off += (bytes + 255) & ~(size_t)255;
    return p;
  };
  float* Q     = (float*)alloc((size_t)NN * 64 * 4);
  float* Kq    = (float*)alloc((size_t)NN * 64 * 4);
  float* V     = (float*)alloc((size_t)NN * 64 * 4);
  bf16u* cmb   = (bf16u*)alloc((size_t)NE * 64 * 2);
  float* sexp  = (float*)alloc((size_t)NE * 4 * 4);
  float* hpre  = (float*)alloc((size_t)NN * 64 * 4);
  bf16u* BpE   = (bf16u*)alloc(8192 * 2);
  bf16u* Bp1   = (bf16u*)alloc(4096 * 2);
  bf16u* Bp2   = (bf16u*)alloc(4096 * 2);
  bf16u* BpQ   = (bf16u*)alloc(12288 * 2);
  bf16u* BpF1  = (bf16u*)alloc(8192 * 2);
  bf16u* BpF2  = (bf16u*)alloc(8192 * 2);
  int*   cnt   = (int*)alloc((size_t)NN * 4);
  int*   startp= (int*)alloc(((size_t)NN + 1) * 4);
  int*   cursor= (int*)alloc((size_t)NN * 4);
  int*   eidx  = (int*)alloc((size_t)NE * 4);
  int*   nid   = (int*)alloc((size_t)NE * 4);
  int*   sid   = (int*)alloc((size_t)NE * 4);

  float* out_h    = (float*)d_out;
  float* out_conn = out_h + (size_t)NN * 64;

  hipMemsetAsync(cnt, 0, (size_t)NN * 4, stream);

  k0_pack<<<48, 256, 0, stream>>>(E_w, conn1_w, conn2_w, qkv_w, ffn1_w, ffn2_w,
                                  BpE, Bp1, Bp2, BpQ, BpF1, BpF2);
  k_hist<<<NE / 256, 256, 0, stream>>>(dst, cnt);
  k_scan<<<1, SCAN_T, 0, stream>>>(cnt, startp, cursor);
  k_scatter<<<NE / 256, 256, 0, stream>>>(dst, src, cursor, eidx, nid, sid);
  k1_qkv<<<(NN + 63) / 64, 256, 0, stream>>>(x, BpQ, qkv_b, Q, Kq, V);
  k2_edge<<<NE / 64, 256, 0, stream>>>(e, eidx, nid, sid, BpE, E_b, Aw, Bp1, conn1_b,
                                       Q, Kq, ln1c_g, ln1c_b, Bp2, conn2_b,
                                       ln2c_g, ln2c_b, cmb, sexp, out_conn);
  k_agg<<<(NN * 64 + 255) / 256, 256, 0, stream>>>(startp, sid, sexp, cmb, V, x, hpre);
  k5_node<<<(NN + 63) / 64, 256, 0, stream>>>(hpre, ln1h_g, ln1h_b, BpF1, ffn1_b,
                                              BpF2, ffn2_b, ln2h_g, ln2h_b, out_h);
}

// Round 12
// 524.932 us; speedup vs baseline: 1.0399x; 1.0399x over previous
//
#include <hip/hip_runtime.h>
#include <cstdint>

#define NN 50000
#define NE 512000

typedef unsigned short bf16u;
typedef __attribute__((ext_vector_type(8))) short short8v;
typedef __attribute__((ext_vector_type(4))) float f32x4;

__device__ __forceinline__ bf16u f2bf(float f){
  union { float f; unsigned int u; } v; v.f = f;
  unsigned int r = v.u + 0x7FFFu + ((v.u >> 16) & 1u);
  return (bf16u)(r >> 16);
}
__device__ __forceinline__ float bf2f(bf16u s){
  union { unsigned int u; float f; } v; v.u = ((unsigned int)s) << 16;
  return v.f;
}

// ---------- K0: weight packing into MFMA B-fragments ----------
// B-frag layout (mfma_f32_16x16x32_bf16): elem [((ks*NF+nf)*64+l)*8+j] =
//   W[n][k],  n = nf*16 + (l&15),  k = ks*32 + ((l>>4)<<3) + j
__global__ void k0_pack(const float* __restrict__ E_w, const float* __restrict__ conn1_w,
                        const float* __restrict__ conn2_w, const float* __restrict__ qkv_w,
                        const float* __restrict__ ffn1_w, const float* __restrict__ ffn2_w,
                        bf16u* __restrict__ BpE, bf16u* __restrict__ Bp1,
                        bf16u* __restrict__ Bp2, bf16u* __restrict__ BpQ,
                        bf16u* __restrict__ BpF1, bf16u* __restrict__ BpF2){
  int i = blockIdx.x * 256 + threadIdx.x;   // 0..12287
  int j = i & 7, l = (i >> 3) & 63;
  int nl = l & 15, kl = (l >> 4) << 3;
  if (i < 8192){   // E_w: (128,64), NF=8, KS=2
    int rest = i >> 9, nf = rest & 7, ks = rest >> 3;
    int n = nf * 16 + nl, k = ks * 32 + kl + j;
    BpE[i] = f2bf(E_w[n * 64 + k]);
  }
  if (i < 4096){   // conn1_w/conn2_w: (64,64), NF=4, KS=2
    int rest = i >> 9, nf = rest & 3, ks = rest >> 2;
    int n = nf * 16 + nl, k = ks * 32 + kl + j;
    Bp1[i] = f2bf(conn1_w[n * 64 + k]);
    Bp2[i] = f2bf(conn2_w[n * 64 + k]);
  }
  if (i < 12288){  // qkv_w: (192,64), NF=12, KS=2
    int rest = i >> 9, nf = rest % 12, ks = rest / 12;
    int n = nf * 16 + nl, k = ks * 32 + kl + j;
    BpQ[i] = f2bf(qkv_w[n * 64 + k]);
  }
  if (i < 8192){   // ffn1_w: (128,64), NF=8, KS=2
    int rest = i >> 9, nf = rest & 7, ks = rest >> 3;
    int n = nf * 16 + nl, k = ks * 32 + kl + j;
    BpF1[i] = f2bf(ffn1_w[n * 64 + k]);
  }
  if (i < 8192){   // ffn2_w: (64,128), NF=4, KS=4
    int rest = i >> 9, nf = rest & 3, ks = rest >> 2;
    int n = nf * 16 + nl, k = ks * 32 + kl + j;
    BpF2[i] = f2bf(ffn2_w[n * 128 + k]);
  }
}

// ---------- CSR build ----------
__global__ void k_hist(const int* __restrict__ dst, int* __restrict__ cnt){
  int e = blockIdx.x * 256 + threadIdx.x;
  if (e < NE) atomicAdd(&cnt[dst[e]], 1);
}

#define SCAN_T 1024
#define PER_T 52   // 1024*52 >= NN; 52*4B = 208B, 16B-aligned -> int4 loads
__global__ __launch_bounds__(SCAN_T) void k_scan(const int* __restrict__ cnt,
                                                 int* __restrict__ start, int* __restrict__ cursor){
  __shared__ int ls[SCAN_T];
  int t = threadIdx.x;
  int base = t * PER_T;
  int s = 0;
  const int4* cp = (const int4*)(cnt + base);
#pragma unroll
  for (int c = 0; c < 13; ++c){
    int4 v = cp[c];
    int n0 = base + c * 4;
    s += (n0 + 0 < NN ? v.x : 0) + (n0 + 1 < NN ? v.y : 0)
       + (n0 + 2 < NN ? v.z : 0) + (n0 + 3 < NN ? v.w : 0);
  }
  ls[t] = s; __syncthreads();
  for (int off = 1; off < SCAN_T; off <<= 1){
    int v = ls[t];
    int add = (t >= off) ? ls[t - off] : 0;
    __syncthreads();
    ls[t] = v + add;
    __syncthreads();
  }
  int run = (t > 0) ? ls[t - 1] : 0;
  for (int i = 0; i < PER_T; ++i){
    int n = base + i;
    if (n < NN){ start[n] = run; cursor[n] = run; run += cnt[n]; }
  }
  if (t == SCAN_T - 1) start[NN] = run;
}

__global__ void k_scatter(const int* __restrict__ dst, const int* __restrict__ src,
                          int* __restrict__ cursor, int* __restrict__ eidx,
                          int* __restrict__ nid, int* __restrict__ sid){
  int e = blockIdx.x * 256 + threadIdx.x;
  if (e < NE){
    int dn = dst[e];
    int p = atomicAdd(&cursor[dn], 1);
    eidx[p] = e;
    nid[p] = dn;
    sid[p] = src[e];
  }
}

// ---------- K1: node QKV — MFMA, split-bf16 A ----------
__global__ __launch_bounds__(256) void k1_qkv(const float* __restrict__ x,
    const bf16u* __restrict__ BpQ, const float* __restrict__ qkv_b,
    float* __restrict__ Q, float* __restrict__ K, float* __restrict__ V){
  int tile = blockIdx.x * 64;
  int w = threadIdx.x >> 6, l = threadIdx.x & 63;
  int lg = l >> 4, li = l & 15;
  const short8v* bpq = (const short8v*)BpQ;
  short8v Bq[3][2];
#pragma unroll
  for (int p = 0; p < 3; ++p)
#pragma unroll
    for (int ks = 0; ks < 2; ++ks)
      Bq[p][ks] = bpq[(ks * 12 + p * 4 + w) * 64 + l];
  f32x4 z = {0.f, 0.f, 0.f, 0.f};
  f32x4 acc[3][4];
#pragma unroll
  for (int p = 0; p < 3; ++p)
#pragma unroll
    for (int mf = 0; mf < 4; ++mf) acc[p][mf] = z;
#pragma unroll
  for (int mf = 0; mf < 4; ++mf){
    int row = tile + mf * 16 + li;
    bool g = row < NN;
    const float* xp = x + (size_t)row * 64 + lg * 8;
#pragma unroll
    for (int ks = 0; ks < 2; ++ks){
      float v[8];
      if (g){
        float4 t0 = *(const float4*)(xp + ks * 32);
        float4 t1 = *(const float4*)(xp + ks * 32 + 4);
        v[0]=t0.x; v[1]=t0.y; v[2]=t0.z; v[3]=t0.w;
        v[4]=t1.x; v[5]=t1.y; v[6]=t1.z; v[7]=t1.w;
      } else {
#pragma unroll
        for (int j = 0; j < 8; ++j) v[j] = 0.f;
      }
      short8v hi, lo;
#pragma unroll
      for (int j = 0; j < 8; ++j){
        bf16u h = f2bf(v[j]);
        hi[j] = (short)h;
        lo[j] = (short)f2bf(v[j] - bf2f(h));
      }
#pragma unroll
      for (int p = 0; p < 3; ++p){
        acc[p][mf] = __builtin_amdgcn_mfma_f32_16x16x32_bf16(hi, Bq[p][ks], acc[p][mf], 0, 0, 0);
        acc[p][mf] = __builtin_amdgcn_mfma_f32_16x16x32_bf16(lo, Bq[p][ks], acc[p][mf], 0, 0, 0);
      }
    }
  }
  float bias[3] = {qkv_b[w*16+li], qkv_b[64+w*16+li], qkv_b[128+w*16+li]};
  float* outs[3] = {Q, K, V};
#pragma unroll
  for (int p = 0; p < 3; ++p)
#pragma unroll
    for (int mf = 0; mf < 4; ++mf)
#pragma unroll
      for (int r = 0; r < 4; ++r){
        int row = tile + mf * 16 + lg * 4 + r;
        if (row < NN) outs[p][(size_t)row * 64 + w * 16 + li] = acc[p][mf][r] + bias[p];
      }
}

// ---------- K2: fused edge kernel — bf16 rbuf overlaid on cmid, no cross-phase regs ----------
// LDS: cpre [0,9216) bf16 (A..D) ; buf2 [9216,18432): cmid bf16 (B..C) then rbufb bf16 (D..E)
__global__ __launch_bounds__(256, 6) void k2_edge(
    const float* __restrict__ e, const int* __restrict__ eidx,
    const int* __restrict__ nid, const int* __restrict__ sid,
    const bf16u* __restrict__ BpE, const float* __restrict__ E_b,
    const float* __restrict__ Aw, const bf16u* __restrict__ Bp1, const float* __restrict__ conn1_b,
    const float* __restrict__ Q, const float* __restrict__ K,
    const float* __restrict__ g1c, const float* __restrict__ b1c,
    const bf16u* __restrict__ Bp2, const float* __restrict__ conn2_b,
    const float* __restrict__ g2c, const float* __restrict__ b2c,
    bf16u* __restrict__ cm, float* __restrict__ sexp, float* __restrict__ out_conn){
  __shared__ __align__(16) char shmem[18432];
  __shared__ float mu1[64], rs1[64], mu2[64], rs2[64];
  bf16u* cpre  = (bf16u*)shmem;            // [64*72] bf16
  bf16u* cmid  = (bf16u*)(shmem + 9216);   // [64*72] bf16 (phases B..C)
  bf16u* rbufb = (bf16u*)(shmem + 9216);   // [64*72] bf16 (phases D..E, overlays cmid)
  int tile = blockIdx.x * 64;
  int t = threadIdx.x;
  int w = t >> 6, l = t & 63;
  int lg = l >> 4, li = l & 15;
  int dloc = w * 16 + li;

  float eb0 = E_b[dloc], eb1 = E_b[64 + dloc];
  float awv = Aw[li * 4 + w];
  f32x4 z = {0.f, 0.f, 0.f, 0.f};

  // --- phase A: per-mf Eh MFMA + pointwise ---
  {
    const short8v* bpe = (const short8v*)BpE;
    short8v BW0 = bpe[(0*8 + w)     * 64 + l];
    short8v BW1 = bpe[(1*8 + w)     * 64 + l];
    short8v BB0 = bpe[(0*8 + 4 + w) * 64 + l];
    short8v BB1 = bpe[(1*8 + 4 + w) * 64 + l];
#pragma unroll
    for (int mf = 0; mf < 4; ++mf){
      int eidA = eidx[tile + mf * 16 + li];
      const float* ep = e + (size_t)eidA * 64 + lg * 8;
      f32x4 accW = z, accB = z;
#pragma unroll
      for (int ks = 0; ks < 2; ++ks){
        float4 a0 = *(const float4*)(ep + ks * 32);
        float4 a1 = *(const float4*)(ep + ks * 32 + 4);
        short8v af;
        af[0]=(short)f2bf(a0.x); af[1]=(short)f2bf(a0.y); af[2]=(short)f2bf(a0.z); af[3]=(short)f2bf(a0.w);
        af[4]=(short)f2bf(a1.x); af[5]=(short)f2bf(a1.y); af[6]=(short)f2bf(a1.z); af[7]=(short)f2bf(a1.w);
        accW = __builtin_amdgcn_mfma_f32_16x16x32_bf16(af, ks ? BW1 : BW0, accW, 0, 0, 0);
        accB = __builtin_amdgcn_mfma_f32_16x16x32_bf16(af, ks ? BB1 : BB0, accB, 0, 0, 0);
      }
#pragma unroll
      for (int r = 0; r < 4; ++r){
        int el = mf * 16 + lg * 4 + r;
        int pos = tile + el;
        int dn = nid[pos], sn = sid[pos];
        float qv = Q[(size_t)dn * 64 + dloc];
        float kv = K[(size_t)sn * 64 + dloc];
        float ew  = accW[r] + eb0;
        float ebv = accB[r] + eb1;
        float c1 = (qv + kv) * ew;
        float c2 = copysignf(sqrtf(fabsf(c1)), c1);
        float cpv = fmaxf(c2 + ebv, 0.f);
        float s = cpv * awv;
        s += __shfl_xor(s, 1); s += __shfl_xor(s, 2);
        s += __shfl_xor(s, 4); s += __shfl_xor(s, 8);
        if (li == 0){
          float sc = fminf(fmaxf(s, -5.f), 5.f);
          sexp[(size_t)pos * 4 + w] = __expf(sc);
        }
        cpre[el * 72 + dloc] = f2bf(cpv);
      }
    }
  }
  __syncthreads();

  // --- phase B: conn1 MFMA; store cm global + cmid LDS ---
  {
    float c1b = conn1_b[dloc];
    const short8v* bp1 = (const short8v*)Bp1;
    short8v B10 = bp1[(0*4 + w) * 64 + l];
    short8v B11 = bp1[(1*4 + w) * 64 + l];
#pragma unroll
    for (int mf = 0; mf < 4; ++mf){
      const bf16u* ap = &cpre[(mf * 16 + li) * 72 + lg * 8];
      short8v a0 = *(const short8v*)(ap);
      short8v a1 = *(const short8v*)(ap + 32);
      f32x4 acc = z;
      acc = __builtin_amdgcn_mfma_f32_16x16x32_bf16(a0, B10, acc, 0, 0, 0);
      acc = __builtin_amdgcn_mfma_f32_16x16x32_bf16(a1, B11, acc, 0, 0, 0);
#pragma unroll
      for (int r = 0; r < 4; ++r){
        int el = mf * 16 + lg * 4 + r;
        bf16u vb = f2bf(acc[r] + c1b);
        cm[(size_t)(tile + el) * 64 + dloc] = vb;
        cmid[el * 72 + dloc] = vb;
      }
    }
  }
  __syncthreads();

  // --- phase B2: LN1c stats from cmid, thread = (row, quarter) ---
  {
    int el = t >> 2, q = t & 3;
    const short8v* cp8 = (const short8v*)&cmid[el * 72 + q * 16];
    short8v c0 = cp8[0], c1 = cp8[1];
    float s = 0.f, sq = 0.f;
#pragma unroll
    for (int i = 0; i < 8; ++i){
      float v0 = bf2f((bf16u)c0[i]), v1 = bf2f((bf16u)c1[i]);
      s += v0 + v1; sq += v0*v0 + v1*v1;
    }
    s  += __shfl_xor(s, 1);  s  += __shfl_xor(s, 2);
    sq += __shfl_xor(sq, 1); sq += __shfl_xor(sq, 2);
    if (q == 0){
      float mu = s * (1.f/64.f);
      float var = sq * (1.f/64.f) - mu * mu;
      mu1[el] = mu;
      rs1[el] = rsqrtf(fmaxf(var, 0.f) + 1e-5f);
    }
  }
  __syncthreads();

  // --- phase C: LN1c normalize + relu -> cpre (overwrite) ---
  {
    float g1v = g1c[dloc], b1v = b1c[dloc];
#pragma unroll
    for (int mf = 0; mf < 4; ++mf){
#pragma unroll
      for (int r = 0; r < 4; ++r){
        int el = mf * 16 + lg * 4 + r;
        float cv = bf2f(cmid[el * 72 + dloc]);
        float cn = fmaxf((cv - mu1[el]) * rs1[el] * g1v + b1v, 0.f);
        cpre[el * 72 + dloc] = f2bf(cn);
      }
    }
  }
  __syncthreads();   // cmid reads done; buf2 may now be rbufb

  // --- phase D: conn2 MFMA + residual -> rbufb (bf16, direct LDS store) ---
  {
    float c2b = conn2_b[dloc];
    const short8v* bp2 = (const short8v*)Bp2;
    short8v B20 = bp2[(0*4 + w) * 64 + l];
    short8v B21 = bp2[(1*4 + w) * 64 + l];
#pragma unroll
    for (int mf = 0; mf < 4; ++mf){
      const bf16u* ap = &cpre[(mf * 16 + li) * 72 + lg * 8];
      short8v a0 = *(const short8v*)(ap);
      short8v a1 = *(const short8v*)(ap + 32);
      f32x4 acc = z;
      acc = __builtin_amdgcn_mfma_f32_16x16x32_bf16(a0, B20, acc, 0, 0, 0);
      acc = __builtin_amdgcn_mfma_f32_16x16x32_bf16(a1, B21, acc, 0, 0, 0);
#pragma unroll
      for (int r = 0; r < 4; ++r){
        int el = mf * 16 + lg * 4 + r;
        int eid = eidx[tile + el];
        rbufb[el * 72 + dloc] = f2bf(acc[r] + c2b + e[(size_t)eid * 64 + dloc]);
      }
    }
  }
  __syncthreads();

  // --- phase D2: LN2c stats from rbufb ---
  {
    int el = t >> 2, q = t & 3;
    const short8v* rp8 = (const short8v*)&rbufb[el * 72 + q * 16];
    short8v c0 = rp8[0], c1 = rp8[1];
    float s = 0.f, sq = 0.f;
#pragma unroll
    for (int i = 0; i < 8; ++i){
      float v0 = bf2f((bf16u)c0[i]), v1 = bf2f((bf16u)c1[i]);
      s += v0 + v1; sq += v0*v0 + v1*v1;
    }
    s  += __shfl_xor(s, 1);  s  += __shfl_xor(s, 2);
    sq += __shfl_xor(sq, 1); sq += __shfl_xor(sq, 2);
    if (q == 0){
      float mu = s * (1.f/64.f);
      float var = sq * (1.f/64.f) - mu * mu;
      mu2[el] = mu;
      rs2[el] = rsqrtf(fmaxf(var, 0.f) + 1e-5f);
    }
  }
  __syncthreads();

  // --- phase E: LN2c + scatter store by eid ---
  {
    float g2v = g2c[dloc], b2v = b2c[dloc];
#pragma unroll
    for (int mf = 0; mf < 4; ++mf){
#pragma unroll
      for (int r = 0; r < 4; ++r){
        int el = mf * 16 + lg * 4 + r;
        int eid = eidx[tile + el];
        float rv = bf2f(rbufb[el * 72 + dloc]);
        out_conn[(size_t)eid * 64 + dloc] = (rv - mu2[el]) * rs2[el] * g2v + b2v;
      }
    }
  }
}

// ---------- K_agg: wave per node; cm/sexp sequential, V gathered ----------
__global__ __launch_bounds__(256) void k_agg(
    const int* __restrict__ start, const int* __restrict__ sid,
    const float* __restrict__ sexp, const bf16u* __restrict__ cm, const float* __restrict__ V,
    const float* __restrict__ x, float* __restrict__ hpre){
  int wid = (blockIdx.x * 256 + threadIdx.x) >> 6;
  int lane = threadIdx.x & 63;
  if (wid >= NN) return;
  int s0 = start[wid], s1 = start[wid + 1];
  int h = lane >> 4;
  float num = 0.f, den = 0.f;
  for (int i = s0; i < s1; ++i){
    float sx = sexp[(size_t)i * 4 + h];
    int sn = sid[i];
    float v  = V[(size_t)sn * 64 + lane];
    float cc = bf2f(cm[(size_t)i * 64 + lane]);
    num += sx * (v + cc);
    den += sx;
  }
  hpre[(size_t)wid * 64 + lane] = x[(size_t)wid * 64 + lane] + num / (den + 1e-16f);
}

// ---------- K5: node final — LN1h + FFN (MFMA) + LN2h ----------
__global__ __launch_bounds__(256) void k5_node(
    const float* __restrict__ hpre,
    const float* __restrict__ g1, const float* __restrict__ b1,
    const bf16u* __restrict__ BpF1, const float* __restrict__ ffn1_b,
    const bf16u* __restrict__ BpF2, const float* __restrict__ ffn2_b,
    const float* __restrict__ g2, const float* __restrict__ b2,
    float* __restrict__ out_h){
  __shared__ bf16u hlhi[64 * 72];
  __shared__ bf16u hllo[64 * 72];
  __shared__ bf16u g1o[64 * 136];
  __shared__ float reds[64][4];
  __shared__ float redq[64][4];
  int tile = blockIdx.x * 64;
  int t = threadIdx.x;
  {
    int el = t >> 2, q = t & 3;
    int row = tile + el;
    bool g = row < NN;
    float v[16];
    if (g){
      const float4* hp = (const float4*)(hpre + (size_t)row * 64 + q * 16);
#pragma unroll
      for (int c = 0; c < 4; ++c){
        float4 tv = hp[c];
        v[c*4+0]=tv.x; v[c*4+1]=tv.y; v[c*4+2]=tv.z; v[c*4+3]=tv.w;
      }
    } else {
#pragma unroll
      for (int i = 0; i < 16; ++i) v[i] = 0.f;
    }
    float s = 0.f, sq = 0.f;
#pragma unroll
    for (int i = 0; i < 16; ++i){ s += v[i]; sq += v[i]*v[i]; }
    s  += __shfl_xor(s, 1);  s  += __shfl_xor(s, 2);
    sq += __shfl_xor(sq, 1); sq += __shfl_xor(sq, 2);
    float mu = s * (1.f/64.f);
    float var = sq * (1.f/64.f) - mu * mu;
    float rs = rsqrtf(fmaxf(var, 0.f) + 1e-5f);
#pragma unroll
    for (int i = 0; i < 16; ++i){
      int d = q * 16 + i;
      float hv = (v[i] - mu) * rs * g1[d] + b1[d];
      bf16u hb = f2bf(hv);
      hlhi[el * 72 + d] = hb;
      hllo[el * 72 + d] = f2bf(hv - bf2f(hb));
    }
  }
  __syncthreads();
  int w = t >> 6, l = t & 63;
  int lg = l >> 4, li = l & 15;
  const short8v* bpf1 = (const short8v*)BpF1;
  short8v B1f[2][2];
#pragma unroll
  for (int f = 0; f < 2; ++f)
#pragma unroll
    for (int ks = 0; ks < 2; ++ks)
      B1f[f][ks] = bpf1[(ks * 8 + f * 4 + w) * 64 + l];
  f32x4 z = {0.f, 0.f, 0.f, 0.f};
  f32x4 acc1[2][4];
#pragma unroll
  for (int f = 0; f < 2; ++f)
#pragma unroll
    for (int mf = 0; mf < 4; ++mf) acc1[f][mf] = z;
#pragma unroll
  for (int mf = 0; mf < 4; ++mf){
#pragma unroll
    for (int ks = 0; ks < 2; ++ks){
      const bf16u* ah = &hlhi[(mf * 16 + li) * 72 + ks * 32 + lg * 8];
      const bf16u* al = &hllo[(mf * 16 + li) * 72 + ks * 32 + lg * 8];
      short8v Ahi = *(const short8v*)ah;
      short8v Alo = *(const short8v*)al;
#pragma unroll
      for (int f = 0; f < 2; ++f){
        acc1[f][mf] = __builtin_amdgcn_mfma_f32_16x16x32_bf16(Ahi, B1f[f][ks], acc1[f][mf], 0, 0, 0);
        acc1[f][mf] = __builtin_amdgcn_mfma_f32_16x16x32_bf16(Alo, B1f[f][ks], acc1[f][mf], 0, 0, 0);
      }
    }
  }
  float fb[2] = {ffn1_b[w*16+li], ffn1_b[64+w*16+li]};
#pragma unroll
  for (int f = 0; f < 2; ++f)
#pragma unroll
    for (int mf = 0; mf < 4; ++mf)
#pragma unroll
      for (int r = 0; r < 4; ++r){
        int rowl = mf * 16 + lg * 4 + r;
        int col = f * 64 + w * 16 + li;
        g1o[rowl * 136 + col] = f2bf(fmaxf(acc1[f][mf][r] + fb[f], 0.f));
      }
  __syncthreads();
  const short8v* bpf2 = (const short8v*)BpF2;
  short8v B2f[4];
#pragma unroll
  for (int ks = 0; ks < 4; ++ks) B2f[ks] = bpf2[(ks * 4 + w) * 64 + l];
  int o = w * 16 + li;
  float f2b_ = ffn2_b[o];
  float racc[4][4];
#pragma unroll
  for (int mf = 0; mf < 4; ++mf){
    f32x4 acc = z;
#pragma unroll
    for (int ks = 0; ks < 4; ++ks){
      short8v A2 = *(const short8v*)&g1o[(mf * 16 + li) * 136 + ks * 32 + lg * 8];
      acc = __builtin_amdgcn_mfma_f32_16x16x32_bf16(A2, B2f[ks], acc, 0, 0, 0);
    }
#pragma unroll
    for (int r = 0; r < 4; ++r){
      int rowl = mf * 16 + lg * 4 + r;
      int row = tile + rowl;
      float hres = (row < NN) ? hpre[(size_t)row * 64 + o] : 0.f;
      float rv = acc[r] + f2b_ + hres;
      racc[mf][r] = rv;
      float s = rv, q2 = rv * rv;
      s  += __shfl_xor(s, 1);  s  += __shfl_xor(s, 2);  s  += __shfl_xor(s, 4);  s  += __shfl_xor(s, 8);
      q2 += __shfl_xor(q2, 1); q2 += __shfl_xor(q2, 2); q2 += __shfl_xor(q2, 4); q2 += __shfl_xor(q2, 8);
      if (li == 0){ reds[rowl][w] = s; redq[rowl][w] = q2; }
    }
  }
  __syncthreads();
  float g2v = g2[o], b2v = b2[o];
#pragma unroll
  for (int mf = 0; mf < 4; ++mf){
#pragma unroll
    for (int r = 0; r < 4; ++r){
      int rowl = mf * 16 + lg * 4 + r;
      int row = tile + rowl;
      if (row < NN){
        float S  = reds[rowl][0] + reds[rowl][1] + reds[rowl][2] + reds[rowl][3];
        float Qq = redq[rowl][0] + redq[rowl][1] + redq[rowl][2] + redq[rowl][3];
        float mu2 = S * (1.f/64.f);
        float var2 = Qq * (1.f/64.f) - mu2 * mu2;
        float rs2 = rsqrtf(fmaxf(var2, 0.f) + 1e-5f);
        out_h[(size_t)row * 64 + o] = (racc[mf][r] - mu2) * rs2 * g2v + b2v;
      }
    }
  }
}

extern "C" void kernel_launch(void* const* d_in, const int* in_sizes, int n_in,
                              void* d_out, int out_size, void* d_ws, size_t ws_size,
                              hipStream_t stream){
  const float* x       = (const float*)d_in[0];
  const float* e       = (const float*)d_in[1];
  const int*   dst     = (const int*)d_in[2];
  const int*   src     = (const int*)d_in[3];
  const float* qkv_w   = (const float*)d_in[4];
  const float* qkv_b   = (const float*)d_in[5];
  const float* E_w     = (const float*)d_in[6];
  const float* E_b     = (const float*)d_in[7];
  const float* Aw      = (const float*)d_in[8];
  const float* conn1_w = (const float*)d_in[9];
  const float* conn1_b = (const float*)d_in[10];
  const float* conn2_w = (const float*)d_in[11];
  const float* conn2_b = (const float*)d_in[12];
  const float* ffn1_w  = (const float*)d_in[13];
  const float* ffn1_b  = (const float*)d_in[14];
  const float* ffn2_w  = (const float*)d_in[15];
  const float* ffn2_b  = (const float*)d_in[16];
  const float* ln1h_g  = (const float*)d_in[17];
  const float* ln1h_b  = (const float*)d_in[18];
  const float* ln2h_g  = (const float*)d_in[19];
  const float* ln2h_b  = (const float*)d_in[20];
  const float* ln1c_g  = (const float*)d_in[21];
  const float* ln1c_b  = (const float*)d_in[22];
  const float* ln2c_g  = (const float*)d_in[23];
  const float* ln2c_b  = (const float*)d_in[24];

  char* ws = (char*)d_ws;
  size_t off = 0;
  auto alloc = [&](size_t bytes) -> void* {
    void* p = ws + off;
    off += (bytes + 255) & ~(size_t)255;
    return p;
  };
  float* Q     = (float*)alloc((size_t)NN * 64 * 4);
  float* Kq    = (float*)alloc((size_t)NN * 64 * 4);
  float* V     = (float*)alloc((size_t)NN * 64 * 4);
  bf16u* cmb   = (bf16u*)alloc((size_t)NE * 64 * 2);
  float* sexp  = (float*)alloc((size_t)NE * 4 * 4);
  float* hpre  = (float*)alloc((size_t)NN * 64 * 4);
  bf16u* BpE   = (bf16u*)alloc(8192 * 2);
  bf16u* Bp1   = (bf16u*)alloc(4096 * 2);
  bf16u* Bp2   = (bf16u*)alloc(4096 * 2);
  bf16u* BpQ   = (bf16u*)alloc(12288 * 2);
  bf16u* BpF1  = (bf16u*)alloc(8192 * 2);
  bf16u* BpF2  = (bf16u*)alloc(8192 * 2);
  int*   cnt   = (int*)alloc((size_t)NN * 4);
  int*   startp= (int*)alloc(((size_t)NN + 1) * 4);
  int*   cursor= (int*)alloc((size_t)NN * 4);
  int*   eidx  = (int*)alloc((size_t)NE * 4);
  int*   nid   = (int*)alloc((size_t)NE * 4);
  int*   sid   = (int*)alloc((size_t)NE * 4);

  float* out_h    = (float*)d_out;
  float* out_conn = out_h + (size_t)NN * 64;

  hipMemsetAsync(cnt, 0, (size_t)NN * 4, stream);

  k0_pack<<<48, 256, 0, stream>>>(E_w, conn1_w, conn2_w, qkv_w, ffn1_w, ffn2_w,
                                  BpE, Bp1, Bp2, BpQ, BpF1, BpF2);
  k_hist<<<NE / 256, 256, 0, stream>>>(dst, cnt);
  k_scan<<<1, SCAN_T, 0, stream>>>(cnt, startp, cursor);
  k_scatter<<<NE / 256, 256, 0, stream>>>(dst, src, cursor, eidx, nid, sid);
  k1_qkv<<<(NN + 63) / 64, 256, 0, stream>>>(x, BpQ, qkv_b, Q, Kq, V);
  k2_edge<<<NE / 64, 256, 0, stream>>>(e, eidx, nid, sid, BpE, E_b, Aw, Bp1, conn1_b,
                                       Q, Kq, ln1c_g, ln1c_b, Bp2, conn2_b,
                                       ln2c_g, ln2c_b, cmb, sexp, out_conn);
  k_agg<<<(NN * 64 + 255) / 256, 256, 0, stream>>>(startp, sid, sexp, cmb, V, x, hpre);
  k5_node<<<(NN + 63) / 64, 256, 0, stream>>>(hpre, ln1h_g, ln1h_b, BpF1, ffn1_b,
                                              BpF2, ffn2_b, ln2h_g, ln2h_b, out_h);
}

// Round 13
// 436.655 us; speedup vs baseline: 1.2501x; 1.2022x over previous
//
#include <hip/hip_runtime.h>
#include <cstdint>

#define NN 50000
#define NE 512000

typedef unsigned short bf16u;
typedef __attribute__((ext_vector_type(8))) short short8v;
typedef __attribute__((ext_vector_type(4))) float f32x4;

__device__ __forceinline__ bf16u f2bf(float f){
  union { float f; unsigned int u; } v; v.f = f;
  unsigned int r = v.u + 0x7FFFu + ((v.u >> 16) & 1u);
  return (bf16u)(r >> 16);
}
__device__ __forceinline__ float bf2f(bf16u s){
  union { unsigned int u; float f; } v; v.u = ((unsigned int)s) << 16;
  return v.f;
}

// ---------- K0: weight packing into MFMA B-fragments ----------
// B-frag layout (mfma_f32_16x16x32_bf16): elem [((ks*NF+nf)*64+l)*8+j] =
//   W[n][k],  n = nf*16 + (l&15),  k = ks*32 + ((l>>4)<<3) + j
__global__ void k0_pack(const float* __restrict__ E_w, const float* __restrict__ conn1_w,
                        const float* __restrict__ conn2_w, const float* __restrict__ qkv_w,
                        const float* __restrict__ ffn1_w, const float* __restrict__ ffn2_w,
                        const float* __restrict__ Aw,
                        bf16u* __restrict__ BpE, bf16u* __restrict__ Bp1,
                        bf16u* __restrict__ Bp2, bf16u* __restrict__ BpQ,
                        bf16u* __restrict__ BpF1, bf16u* __restrict__ BpF2,
                        bf16u* __restrict__ BpA){
  int i = blockIdx.x * 256 + threadIdx.x;   // 0..12287
  int j = i & 7, l = (i >> 3) & 63;
  int nl = l & 15, kl = (l >> 4) << 3;
  if (i < 8192){   // E_w: (128,64), NF=8, KS=2
    int rest = i >> 9, nf = rest & 7, ks = rest >> 3;
    int n = nf * 16 + nl, k = ks * 32 + kl + j;
    BpE[i] = f2bf(E_w[n * 64 + k]);
  }
  if (i < 4096){   // conn1_w/conn2_w: (64,64), NF=4, KS=2
    int rest = i >> 9, nf = rest & 3, ks = rest >> 2;
    int n = nf * 16 + nl, k = ks * 32 + kl + j;
    Bp1[i] = f2bf(conn1_w[n * 64 + k]);
    Bp2[i] = f2bf(conn2_w[n * 64 + k]);
  }
  if (i < 12288){  // qkv_w: (192,64), NF=12, KS=2
    int rest = i >> 9, nf = rest % 12, ks = rest / 12;
    int n = nf * 16 + nl, k = ks * 32 + kl + j;
    BpQ[i] = f2bf(qkv_w[n * 64 + k]);
  }
  if (i < 8192){   // ffn1_w: (128,64), NF=8, KS=2
    int rest = i >> 9, nf = rest & 7, ks = rest >> 3;
    int n = nf * 16 + nl, k = ks * 32 + kl + j;
    BpF1[i] = f2bf(ffn1_w[n * 64 + k]);
  }
  if (i < 8192){   // ffn2_w: (64,128), NF=4, KS=4
    int rest = i >> 9, nf = rest & 3, ks = rest >> 2;
    int n = nf * 16 + nl, k = ks * 32 + kl + j;
    BpF2[i] = f2bf(ffn2_w[n * 128 + k]);
  }
  if (i < 1024){   // Aw score B-frag: NF=1, KS=2; col n<4 = head, B[k][n]=Aw[(k&15)*4+n] iff k>>4==n
    int ks = i >> 9;
    int n = nl, k = ks * 32 + kl + j;
    float v = (n < 4 && (k >> 4) == n) ? Aw[(k & 15) * 4 + n] : 0.f;
    BpA[i] = f2bf(v);
  }
}

// ---------- CSR build ----------
__global__ void k_hist(const int* __restrict__ dst, int* __restrict__ cnt){
  int e = blockIdx.x * 256 + threadIdx.x;
  if (e < NE) atomicAdd(&cnt[dst[e]], 1);
}

#define SCAN_T 1024
#define PER_T 52   // 1024*52 >= NN; 52*4B = 208B, 16B-aligned -> int4 loads
__global__ __launch_bounds__(SCAN_T) void k_scan(const int* __restrict__ cnt,
                                                 int* __restrict__ start, int* __restrict__ cursor){
  __shared__ int ls[SCAN_T];
  int t = threadIdx.x;
  int base = t * PER_T;
  int s = 0;
  const int4* cp = (const int4*)(cnt + base);
#pragma unroll
  for (int c = 0; c < 13; ++c){
    int4 v = cp[c];
    int n0 = base + c * 4;
    s += (n0 + 0 < NN ? v.x : 0) + (n0 + 1 < NN ? v.y : 0)
       + (n0 + 2 < NN ? v.z : 0) + (n0 + 3 < NN ? v.w : 0);
  }
  ls[t] = s; __syncthreads();
  for (int off = 1; off < SCAN_T; off <<= 1){
    int v = ls[t];
    int add = (t >= off) ? ls[t - off] : 0;
    __syncthreads();
    ls[t] = v + add;
    __syncthreads();
  }
  int run = (t > 0) ? ls[t - 1] : 0;
  for (int i = 0; i < PER_T; ++i){
    int n = base + i;
    if (n < NN){ start[n] = run; cursor[n] = run; run += cnt[n]; }
  }
  if (t == SCAN_T - 1) start[NN] = run;
}

__global__ void k_scatter(const int* __restrict__ dst, const int* __restrict__ src,
                          int* __restrict__ cursor, int* __restrict__ eidx,
                          int* __restrict__ nid, int* __restrict__ sid){
  int e = blockIdx.x * 256 + threadIdx.x;
  if (e < NE){
    int dn = dst[e];
    int p = atomicAdd(&cursor[dn], 1);
    eidx[p] = e;
    nid[p] = dn;
    sid[p] = src[e];
  }
}

// ---------- K1: node QKV — MFMA, split-bf16 A ----------
__global__ __launch_bounds__(256) void k1_qkv(const float* __restrict__ x,
    const bf16u* __restrict__ BpQ, const float* __restrict__ qkv_b,
    float* __restrict__ Q, float* __restrict__ K, float* __restrict__ V){
  int tile = blockIdx.x * 64;
  int w = threadIdx.x >> 6, l = threadIdx.x & 63;
  int lg = l >> 4, li = l & 15;
  const short8v* bpq = (const short8v*)BpQ;
  short8v Bq[3][2];
#pragma unroll
  for (int p = 0; p < 3; ++p)
#pragma unroll
    for (int ks = 0; ks < 2; ++ks)
      Bq[p][ks] = bpq[(ks * 12 + p * 4 + w) * 64 + l];
  f32x4 z = {0.f, 0.f, 0.f, 0.f};
  f32x4 acc[3][4];
#pragma unroll
  for (int p = 0; p < 3; ++p)
#pragma unroll
    for (int mf = 0; mf < 4; ++mf) acc[p][mf] = z;
#pragma unroll
  for (int mf = 0; mf < 4; ++mf){
    int row = tile + mf * 16 + li;
    bool g = row < NN;
    const float* xp = x + (size_t)row * 64 + lg * 8;
#pragma unroll
    for (int ks = 0; ks < 2; ++ks){
      float v[8];
      if (g){
        float4 t0 = *(const float4*)(xp + ks * 32);
        float4 t1 = *(const float4*)(xp + ks * 32 + 4);
        v[0]=t0.x; v[1]=t0.y; v[2]=t0.z; v[3]=t0.w;
        v[4]=t1.x; v[5]=t1.y; v[6]=t1.z; v[7]=t1.w;
      } else {
#pragma unroll
        for (int j = 0; j < 8; ++j) v[j] = 0.f;
      }
      short8v hi, lo;
#pragma unroll
      for (int j = 0; j < 8; ++j){
        bf16u h = f2bf(v[j]);
        hi[j] = (short)h;
        lo[j] = (short)f2bf(v[j] - bf2f(h));
      }
#pragma unroll
      for (int p = 0; p < 3; ++p){
        acc[p][mf] = __builtin_amdgcn_mfma_f32_16x16x32_bf16(hi, Bq[p][ks], acc[p][mf], 0, 0, 0);
        acc[p][mf] = __builtin_amdgcn_mfma_f32_16x16x32_bf16(lo, Bq[p][ks], acc[p][mf], 0, 0, 0);
      }
    }
  }
  float bias[3] = {qkv_b[w*16+li], qkv_b[64+w*16+li], qkv_b[128+w*16+li]};
  float* outs[3] = {Q, K, V};
#pragma unroll
  for (int p = 0; p < 3; ++p)
#pragma unroll
    for (int mf = 0; mf < 4; ++mf)
#pragma unroll
      for (int r = 0; r < 4; ++r){
        int row = tile + mf * 16 + lg * 4 + r;
        if (row < NN) outs[p][(size_t)row * 64 + w * 16 + li] = acc[p][mf][r] + bias[p];
      }
}

// ---------- K2: fused edge kernel — WAVE-AUTONOMOUS, zero __syncthreads ----------
// Wave w owns 16 CSR positions [tile+16w, tile+16w+16), all 64 dims.
// LN stats wave-local (reg + li-group shfl). Score via extra MFMA (BpA).
// D->A transposes via wave-private 2.3KB LDS buffer.
__global__ __launch_bounds__(256, 4) void k2_edge(
    const float* __restrict__ e, const int* __restrict__ eidx,
    const int* __restrict__ nid, const int* __restrict__ sid,
    const bf16u* __restrict__ BpE, const float* __restrict__ E_b,
    const bf16u* __restrict__ BpA, const bf16u* __restrict__ Bp1, const float* __restrict__ conn1_b,
    const float* __restrict__ Q, const float* __restrict__ K,
    const float* __restrict__ g1c, const float* __restrict__ b1c,
    const bf16u* __restrict__ Bp2, const float* __restrict__ conn2_b,
    const float* __restrict__ g2c, const float* __restrict__ b2c,
    bf16u* __restrict__ cm, float* __restrict__ sexp, float* __restrict__ out_conn){
  __shared__ bf16u ldsT[4 * 16 * 72];     // per-wave 16x72 bf16 transpose buffer
  int t = threadIdx.x;
  int w = t >> 6, l = t & 63;
  int lg = l >> 4, li = l & 15;
  int pos0 = blockIdx.x * 64 + w * 16;
  bf16u* T = &ldsT[w * (16 * 72)];
  f32x4 z = {0.f, 0.f, 0.f, 0.f};

  // --- phase A: Eh MFMA (16 edges x 128 outs, this wave) ---
  short8v afr[2];
  {
    int eidA = eidx[pos0 + li];
    const float* ep = e + (size_t)eidA * 64 + lg * 8;
#pragma unroll
    for (int ks = 0; ks < 2; ++ks){
      float4 a0 = *(const float4*)(ep + ks * 32);
      float4 a1 = *(const float4*)(ep + ks * 32 + 4);
      short8v af;
      af[0]=(short)f2bf(a0.x); af[1]=(short)f2bf(a0.y); af[2]=(short)f2bf(a0.z); af[3]=(short)f2bf(a0.w);
      af[4]=(short)f2bf(a1.x); af[5]=(short)f2bf(a1.y); af[6]=(short)f2bf(a1.z); af[7]=(short)f2bf(a1.w);
      afr[ks] = af;
    }
  }
  f32x4 accW[4], accB[4];
#pragma unroll
  for (int nf = 0; nf < 4; ++nf){ accW[nf] = z; accB[nf] = z; }
  {
    const short8v* bpe = (const short8v*)BpE;
#pragma unroll
    for (int ks = 0; ks < 2; ++ks){
#pragma unroll
      for (int nf = 0; nf < 4; ++nf){
        short8v BW = bpe[(ks * 8 + nf) * 64 + l];
        short8v BB = bpe[(ks * 8 + 4 + nf) * 64 + l];
        accW[nf] = __builtin_amdgcn_mfma_f32_16x16x32_bf16(afr[ks], BW, accW[nf], 0, 0, 0);
        accB[nf] = __builtin_amdgcn_mfma_f32_16x16x32_bf16(afr[ks], BB, accB[nf], 0, 0, 0);
      }
    }
  }

  // --- pointwise: conn_pre (D-layout: row=lg*4+r, col=nf*16+li) ---
  int dnv[4], snv[4], eidv[4];
#pragma unroll
  for (int r = 0; r < 4; ++r){
    int pos = pos0 + lg * 4 + r;
    dnv[r] = nid[pos]; snv[r] = sid[pos]; eidv[r] = eidx[pos];
  }
  float cp[4][4];
#pragma unroll
  for (int nf = 0; nf < 4; ++nf){
    int dim = nf * 16 + li;
    float eb0 = E_b[dim], eb1 = E_b[64 + dim];
#pragma unroll
    for (int r = 0; r < 4; ++r){
      float qv = Q[(size_t)dnv[r] * 64 + dim];
      float kv = K[(size_t)snv[r] * 64 + dim];
      float ew  = accW[nf][r] + eb0;
      float ebv = accB[nf][r] + eb1;
      float c1 = (qv + kv) * ew;
      float c2 = copysignf(sqrtf(fabsf(c1)), c1);
      cp[nf][r] = fmaxf(c2 + ebv, 0.f);
    }
  }

  // --- transpose #1: cp D-layout -> LDS -> A-frags ---
#pragma unroll
  for (int nf = 0; nf < 4; ++nf)
#pragma unroll
    for (int r = 0; r < 4; ++r)
      T[(lg * 4 + r) * 72 + nf * 16 + li] = f2bf(cp[nf][r]);
  __builtin_amdgcn_wave_barrier();
  short8v a1f[2];
  a1f[0] = *(const short8v*)&T[li * 72 + 0 * 32 + lg * 8];
  a1f[1] = *(const short8v*)&T[li * 72 + 1 * 32 + lg * 8];

  // --- score MFMA (head = output col, cols 0..3 valid) + exp + store ---
  {
    const short8v* bpa = (const short8v*)BpA;
    f32x4 sacc = z;
    sacc = __builtin_amdgcn_mfma_f32_16x16x32_bf16(a1f[0], bpa[0 * 64 + l], sacc, 0, 0, 0);
    sacc = __builtin_amdgcn_mfma_f32_16x16x32_bf16(a1f[1], bpa[1 * 64 + l], sacc, 0, 0, 0);
    if (li < 4){
#pragma unroll
      for (int r = 0; r < 4; ++r){
        float sc = fminf(fmaxf(sacc[r], -5.f), 5.f);
        sexp[(size_t)(pos0 + lg * 4 + r) * 4 + li] = __expf(sc);
      }
    }
  }

  // --- conn1 MFMA -> cmv (D-layout, f32) ---
  float cmv[4][4];
  {
    const short8v* bp1 = (const short8v*)Bp1;
#pragma unroll
    for (int nf = 0; nf < 4; ++nf){
      f32x4 acc = z;
      acc = __builtin_amdgcn_mfma_f32_16x16x32_bf16(a1f[0], bp1[(0 * 4 + nf) * 64 + l], acc, 0, 0, 0);
      acc = __builtin_amdgcn_mfma_f32_16x16x32_bf16(a1f[1], bp1[(1 * 4 + nf) * 64 + l], acc, 0, 0, 0);
      float c1b = conn1_b[nf * 16 + li];
#pragma unroll
      for (int r = 0; r < 4; ++r){
        float v = acc[r] + c1b;
        cmv[nf][r] = v;
        cm[(size_t)(pos0 + lg * 4 + r) * 64 + nf * 16 + li] = f2bf(v);
      }
    }
  }

  // --- LN1c stats (wave-local: 4 reg adds + li-group shfl) ---
  float mu1r[4], rs1r[4];
#pragma unroll
  for (int r = 0; r < 4; ++r){
    float s = cmv[0][r] + cmv[1][r] + cmv[2][r] + cmv[3][r];
    float q = cmv[0][r]*cmv[0][r] + cmv[1][r]*cmv[1][r] + cmv[2][r]*cmv[2][r] + cmv[3][r]*cmv[3][r];
    s += __shfl_xor(s, 1); s += __shfl_xor(s, 2); s += __shfl_xor(s, 4); s += __shfl_xor(s, 8);
    q += __shfl_xor(q, 1); q += __shfl_xor(q, 2); q += __shfl_xor(q, 4); q += __shfl_xor(q, 8);
    float mu = s * (1.f / 64.f);
    float var = q * (1.f / 64.f) - mu * mu;
    mu1r[r] = mu;
    rs1r[r] = rsqrtf(fmaxf(var, 0.f) + 1e-5f);
  }

  // --- LN1c normalize + relu -> transpose #2 (reuse T) ---
  __builtin_amdgcn_wave_barrier();
#pragma unroll
  for (int nf = 0; nf < 4; ++nf){
    int dim = nf * 16 + li;
    float g1v = g1c[dim], b1v = b1c[dim];
#pragma unroll
    for (int r = 0; r < 4; ++r){
      float cn = fmaxf((cmv[nf][r] - mu1r[r]) * rs1r[r] * g1v + b1v, 0.f);
      T[(lg * 4 + r) * 72 + dim] = f2bf(cn);
    }
  }
  __builtin_amdgcn_wave_barrier();
  short8v a2f[2];
  a2f[0] = *(const short8v*)&T[li * 72 + 0 * 32 + lg * 8];
  a2f[1] = *(const short8v*)&T[li * 72 + 1 * 32 + lg * 8];

  // --- conn2 MFMA + residual -> rv (f32 regs) ---
  float rv[4][4];
  {
    const short8v* bp2 = (const short8v*)Bp2;
#pragma unroll
    for (int nf = 0; nf < 4; ++nf){
      f32x4 acc = z;
      acc = __builtin_amdgcn_mfma_f32_16x16x32_bf16(a2f[0], bp2[(0 * 4 + nf) * 64 + l], acc, 0, 0, 0);
      acc = __builtin_amdgcn_mfma_f32_16x16x32_bf16(a2f[1], bp2[(1 * 4 + nf) * 64 + l], acc, 0, 0, 0);
      int dim = nf * 16 + li;
      float c2b = conn2_b[dim];
#pragma unroll
      for (int r = 0; r < 4; ++r)
        rv[nf][r] = acc[r] + c2b + e[(size_t)eidv[r] * 64 + dim];
    }
  }

  // --- LN2c stats (wave-local) + store out_conn ---
#pragma unroll
  for (int r = 0; r < 4; ++r){
    float s = rv[0][r] + rv[1][r] + rv[2][r] + rv[3][r];
    float q = rv[0][r]*rv[0][r] + rv[1][r]*rv[1][r] + rv[2][r]*rv[2][r] + rv[3][r]*rv[3][r];
    s += __shfl_xor(s, 1); s += __shfl_xor(s, 2); s += __shfl_xor(s, 4); s += __shfl_xor(s, 8);
    q += __shfl_xor(q, 1); q += __shfl_xor(q, 2); q += __shfl_xor(q, 4); q += __shfl_xor(q, 8);
    float mu = s * (1.f / 64.f);
    float var = q * (1.f / 64.f) - mu * mu;
    float rs = rsqrtf(fmaxf(var, 0.f) + 1e-5f);
#pragma unroll
    for (int nf = 0; nf < 4; ++nf){
      int dim = nf * 16 + li;
      out_conn[(size_t)eidv[r] * 64 + dim] = (rv[nf][r] - mu) * rs * g2c[dim] + b2c[dim];
    }
  }
}

// ---------- K_agg: wave per node; cm/sexp sequential, V gathered ----------
__global__ __launch_bounds__(256) void k_agg(
    const int* __restrict__ start, const int* __restrict__ sid,
    const float* __restrict__ sexp, const bf16u* __restrict__ cm, const float* __restrict__ V,
    const float* __restrict__ x, float* __restrict__ hpre){
  int wid = (blockIdx.x * 256 + threadIdx.x) >> 6;
  int lane = threadIdx.x & 63;
  if (wid >= NN) return;
  int s0 = start[wid], s1 = start[wid + 1];
  int h = lane >> 4;
  float num = 0.f, den = 0.f;
  for (int i = s0; i < s1; ++i){
    float sx = sexp[(size_t)i * 4 + h];
    int sn = sid[i];
    float v  = V[(size_t)sn * 64 + lane];
    float cc = bf2f(cm[(size_t)i * 64 + lane]);
    num += sx * (v + cc);
    den += sx;
  }
  hpre[(size_t)wid * 64 + lane] = x[(size_t)wid * 64 + lane] + num / (den + 1e-16f);
}

// ---------- K5: node final — LN1h + FFN (MFMA) + LN2h ----------
__global__ __launch_bounds__(256) void k5_node(
    const float* __restrict__ hpre,
    const float* __restrict__ g1, const float* __restrict__ b1,
    const bf16u* __restrict__ BpF1, const float* __restrict__ ffn1_b,
    const bf16u* __restrict__ BpF2, const float* __restrict__ ffn2_b,
    const float* __restrict__ g2, const float* __restrict__ b2,
    float* __restrict__ out_h){
  __shared__ bf16u hlhi[64 * 72];
  __shared__ bf16u hllo[64 * 72];
  __shared__ bf16u g1o[64 * 136];
  __shared__ float reds[64][4];
  __shared__ float redq[64][4];
  int tile = blockIdx.x * 64;
  int t = threadIdx.x;
  {
    int el = t >> 2, q = t & 3;
    int row = tile + el;
    bool g = row < NN;
    float v[16];
    if (g){
      const float4* hp = (const float4*)(hpre + (size_t)row * 64 + q * 16);
#pragma unroll
      for (int c = 0; c < 4; ++c){
        float4 tv = hp[c];
        v[c*4+0]=tv.x; v[c*4+1]=tv.y; v[c*4+2]=tv.z; v[c*4+3]=tv.w;
      }
    } else {
#pragma unroll
      for (int i = 0; i < 16; ++i) v[i] = 0.f;
    }
    float s = 0.f, sq = 0.f;
#pragma unroll
    for (int i = 0; i < 16; ++i){ s += v[i]; sq += v[i]*v[i]; }
    s  += __shfl_xor(s, 1);  s  += __shfl_xor(s, 2);
    sq += __shfl_xor(sq, 1); sq += __shfl_xor(sq, 2);
    float mu = s * (1.f/64.f);
    float var = sq * (1.f/64.f) - mu * mu;
    float rs = rsqrtf(fmaxf(var, 0.f) + 1e-5f);
#pragma unroll
    for (int i = 0; i < 16; ++i){
      int d = q * 16 + i;
      float hv = (v[i] - mu) * rs * g1[d] + b1[d];
      bf16u hb = f2bf(hv);
      hlhi[el * 72 + d] = hb;
      hllo[el * 72 + d] = f2bf(hv - bf2f(hb));
    }
  }
  __syncthreads();
  int w = t >> 6, l = t & 63;
  int lg = l >> 4, li = l & 15;
  const short8v* bpf1 = (const short8v*)BpF1;
  short8v B1f[2][2];
#pragma unroll
  for (int f = 0; f < 2; ++f)
#pragma unroll
    for (int ks = 0; ks < 2; ++ks)
      B1f[f][ks] = bpf1[(ks * 8 + f * 4 + w) * 64 + l];
  f32x4 z = {0.f, 0.f, 0.f, 0.f};
  f32x4 acc1[2][4];
#pragma unroll
  for (int f = 0; f < 2; ++f)
#pragma unroll
    for (int mf = 0; mf < 4; ++mf) acc1[f][mf] = z;
#pragma unroll
  for (int mf = 0; mf < 4; ++mf){
#pragma unroll
    for (int ks = 0; ks < 2; ++ks){
      const bf16u* ah = &hlhi[(mf * 16 + li) * 72 + ks * 32 + lg * 8];
      const bf16u* al = &hllo[(mf * 16 + li) * 72 + ks * 32 + lg * 8];
      short8v Ahi = *(const short8v*)ah;
      short8v Alo = *(const short8v*)al;
#pragma unroll
      for (int f = 0; f < 2; ++f){
        acc1[f][mf] = __builtin_amdgcn_mfma_f32_16x16x32_bf16(Ahi, B1f[f][ks], acc1[f][mf], 0, 0, 0);
        acc1[f][mf] = __builtin_amdgcn_mfma_f32_16x16x32_bf16(Alo, B1f[f][ks], acc1[f][mf], 0, 0, 0);
      }
    }
  }
  float fb[2] = {ffn1_b[w*16+li], ffn1_b[64+w*16+li]};
#pragma unroll
  for (int f = 0; f < 2; ++f)
#pragma unroll
    for (int mf = 0; mf < 4; ++mf)
#pragma unroll
      for (int r = 0; r < 4; ++r){
        int rowl = mf * 16 + lg * 4 + r;
        int col = f * 64 + w * 16 + li;
        g1o[rowl * 136 + col] = f2bf(fmaxf(acc1[f][mf][r] + fb[f], 0.f));
      }
  __syncthreads();
  const short8v* bpf2 = (const short8v*)BpF2;
  short8v B2f[4];
#pragma unroll
  for (int ks = 0; ks < 4; ++ks) B2f[ks] = bpf2[(ks * 4 + w) * 64 + l];
  int o = w * 16 + li;
  float f2b_ = ffn2_b[o];
  float racc[4][4];
#pragma unroll
  for (int mf = 0; mf < 4; ++mf){
    f32x4 acc = z;
#pragma unroll
    for (int ks = 0; ks < 4; ++ks){
      short8v A2 = *(const short8v*)&g1o[(mf * 16 + li) * 136 + ks * 32 + lg * 8];
      acc = __builtin_amdgcn_mfma_f32_16x16x32_bf16(A2, B2f[ks], acc, 0, 0, 0);
    }
#pragma unroll
    for (int r = 0; r < 4; ++r){
      int rowl = mf * 16 + lg * 4 + r;
      int row = tile + rowl;
      float hres = (row < NN) ? hpre[(size_t)row * 64 + o] : 0.f;
      float rvv = acc[r] + f2b_ + hres;
      racc[mf][r] = rvv;
      float s = rvv, q2 = rvv * rvv;
      s  += __shfl_xor(s, 1);  s  += __shfl_xor(s, 2);  s  += __shfl_xor(s, 4);  s  += __shfl_xor(s, 8);
      q2 += __shfl_xor(q2, 1); q2 += __shfl_xor(q2, 2); q2 += __shfl_xor(q2, 4); q2 += __shfl_xor(q2, 8);
      if (li == 0){ reds[rowl][w] = s; redq[rowl][w] = q2; }
    }
  }
  __syncthreads();
  float g2v = g2[o], b2v = b2[o];
#pragma unroll
  for (int mf = 0; mf < 4; ++mf){
#pragma unroll
    for (int r = 0; r < 4; ++r){
      int rowl = mf * 16 + lg * 4 + r;
      int row = tile + rowl;
      if (row < NN){
        float S  = reds[rowl][0] + reds[rowl][1] + reds[rowl][2] + reds[rowl][3];
        float Qq = redq[rowl][0] + redq[rowl][1] + redq[rowl][2] + redq[rowl][3];
        float mu2 = S * (1.f/64.f);
        float var2 = Qq * (1.f/64.f) - mu2 * mu2;
        float rs2 = rsqrtf(fmaxf(var2, 0.f) + 1e-5f);
        out_h[(size_t)row * 64 + o] = (racc[mf][r] - mu2) * rs2 * g2v + b2v;
      }
    }
  }
}

extern "C" void kernel_launch(void* const* d_in, const int* in_sizes, int n_in,
                              void* d_out, int out_size, void* d_ws, size_t ws_size,
                              hipStream_t stream){
  const float* x       = (const float*)d_in[0];
  const float* e       = (const float*)d_in[1];
  const int*   dst     = (const int*)d_in[2];
  const int*   src     = (const int*)d_in[3];
  const float* qkv_w   = (const float*)d_in[4];
  const float* qkv_b   = (const float*)d_in[5];
  const float* E_w     = (const float*)d_in[6];
  const float* E_b     = (const float*)d_in[7];
  const float* Aw      = (const float*)d_in[8];
  const float* conn1_w = (const float*)d_in[9];
  const float* conn1_b = (const float*)d_in[10];
  const float* conn2_w = (const float*)d_in[11];
  const float* conn2_b = (const float*)d_in[12];
  const float* ffn1_w  = (const float*)d_in[13];
  const float* ffn1_b  = (const float*)d_in[14];
  const float* ffn2_w  = (const float*)d_in[15];
  const float* ffn2_b  = (const float*)d_in[16];
  const float* ln1h_g  = (const float*)d_in[17];
  const float* ln1h_b  = (const float*)d_in[18];
  const float* ln2h_g  = (const float*)d_in[19];
  const float* ln2h_b  = (const float*)d_in[20];
  const float* ln1c_g  = (const float*)d_in[21];
  const float* ln1c_b  = (const float*)d_in[22];
  const float* ln2c_g  = (const float*)d_in[23];
  const float* ln2c_b  = (const float*)d_in[24];

  char* ws = (char*)d_ws;
  size_t off = 0;
  auto alloc = [&](size_t bytes) -> void* {
    void* p = ws + off;
    off += (bytes + 255) & ~(size_t)255;
    return p;
  };
  float* Q     = (float*)alloc((size_t)NN * 64 * 4);
  float* Kq    = (float*)alloc((size_t)NN * 64 * 4);
  float* V     = (float*)alloc((size_t)NN * 64 * 4);
  bf16u* cmb   = (bf16u*)alloc((size_t)NE * 64 * 2);
  float* sexp  = (float*)alloc((size_t)NE * 4 * 4);
  float* hpre  = (float*)alloc((size_t)NN * 64 * 4);
  bf16u* BpE   = (bf16u*)alloc(8192 * 2);
  bf16u* Bp1   = (bf16u*)alloc(4096 * 2);
  bf16u* Bp2   = (bf16u*)alloc(4096 * 2);
  bf16u* BpQ   = (bf16u*)alloc(12288 * 2);
  bf16u* BpF1  = (bf16u*)alloc(8192 * 2);
  bf16u* BpF2  = (bf16u*)alloc(8192 * 2);
  bf16u* BpA   = (bf16u*)alloc(1024 * 2);
  int*   cnt   = (int*)alloc((size_t)NN * 4);
  int*   startp= (int*)alloc(((size_t)NN + 1) * 4);
  int*   cursor= (int*)alloc((size_t)NN * 4);
  int*   eidx  = (int*)alloc((size_t)NE * 4);
  int*   nid   = (int*)alloc((size_t)NE * 4);
  int*   sid   = (int*)alloc((size_t)NE * 4);

  float* out_h    = (float*)d_out;
  float* out_conn = out_h + (size_t)NN * 64;

  hipMemsetAsync(cnt, 0, (size_t)NN * 4, stream);

  k0_pack<<<48, 256, 0, stream>>>(E_w, conn1_w, conn2_w, qkv_w, ffn1_w, ffn2_w, Aw,
                                  BpE, Bp1, Bp2, BpQ, BpF1, BpF2, BpA);
  k_hist<<<NE / 256, 256, 0, stream>>>(dst, cnt);
  k_scan<<<1, SCAN_T, 0, stream>>>(cnt, startp, cursor);
  k_scatter<<<NE / 256, 256, 0, stream>>>(dst, src, cursor, eidx, nid, sid);
  k1_qkv<<<(NN + 63) / 64, 256, 0, stream>>>(x, BpQ, qkv_b, Q, Kq, V);
  k2_edge<<<NE / 64, 256, 0, stream>>>(e, eidx, nid, sid, BpE, E_b, BpA, Bp1, conn1_b,
                                       Q, Kq, ln1c_g, ln1c_b, Bp2, conn2_b,
                                       ln2c_g, ln2c_b, cmb, sexp, out_conn);
  k_agg<<<(NN * 64 + 255) / 256, 256, 0, stream>>>(startp, sid, sexp, cmb, V, x, hpre);
  k5_node<<<(NN + 63) / 64, 256, 0, stream>>>(hpre, ln1h_g, ln1h_b, BpF1, ffn1_b,
                                              BpF2, ffn2_b, ln2h_g, ln2h_b, out_h);
}

// Round 14
// 433.481 us; speedup vs baseline: 1.2593x; 1.0073x over previous
//
#include <hip/hip_runtime.h>
#include <cstdint>

#define NN 50000
#define NE 512000

typedef unsigned short bf16u;
typedef __attribute__((ext_vector_type(8))) short short8v;
typedef __attribute__((ext_vector_type(4))) float f32x4;

__device__ __forceinline__ bf16u f2bf(float f){
  union { float f; unsigned int u; } v; v.f = f;
  unsigned int r = v.u + 0x7FFFu + ((v.u >> 16) & 1u);
  return (bf16u)(r >> 16);
}
__device__ __forceinline__ float bf2f(bf16u s){
  union { unsigned int u; float f; } v; v.u = ((unsigned int)s) << 16;
  return v.f;
}

// ---------- K0: weight packing into MFMA B-fragments ----------
__global__ void k0_pack(const float* __restrict__ E_w, const float* __restrict__ conn1_w,
                        const float* __restrict__ conn2_w, const float* __restrict__ qkv_w,
                        const float* __restrict__ ffn1_w, const float* __restrict__ ffn2_w,
                        const float* __restrict__ Aw,
                        bf16u* __restrict__ BpE, bf16u* __restrict__ Bp1,
                        bf16u* __restrict__ Bp2, bf16u* __restrict__ BpQ,
                        bf16u* __restrict__ BpF1, bf16u* __restrict__ BpF2,
                        bf16u* __restrict__ BpA){
  int i = blockIdx.x * 256 + threadIdx.x;   // 0..12287
  int j = i & 7, l = (i >> 3) & 63;
  int nl = l & 15, kl = (l >> 4) << 3;
  if (i < 8192){   // E_w: (128,64), NF=8, KS=2
    int rest = i >> 9, nf = rest & 7, ks = rest >> 3;
    int n = nf * 16 + nl, k = ks * 32 + kl + j;
    BpE[i] = f2bf(E_w[n * 64 + k]);
  }
  if (i < 4096){   // conn1_w/conn2_w: (64,64), NF=4, KS=2
    int rest = i >> 9, nf = rest & 3, ks = rest >> 2;
    int n = nf * 16 + nl, k = ks * 32 + kl + j;
    Bp1[i] = f2bf(conn1_w[n * 64 + k]);
    Bp2[i] = f2bf(conn2_w[n * 64 + k]);
  }
  if (i < 12288){  // qkv_w: (192,64), NF=12, KS=2
    int rest = i >> 9, nf = rest % 12, ks = rest / 12;
    int n = nf * 16 + nl, k = ks * 32 + kl + j;
    BpQ[i] = f2bf(qkv_w[n * 64 + k]);
  }
  if (i < 8192){   // ffn1_w: (128,64), NF=8, KS=2
    int rest = i >> 9, nf = rest & 7, ks = rest >> 3;
    int n = nf * 16 + nl, k = ks * 32 + kl + j;
    BpF1[i] = f2bf(ffn1_w[n * 64 + k]);
  }
  if (i < 8192){   // ffn2_w: (64,128), NF=4, KS=4
    int rest = i >> 9, nf = rest & 3, ks = rest >> 2;
    int n = nf * 16 + nl, k = ks * 32 + kl + j;
    BpF2[i] = f2bf(ffn2_w[n * 128 + k]);
  }
  if (i < 1024){   // Aw score B-frag: col n<4 = head, B[k][n]=Aw[(k&15)*4+n] iff k>>4==n
    int ks = i >> 9;
    int n = nl, k = ks * 32 + kl + j;
    float v = (n < 4 && (k >> 4) == n) ? Aw[(k & 15) * 4 + n] : 0.f;
    BpA[i] = f2bf(v);
  }
}

// ---------- CSR build ----------
__global__ void k_hist(const int* __restrict__ dst, int* __restrict__ cnt){
  int e = blockIdx.x * 256 + threadIdx.x;
  if (e < NE) atomicAdd(&cnt[dst[e]], 1);
}

#define SCAN_T 1024
#define PER_T 52   // 1024*52 >= NN; 16B-aligned -> int4 loads
__global__ __launch_bounds__(SCAN_T) void k_scan(const int* __restrict__ cnt,
                                                 int* __restrict__ start, int* __restrict__ cursor){
  __shared__ int ls[SCAN_T];
  int t = threadIdx.x;
  int base = t * PER_T;
  int s = 0;
  const int4* cp = (const int4*)(cnt + base);
#pragma unroll
  for (int c = 0; c < 13; ++c){
    int4 v = cp[c];
    int n0 = base + c * 4;
    s += (n0 + 0 < NN ? v.x : 0) + (n0 + 1 < NN ? v.y : 0)
       + (n0 + 2 < NN ? v.z : 0) + (n0 + 3 < NN ? v.w : 0);
  }
  ls[t] = s; __syncthreads();
  for (int off = 1; off < SCAN_T; off <<= 1){
    int v = ls[t];
    int add = (t >= off) ? ls[t - off] : 0;
    __syncthreads();
    ls[t] = v + add;
    __syncthreads();
  }
  int run = (t > 0) ? ls[t - 1] : 0;
  for (int i = 0; i < PER_T; ++i){
    int n = base + i;
    if (n < NN){ start[n] = run; cursor[n] = run; run += cnt[n]; }
  }
  if (t == SCAN_T - 1) start[NN] = run;
}

// packed record per CSR position: {eid, dst_node, src_node, 0}
__global__ void k_scatter(const int* __restrict__ dst, const int* __restrict__ src,
                          int* __restrict__ cursor, int4* __restrict__ pack){
  int e = blockIdx.x * 256 + threadIdx.x;
  if (e < NE){
    int dn = dst[e];
    int p = atomicAdd(&cursor[dn], 1);
    int4 rec; rec.x = e; rec.y = dn; rec.z = src[e]; rec.w = 0;
    pack[p] = rec;
  }
}

// ---------- K1: node QKV — MFMA, split-bf16 A ----------
__global__ __launch_bounds__(256) void k1_qkv(const float* __restrict__ x,
    const bf16u* __restrict__ BpQ, const float* __restrict__ qkv_b,
    float* __restrict__ Q, float* __restrict__ K, float* __restrict__ V){
  int tile = blockIdx.x * 64;
  int w = threadIdx.x >> 6, l = threadIdx.x & 63;
  int lg = l >> 4, li = l & 15;
  const short8v* bpq = (const short8v*)BpQ;
  short8v Bq[3][2];
#pragma unroll
  for (int p = 0; p < 3; ++p)
#pragma unroll
    for (int ks = 0; ks < 2; ++ks)
      Bq[p][ks] = bpq[(ks * 12 + p * 4 + w) * 64 + l];
  f32x4 z = {0.f, 0.f, 0.f, 0.f};
  f32x4 acc[3][4];
#pragma unroll
  for (int p = 0; p < 3; ++p)
#pragma unroll
    for (int mf = 0; mf < 4; ++mf) acc[p][mf] = z;
#pragma unroll
  for (int mf = 0; mf < 4; ++mf){
    int row = tile + mf * 16 + li;
    bool g = row < NN;
    const float* xp = x + (size_t)row * 64 + lg * 8;
#pragma unroll
    for (int ks = 0; ks < 2; ++ks){
      float v[8];
      if (g){
        float4 t0 = *(const float4*)(xp + ks * 32);
        float4 t1 = *(const float4*)(xp + ks * 32 + 4);
        v[0]=t0.x; v[1]=t0.y; v[2]=t0.z; v[3]=t0.w;
        v[4]=t1.x; v[5]=t1.y; v[6]=t1.z; v[7]=t1.w;
      } else {
#pragma unroll
        for (int j = 0; j < 8; ++j) v[j] = 0.f;
      }
      short8v hi, lo;
#pragma unroll
      for (int j = 0; j < 8; ++j){
        bf16u h = f2bf(v[j]);
        hi[j] = (short)h;
        lo[j] = (short)f2bf(v[j] - bf2f(h));
      }
#pragma unroll
      for (int p = 0; p < 3; ++p){
        acc[p][mf] = __builtin_amdgcn_mfma_f32_16x16x32_bf16(hi, Bq[p][ks], acc[p][mf], 0, 0, 0);
        acc[p][mf] = __builtin_amdgcn_mfma_f32_16x16x32_bf16(lo, Bq[p][ks], acc[p][mf], 0, 0, 0);
      }
    }
  }
  float bias[3] = {qkv_b[w*16+li], qkv_b[64+w*16+li], qkv_b[128+w*16+li]};
  float* outs[3] = {Q, K, V};
#pragma unroll
  for (int p = 0; p < 3; ++p)
#pragma unroll
    for (int mf = 0; mf < 4; ++mf)
#pragma unroll
      for (int r = 0; r < 4; ++r){
        int row = tile + mf * 16 + lg * 4 + r;
        if (row < NN) outs[p][(size_t)row * 64 + w * 16 + li] = acc[p][mf][r] + bias[p];
      }
}

// ---------- K2: fused edge kernel — wave-autonomous, 6 waves/SIMD budget ----------
__global__ __launch_bounds__(256, 6) void k2_edge(
    const float* __restrict__ e, const int4* __restrict__ pack,
    const bf16u* __restrict__ BpE, const float* __restrict__ E_b,
    const bf16u* __restrict__ BpA, const bf16u* __restrict__ Bp1, const float* __restrict__ conn1_b,
    const float* __restrict__ Q, const float* __restrict__ K,
    const float* __restrict__ g1c, const float* __restrict__ b1c,
    const bf16u* __restrict__ Bp2, const float* __restrict__ conn2_b,
    const float* __restrict__ g2c, const float* __restrict__ b2c,
    bf16u* __restrict__ cm, float* __restrict__ sexp, float* __restrict__ out_conn){
  __shared__ bf16u ldsT[4 * 16 * 72];     // per-wave 16x72 bf16 transpose buffer
  int t = threadIdx.x;
  int w = t >> 6, l = t & 63;
  int lg = l >> 4, li = l & 15;
  int pos0 = blockIdx.x * 64 + w * 16;
  bf16u* T = &ldsT[w * (16 * 72)];
  f32x4 z = {0.f, 0.f, 0.f, 0.f};

  // --- phase A: Eh MFMA (16 edges x 128 outs, this wave) ---
  short8v afr[2];
  {
    int eidA = pack[pos0 + li].x;
    const float* ep = e + (size_t)eidA * 64 + lg * 8;
#pragma unroll
    for (int ks = 0; ks < 2; ++ks){
      float4 a0 = *(const float4*)(ep + ks * 32);
      float4 a1 = *(const float4*)(ep + ks * 32 + 4);
      short8v af;
      af[0]=(short)f2bf(a0.x); af[1]=(short)f2bf(a0.y); af[2]=(short)f2bf(a0.z); af[3]=(short)f2bf(a0.w);
      af[4]=(short)f2bf(a1.x); af[5]=(short)f2bf(a1.y); af[6]=(short)f2bf(a1.z); af[7]=(short)f2bf(a1.w);
      afr[ks] = af;
    }
  }
  f32x4 accW[4], accB[4];
#pragma unroll
  for (int nf = 0; nf < 4; ++nf){ accW[nf] = z; accB[nf] = z; }
  {
    const short8v* bpe = (const short8v*)BpE;
#pragma unroll
    for (int ks = 0; ks < 2; ++ks){
#pragma unroll
      for (int nf = 0; nf < 4; ++nf){
        short8v BW = bpe[(ks * 8 + nf) * 64 + l];
        short8v BB = bpe[(ks * 8 + 4 + nf) * 64 + l];
        accW[nf] = __builtin_amdgcn_mfma_f32_16x16x32_bf16(afr[ks], BW, accW[nf], 0, 0, 0);
        accB[nf] = __builtin_amdgcn_mfma_f32_16x16x32_bf16(afr[ks], BB, accB[nf], 0, 0, 0);
      }
    }
  }

  // --- pointwise: conn_pre (D-layout: row=lg*4+r, col=nf*16+li) ---
  int dnv[4], snv[4], eidv[4];
#pragma unroll
  for (int r = 0; r < 4; ++r){
    int4 rec = pack[pos0 + lg * 4 + r];
    eidv[r] = rec.x; dnv[r] = rec.y; snv[r] = rec.z;
  }
  float cp[4][4];
#pragma unroll
  for (int nf = 0; nf < 4; ++nf){
    int dim = nf * 16 + li;
    float eb0 = E_b[dim], eb1 = E_b[64 + dim];
#pragma unroll
    for (int r = 0; r < 4; ++r){
      float qv = Q[(size_t)dnv[r] * 64 + dim];
      float kv = K[(size_t)snv[r] * 64 + dim];
      float ew  = accW[nf][r] + eb0;
      float ebv = accB[nf][r] + eb1;
      float c1 = (qv + kv) * ew;
      float c2 = copysignf(sqrtf(fabsf(c1)), c1);
      cp[nf][r] = fmaxf(c2 + ebv, 0.f);
    }
  }

  // --- transpose #1: cp D-layout -> LDS -> A-frags ---
#pragma unroll
  for (int nf = 0; nf < 4; ++nf)
#pragma unroll
    for (int r = 0; r < 4; ++r)
      T[(lg * 4 + r) * 72 + nf * 16 + li] = f2bf(cp[nf][r]);
  __builtin_amdgcn_wave_barrier();
  short8v a1f[2];
  a1f[0] = *(const short8v*)&T[li * 72 + 0 * 32 + lg * 8];
  a1f[1] = *(const short8v*)&T[li * 72 + 1 * 32 + lg * 8];

  // --- score MFMA + exp + store ---
  {
    const short8v* bpa = (const short8v*)BpA;
    f32x4 sacc = z;
    sacc = __builtin_amdgcn_mfma_f32_16x16x32_bf16(a1f[0], bpa[0 * 64 + l], sacc, 0, 0, 0);
    sacc = __builtin_amdgcn_mfma_f32_16x16x32_bf16(a1f[1], bpa[1 * 64 + l], sacc, 0, 0, 0);
    if (li < 4){
#pragma unroll
      for (int r = 0; r < 4; ++r){
        float sc = fminf(fmaxf(sacc[r], -5.f), 5.f);
        sexp[(size_t)(pos0 + lg * 4 + r) * 4 + li] = __expf(sc);
      }
    }
  }

  // --- conn1 MFMA -> cmv (D-layout, f32) ---
  float cmv[4][4];
  {
    const short8v* bp1 = (const short8v*)Bp1;
#pragma unroll
    for (int nf = 0; nf < 4; ++nf){
      f32x4 acc = z;
      acc = __builtin_amdgcn_mfma_f32_16x16x32_bf16(a1f[0], bp1[(0 * 4 + nf) * 64 + l], acc, 0, 0, 0);
      acc = __builtin_amdgcn_mfma_f32_16x16x32_bf16(a1f[1], bp1[(1 * 4 + nf) * 64 + l], acc, 0, 0, 0);
      float c1b = conn1_b[nf * 16 + li];
#pragma unroll
      for (int r = 0; r < 4; ++r){
        float v = acc[r] + c1b;
        cmv[nf][r] = v;
        cm[(size_t)(pos0 + lg * 4 + r) * 64 + nf * 16 + li] = f2bf(v);
      }
    }
  }

  // --- LN1c stats (wave-local) ---
  float mu1r[4], rs1r[4];
#pragma unroll
  for (int r = 0; r < 4; ++r){
    float s = cmv[0][r] + cmv[1][r] + cmv[2][r] + cmv[3][r];
    float q = cmv[0][r]*cmv[0][r] + cmv[1][r]*cmv[1][r] + cmv[2][r]*cmv[2][r] + cmv[3][r]*cmv[3][r];
    s += __shfl_xor(s, 1); s += __shfl_xor(s, 2); s += __shfl_xor(s, 4); s += __shfl_xor(s, 8);
    q += __shfl_xor(q, 1); q += __shfl_xor(q, 2); q += __shfl_xor(q, 4); q += __shfl_xor(q, 8);
    float mu = s * (1.f / 64.f);
    float var = q * (1.f / 64.f) - mu * mu;
    mu1r[r] = mu;
    rs1r[r] = rsqrtf(fmaxf(var, 0.f) + 1e-5f);
  }

  // --- LN1c normalize + relu -> transpose #2 (reuse T) ---
  __builtin_amdgcn_wave_barrier();
#pragma unroll
  for (int nf = 0; nf < 4; ++nf){
    int dim = nf * 16 + li;
    float g1v = g1c[dim], b1v = b1c[dim];
#pragma unroll
    for (int r = 0; r < 4; ++r){
      float cn = fmaxf((cmv[nf][r] - mu1r[r]) * rs1r[r] * g1v + b1v, 0.f);
      T[(lg * 4 + r) * 72 + dim] = f2bf(cn);
    }
  }
  __builtin_amdgcn_wave_barrier();
  short8v a2f[2];
  a2f[0] = *(const short8v*)&T[li * 72 + 0 * 32 + lg * 8];
  a2f[1] = *(const short8v*)&T[li * 72 + 1 * 32 + lg * 8];

  // --- conn2 MFMA + residual -> rv (f32 regs) ---
  float rv[4][4];
  {
    const short8v* bp2 = (const short8v*)Bp2;
#pragma unroll
    for (int nf = 0; nf < 4; ++nf){
      f32x4 acc = z;
      acc = __builtin_amdgcn_mfma_f32_16x16x32_bf16(a2f[0], bp2[(0 * 4 + nf) * 64 + l], acc, 0, 0, 0);
      acc = __builtin_amdgcn_mfma_f32_16x16x32_bf16(a2f[1], bp2[(1 * 4 + nf) * 64 + l], acc, 0, 0, 0);
      int dim = nf * 16 + li;
      float c2b = conn2_b[dim];
#pragma unroll
      for (int r = 0; r < 4; ++r)
        rv[nf][r] = acc[r] + c2b + e[(size_t)eidv[r] * 64 + dim];
    }
  }

  // --- LN2c stats (wave-local) + store out_conn ---
#pragma unroll
  for (int r = 0; r < 4; ++r){
    float s = rv[0][r] + rv[1][r] + rv[2][r] + rv[3][r];
    float q = rv[0][r]*rv[0][r] + rv[1][r]*rv[1][r] + rv[2][r]*rv[2][r] + rv[3][r]*rv[3][r];
    s += __shfl_xor(s, 1); s += __shfl_xor(s, 2); s += __shfl_xor(s, 4); s += __shfl_xor(s, 8);
    q += __shfl_xor(q, 1); q += __shfl_xor(q, 2); q += __shfl_xor(q, 4); q += __shfl_xor(q, 8);
    float mu = s * (1.f / 64.f);
    float var = q * (1.f / 64.f) - mu * mu;
    float rs = rsqrtf(fmaxf(var, 0.f) + 1e-5f);
#pragma unroll
    for (int nf = 0; nf < 4; ++nf){
      int dim = nf * 16 + li;
      out_conn[(size_t)eidv[r] * 64 + dim] = (rv[nf][r] - mu) * rs * g2c[dim] + b2c[dim];
    }
  }
}

// ---------- K_agg: wave per node; 2-way ILP over edge list ----------
__global__ __launch_bounds__(256) void k_agg(
    const int* __restrict__ start, const int4* __restrict__ pack,
    const float* __restrict__ sexp, const bf16u* __restrict__ cm, const float* __restrict__ V,
    const float* __restrict__ x, float* __restrict__ hpre){
  int wid = (blockIdx.x * 256 + threadIdx.x) >> 6;
  int lane = threadIdx.x & 63;
  if (wid >= NN) return;
  int s0 = start[wid], s1 = start[wid + 1];
  int h = lane >> 4;
  float num0 = 0.f, den0 = 0.f, num1 = 0.f, den1 = 0.f;
  int i = s0;
  for (; i + 1 < s1; i += 2){
    float sxa = sexp[(size_t)i * 4 + h];
    float sxb = sexp[(size_t)(i + 1) * 4 + h];
    int sna = pack[i].z, snb = pack[i + 1].z;
    float va = V[(size_t)sna * 64 + lane];
    float vb = V[(size_t)snb * 64 + lane];
    float ca = bf2f(cm[(size_t)i * 64 + lane]);
    float cb = bf2f(cm[(size_t)(i + 1) * 64 + lane]);
    num0 += sxa * (va + ca); den0 += sxa;
    num1 += sxb * (vb + cb); den1 += sxb;
  }
  if (i < s1){
    float sx = sexp[(size_t)i * 4 + h];
    int sn = pack[i].z;
    float v  = V[(size_t)sn * 64 + lane];
    float cc = bf2f(cm[(size_t)i * 64 + lane]);
    num0 += sx * (v + cc); den0 += sx;
  }
  float num = num0 + num1, den = den0 + den1;
  hpre[(size_t)wid * 64 + lane] = x[(size_t)wid * 64 + lane] + num / (den + 1e-16f);
}

// ---------- K5: node final — LN1h + FFN (MFMA) + LN2h ----------
__global__ __launch_bounds__(256) void k5_node(
    const float* __restrict__ hpre,
    const float* __restrict__ g1, const float* __restrict__ b1,
    const bf16u* __restrict__ BpF1, const float* __restrict__ ffn1_b,
    const bf16u* __restrict__ BpF2, const float* __restrict__ ffn2_b,
    const float* __restrict__ g2, const float* __restrict__ b2,
    float* __restrict__ out_h){
  __shared__ bf16u hlhi[64 * 72];
  __shared__ bf16u hllo[64 * 72];
  __shared__ bf16u g1o[64 * 136];
  __shared__ float reds[64][4];
  __shared__ float redq[64][4];
  int tile = blockIdx.x * 64;
  int t = threadIdx.x;
  {
    int el = t >> 2, q = t & 3;
    int row = tile + el;
    bool g = row < NN;
    float v[16];
    if (g){
      const float4* hp = (const float4*)(hpre + (size_t)row * 64 + q * 16);
#pragma unroll
      for (int c = 0; c < 4; ++c){
        float4 tv = hp[c];
        v[c*4+0]=tv.x; v[c*4+1]=tv.y; v[c*4+2]=tv.z; v[c*4+3]=tv.w;
      }
    } else {
#pragma unroll
      for (int i = 0; i < 16; ++i) v[i] = 0.f;
    }
    float s = 0.f, sq = 0.f;
#pragma unroll
    for (int i = 0; i < 16; ++i){ s += v[i]; sq += v[i]*v[i]; }
    s  += __shfl_xor(s, 1);  s  += __shfl_xor(s, 2);
    sq += __shfl_xor(sq, 1); sq += __shfl_xor(sq, 2);
    float mu = s * (1.f/64.f);
    float var = sq * (1.f/64.f) - mu * mu;
    float rs = rsqrtf(fmaxf(var, 0.f) + 1e-5f);
#pragma unroll
    for (int i = 0; i < 16; ++i){
      int d = q * 16 + i;
      float hv = (v[i] - mu) * rs * g1[d] + b1[d];
      bf16u hb = f2bf(hv);
      hlhi[el * 72 + d] = hb;
      hllo[el * 72 + d] = f2bf(hv - bf2f(hb));
    }
  }
  __syncthreads();
  int w = t >> 6, l = t & 63;
  int lg = l >> 4, li = l & 15;
  const short8v* bpf1 = (const short8v*)BpF1;
  short8v B1f[2][2];
#pragma unroll
  for (int f = 0; f < 2; ++f)
#pragma unroll
    for (int ks = 0; ks < 2; ++ks)
      B1f[f][ks] = bpf1[(ks * 8 + f * 4 + w) * 64 + l];
  f32x4 z = {0.f, 0.f, 0.f, 0.f};
  f32x4 acc1[2][4];
#pragma unroll
  for (int f = 0; f < 2; ++f)
#pragma unroll
    for (int mf = 0; mf < 4; ++mf) acc1[f][mf] = z;
#pragma unroll
  for (int mf = 0; mf < 4; ++mf){
#pragma unroll
    for (int ks = 0; ks < 2; ++ks){
      const bf16u* ah = &hlhi[(mf * 16 + li) * 72 + ks * 32 + lg * 8];
      const bf16u* al = &hllo[(mf * 16 + li) * 72 + ks * 32 + lg * 8];
      short8v Ahi = *(const short8v*)ah;
      short8v Alo = *(const short8v*)al;
#pragma unroll
      for (int f = 0; f < 2; ++f){
        acc1[f][mf] = __builtin_amdgcn_mfma_f32_16x16x32_bf16(Ahi, B1f[f][ks], acc1[f][mf], 0, 0, 0);
        acc1[f][mf] = __builtin_amdgcn_mfma_f32_16x16x32_bf16(Alo, B1f[f][ks], acc1[f][mf], 0, 0, 0);
      }
    }
  }
  float fb[2] = {ffn1_b[w*16+li], ffn1_b[64+w*16+li]};
#pragma unroll
  for (int f = 0; f < 2; ++f)
#pragma unroll
    for (int mf = 0; mf < 4; ++mf)
#pragma unroll
      for (int r = 0; r < 4; ++r){
        int rowl = mf * 16 + lg * 4 + r;
        int col = f * 64 + w * 16 + li;
        g1o[rowl * 136 + col] = f2bf(fmaxf(acc1[f][mf][r] + fb[f], 0.f));
      }
  __syncthreads();
  const short8v* bpf2 = (const short8v*)BpF2;
  short8v B2f[4];
#pragma unroll
  for (int ks = 0; ks < 4; ++ks) B2f[ks] = bpf2[(ks * 4 + w) * 64 + l];
  int o = w * 16 + li;
  float f2b_ = ffn2_b[o];
  float racc[4][4];
#pragma unroll
  for (int mf = 0; mf < 4; ++mf){
    f32x4 acc = z;
#pragma unroll
    for (int ks = 0; ks < 4; ++ks){
      short8v A2 = *(const short8v*)&g1o[(mf * 16 + li) * 136 + ks * 32 + lg * 8];
      acc = __builtin_amdgcn_mfma_f32_16x16x32_bf16(A2, B2f[ks], acc, 0, 0, 0);
    }
#pragma unroll
    for (int r = 0; r < 4; ++r){
      int rowl = mf * 16 + lg * 4 + r;
      int row = tile + rowl;
      float hres = (row < NN) ? hpre[(size_t)row * 64 + o] : 0.f;
      float rvv = acc[r] + f2b_ + hres;
      racc[mf][r] = rvv;
      float s = rvv, q2 = rvv * rvv;
      s  += __shfl_xor(s, 1);  s  += __shfl_xor(s, 2);  s  += __shfl_xor(s, 4);  s  += __shfl_xor(s, 8);
      q2 += __shfl_xor(q2, 1); q2 += __shfl_xor(q2, 2); q2 += __shfl_xor(q2, 4); q2 += __shfl_xor(q2, 8);
      if (li == 0){ reds[rowl][w] = s; redq[rowl][w] = q2; }
    }
  }
  __syncthreads();
  float g2v = g2[o], b2v = b2[o];
#pragma unroll
  for (int mf = 0; mf < 4; ++mf){
#pragma unroll
    for (int r = 0; r < 4; ++r){
      int rowl = mf * 16 + lg * 4 + r;
      int row = tile + rowl;
      if (row < NN){
        float S  = reds[rowl][0] + reds[rowl][1] + reds[rowl][2] + reds[rowl][3];
        float Qq = redq[rowl][0] + redq[rowl][1] + redq[rowl][2] + redq[rowl][3];
        float mu2 = S * (1.f/64.f);
        float var2 = Qq * (1.f/64.f) - mu2 * mu2;
        float rs2 = rsqrtf(fmaxf(var2, 0.f) + 1e-5f);
        out_h[(size_t)row * 64 + o] = (racc[mf][r] - mu2) * rs2 * g2v + b2v;
      }
    }
  }
}

extern "C" void kernel_launch(void* const* d_in, const int* in_sizes, int n_in,
                              void* d_out, int out_size, void* d_ws, size_t ws_size,
                              hipStream_t stream){
  const float* x       = (const float*)d_in[0];
  const float* e       = (const float*)d_in[1];
  const int*   dst     = (const int*)d_in[2];
  const int*   src     = (const int*)d_in[3];
  const float* qkv_w   = (const float*)d_in[4];
  const float* qkv_b   = (const float*)d_in[5];
  const float* E_w     = (const float*)d_in[6];
  const float* E_b     = (const float*)d_in[7];
  const float* Aw      = (const float*)d_in[8];
  const float* conn1_w = (const float*)d_in[9];
  const float* conn1_b = (const float*)d_in[10];
  const float* conn2_w = (const float*)d_in[11];
  const float* conn2_b = (const float*)d_in[12];
  const float* ffn1_w  = (const float*)d_in[13];
  const float* ffn1_b  = (const float*)d_in[14];
  const float* ffn2_w  = (const float*)d_in[15];
  const float* ffn2_b  = (const float*)d_in[16];
  const float* ln1h_g  = (const float*)d_in[17];
  const float* ln1h_b  = (const float*)d_in[18];
  const float* ln2h_g  = (const float*)d_in[19];
  const float* ln2h_b  = (const float*)d_in[20];
  const float* ln1c_g  = (const float*)d_in[21];
  const float* ln1c_b  = (const float*)d_in[22];
  const float* ln2c_g  = (const float*)d_in[23];
  const float* ln2c_b  = (const float*)d_in[24];

  char* ws = (char*)d_ws;
  size_t off = 0;
  auto alloc = [&](size_t bytes) -> void* {
    void* p = ws + off;
    off += (bytes + 255) & ~(size_t)255;
    return p;
  };
  float* Q     = (float*)alloc((size_t)NN * 64 * 4);
  float* Kq    = (float*)alloc((size_t)NN * 64 * 4);
  float* V     = (float*)alloc((size_t)NN * 64 * 4);
  bf16u* cmb   = (bf16u*)alloc((size_t)NE * 64 * 2);
  float* sexp  = (float*)alloc((size_t)NE * 4 * 4);
  float* hpre  = (float*)alloc((size_t)NN * 64 * 4);
  bf16u* BpE   = (bf16u*)alloc(8192 * 2);
  bf16u* Bp1   = (bf16u*)alloc(4096 * 2);
  bf16u* Bp2   = (bf16u*)alloc(4096 * 2);
  bf16u* BpQ   = (bf16u*)alloc(12288 * 2);
  bf16u* BpF1  = (bf16u*)alloc(8192 * 2);
  bf16u* BpF2  = (bf16u*)alloc(8192 * 2);
  bf16u* BpA   = (bf16u*)alloc(1024 * 2);
  int*   cnt   = (int*)alloc((size_t)NN * 4);
  int*   startp= (int*)alloc(((size_t)NN + 1) * 4);
  int*   cursor= (int*)alloc((size_t)NN * 4);
  int4*  pack  = (int4*)alloc((size_t)NE * 16);

  float* out_h    = (float*)d_out;
  float* out_conn = out_h + (size_t)NN * 64;

  hipMemsetAsync(cnt, 0, (size_t)NN * 4, stream);

  k0_pack<<<48, 256, 0, stream>>>(E_w, conn1_w, conn2_w, qkv_w, ffn1_w, ffn2_w, Aw,
                                  BpE, Bp1, Bp2, BpQ, BpF1, BpF2, BpA);
  k_hist<<<NE / 256, 256, 0, stream>>>(dst, cnt);
  k_scan<<<1, SCAN_T, 0, stream>>>(cnt, startp, cursor);
  k_scatter<<<NE / 256, 256, 0, stream>>>(dst, src, cursor, pack);
  k1_qkv<<<(NN + 63) / 64, 256, 0, stream>>>(x, BpQ, qkv_b, Q, Kq, V);
  k2_edge<<<NE / 64, 256, 0, stream>>>(e, pack, BpE, E_b, BpA, Bp1, conn1_b,
                                       Q, Kq, ln1c_g, ln1c_b, Bp2, conn2_b,
                                       ln2c_g, ln2c_b, cmb, sexp, out_conn);
  k_agg<<<(NN * 64 + 255) / 256, 256, 0, stream>>>(startp, pack, sexp, cmb, V, x, hpre);
  k5_node<<<(NN + 63) / 64, 256, 0, stream>>>(hpre, ln1h_g, ln1h_b, BpF1, ffn1_b,
                                              BpF2, ffn2_b, ln2h_g, ln2h_b, out_h);
}

// Round 15
// 403.414 us; speedup vs baseline: 1.3531x; 1.0745x over previous
//
#include <hip/hip_runtime.h>
#include <cstdint>

#define NN 50000
#define NE 512000

typedef unsigned short bf16u;
typedef __attribute__((ext_vector_type(8))) short short8v;
typedef __attribute__((ext_vector_type(4))) float f32x4;

__device__ __forceinline__ bf16u f2bf(float f){
  union { float f; unsigned int u; } v; v.f = f;
  unsigned int r = v.u + 0x7FFFu + ((v.u >> 16) & 1u);
  return (bf16u)(r >> 16);
}
__device__ __forceinline__ float bf2f(bf16u s){
  union { unsigned int u; float f; } v; v.u = ((unsigned int)s) << 16;
  return v.f;
}

// ---------- K0: weight packing into MFMA B-fragments ----------
__global__ void k0_pack(const float* __restrict__ E_w, const float* __restrict__ conn1_w,
                        const float* __restrict__ conn2_w, const float* __restrict__ qkv_w,
                        const float* __restrict__ ffn1_w, const float* __restrict__ ffn2_w,
                        const float* __restrict__ Aw,
                        bf16u* __restrict__ BpE, bf16u* __restrict__ Bp1,
                        bf16u* __restrict__ Bp2, bf16u* __restrict__ BpQ,
                        bf16u* __restrict__ BpF1, bf16u* __restrict__ BpF2,
                        bf16u* __restrict__ BpA){
  int i = blockIdx.x * 256 + threadIdx.x;   // 0..12287
  int j = i & 7, l = (i >> 3) & 63;
  int nl = l & 15, kl = (l >> 4) << 3;
  if (i < 8192){   // E_w: (128,64), NF=8, KS=2
    int rest = i >> 9, nf = rest & 7, ks = rest >> 3;
    int n = nf * 16 + nl, k = ks * 32 + kl + j;
    BpE[i] = f2bf(E_w[n * 64 + k]);
  }
  if (i < 4096){   // conn1_w/conn2_w: (64,64), NF=4, KS=2
    int rest = i >> 9, nf = rest & 3, ks = rest >> 2;
    int n = nf * 16 + nl, k = ks * 32 + kl + j;
    Bp1[i] = f2bf(conn1_w[n * 64 + k]);
    Bp2[i] = f2bf(conn2_w[n * 64 + k]);
  }
  if (i < 12288){  // qkv_w: (192,64), NF=12, KS=2
    int rest = i >> 9, nf = rest % 12, ks = rest / 12;
    int n = nf * 16 + nl, k = ks * 32 + kl + j;
    BpQ[i] = f2bf(qkv_w[n * 64 + k]);
  }
  if (i < 8192){   // ffn1_w: (128,64), NF=8, KS=2
    int rest = i >> 9, nf = rest & 7, ks = rest >> 3;
    int n = nf * 16 + nl, k = ks * 32 + kl + j;
    BpF1[i] = f2bf(ffn1_w[n * 64 + k]);
  }
  if (i < 8192){   // ffn2_w: (64,128), NF=4, KS=4
    int rest = i >> 9, nf = rest & 3, ks = rest >> 2;
    int n = nf * 16 + nl, k = ks * 32 + kl + j;
    BpF2[i] = f2bf(ffn2_w[n * 128 + k]);
  }
  if (i < 1024){   // Aw score B-frag: col n<4 = head, B[k][n]=Aw[(k&15)*4+n] iff k>>4==n
    int ks = i >> 9;
    int n = nl, k = ks * 32 + kl + j;
    float v = (n < 4 && (k >> 4) == n) ? Aw[(k & 15) * 4 + n] : 0.f;
    BpA[i] = f2bf(v);
  }
}

// ---------- CSR build ----------
__global__ void k_hist(const int* __restrict__ dst, int* __restrict__ cnt){
  int e = blockIdx.x * 256 + threadIdx.x;
  if (e < NE) atomicAdd(&cnt[dst[e]], 1);
}

#define SCAN_T 1024
#define PER_T 52   // 1024*52 >= NN; 16B-aligned -> int4 loads
__global__ __launch_bounds__(SCAN_T) void k_scan(const int* __restrict__ cnt,
                                                 int* __restrict__ start, int* __restrict__ cursor){
  __shared__ int ls[SCAN_T];
  int t = threadIdx.x;
  int base = t * PER_T;
  int s = 0;
  const int4* cp = (const int4*)(cnt + base);
#pragma unroll
  for (int c = 0; c < 13; ++c){
    int4 v = cp[c];
    int n0 = base + c * 4;
    s += (n0 + 0 < NN ? v.x : 0) + (n0 + 1 < NN ? v.y : 0)
       + (n0 + 2 < NN ? v.z : 0) + (n0 + 3 < NN ? v.w : 0);
  }
  ls[t] = s; __syncthreads();
  for (int off = 1; off < SCAN_T; off <<= 1){
    int v = ls[t];
    int add = (t >= off) ? ls[t - off] : 0;
    __syncthreads();
    ls[t] = v + add;
    __syncthreads();
  }
  int run = (t > 0) ? ls[t - 1] : 0;
  for (int i = 0; i < PER_T; ++i){
    int n = base + i;
    if (n < NN){ start[n] = run; cursor[n] = run; run += cnt[n]; }
  }
  if (t == SCAN_T - 1) start[NN] = run;
}

// packed record per CSR position: {eid, dst_node, src_node, 0}
__global__ void k_scatter(const int* __restrict__ dst, const int* __restrict__ src,
                          int* __restrict__ cursor, int4* __restrict__ pack){
  int e = blockIdx.x * 256 + threadIdx.x;
  if (e < NE){
    int dn = dst[e];
    int p = atomicAdd(&cursor[dn], 1);
    int4 rec; rec.x = e; rec.y = dn; rec.z = src[e]; rec.w = 0;
    pack[p] = rec;
  }
}

// ---------- K1: node QKV — MFMA, split-bf16 A ----------
__global__ __launch_bounds__(256) void k1_qkv(const float* __restrict__ x,
    const bf16u* __restrict__ BpQ, const float* __restrict__ qkv_b,
    float* __restrict__ Q, float* __restrict__ K, float* __restrict__ V){
  int tile = blockIdx.x * 64;
  int w = threadIdx.x >> 6, l = threadIdx.x & 63;
  int lg = l >> 4, li = l & 15;
  const short8v* bpq = (const short8v*)BpQ;
  short8v Bq[3][2];
#pragma unroll
  for (int p = 0; p < 3; ++p)
#pragma unroll
    for (int ks = 0; ks < 2; ++ks)
      Bq[p][ks] = bpq[(ks * 12 + p * 4 + w) * 64 + l];
  f32x4 z = {0.f, 0.f, 0.f, 0.f};
  f32x4 acc[3][4];
#pragma unroll
  for (int p = 0; p < 3; ++p)
#pragma unroll
    for (int mf = 0; mf < 4; ++mf) acc[p][mf] = z;
#pragma unroll
  for (int mf = 0; mf < 4; ++mf){
    int row = tile + mf * 16 + li;
    bool g = row < NN;
    const float* xp = x + (size_t)row * 64 + lg * 8;
#pragma unroll
    for (int ks = 0; ks < 2; ++ks){
      float v[8];
      if (g){
        float4 t0 = *(const float4*)(xp + ks * 32);
        float4 t1 = *(const float4*)(xp + ks * 32 + 4);
        v[0]=t0.x; v[1]=t0.y; v[2]=t0.z; v[3]=t0.w;
        v[4]=t1.x; v[5]=t1.y; v[6]=t1.z; v[7]=t1.w;
      } else {
#pragma unroll
        for (int j = 0; j < 8; ++j) v[j] = 0.f;
      }
      short8v hi, lo;
#pragma unroll
      for (int j = 0; j < 8; ++j){
        bf16u h = f2bf(v[j]);
        hi[j] = (short)h;
        lo[j] = (short)f2bf(v[j] - bf2f(h));
      }
#pragma unroll
      for (int p = 0; p < 3; ++p){
        acc[p][mf] = __builtin_amdgcn_mfma_f32_16x16x32_bf16(hi, Bq[p][ks], acc[p][mf], 0, 0, 0);
        acc[p][mf] = __builtin_amdgcn_mfma_f32_16x16x32_bf16(lo, Bq[p][ks], acc[p][mf], 0, 0, 0);
      }
    }
  }
  float bias[3] = {qkv_b[w*16+li], qkv_b[64+w*16+li], qkv_b[128+w*16+li]};
  float* outs[3] = {Q, K, V};
#pragma unroll
  for (int p = 0; p < 3; ++p)
#pragma unroll
    for (int mf = 0; mf < 4; ++mf)
#pragma unroll
      for (int r = 0; r < 4; ++r){
        int row = tile + mf * 16 + lg * 4 + r;
        if (row < NN) outs[p][(size_t)row * 64 + w * 16 + li] = acc[p][mf][r] + bias[p];
      }
}

// ---------- K2: fused edge kernel — wave-autonomous, 5 waves/SIMD budget ----------
__global__ __launch_bounds__(256, 5) void k2_edge(
    const float* __restrict__ e, const int4* __restrict__ pack,
    const bf16u* __restrict__ BpE, const float* __restrict__ E_b,
    const bf16u* __restrict__ BpA, const bf16u* __restrict__ Bp1, const float* __restrict__ conn1_b,
    const float* __restrict__ Q, const float* __restrict__ K,
    const float* __restrict__ g1c, const float* __restrict__ b1c,
    const bf16u* __restrict__ Bp2, const float* __restrict__ conn2_b,
    const float* __restrict__ g2c, const float* __restrict__ b2c,
    bf16u* __restrict__ cm, float* __restrict__ sexp, float* __restrict__ out_conn){
  __shared__ bf16u ldsT[4 * 16 * 72];     // per-wave 16x72 bf16 transpose buffer
  int t = threadIdx.x;
  int w = t >> 6, l = t & 63;
  int lg = l >> 4, li = l & 15;
  int pos0 = blockIdx.x * 64 + w * 16;
  bf16u* T = &ldsT[w * (16 * 72)];
  f32x4 z = {0.f, 0.f, 0.f, 0.f};

  // --- phase A: Eh MFMA (16 edges x 128 outs, this wave) ---
  short8v afr[2];
  {
    int eidA = pack[pos0 + li].x;
    const float* ep = e + (size_t)eidA * 64 + lg * 8;
#pragma unroll
    for (int ks = 0; ks < 2; ++ks){
      float4 a0 = *(const float4*)(ep + ks * 32);
      float4 a1 = *(const float4*)(ep + ks * 32 + 4);
      short8v af;
      af[0]=(short)f2bf(a0.x); af[1]=(short)f2bf(a0.y); af[2]=(short)f2bf(a0.z); af[3]=(short)f2bf(a0.w);
      af[4]=(short)f2bf(a1.x); af[5]=(short)f2bf(a1.y); af[6]=(short)f2bf(a1.z); af[7]=(short)f2bf(a1.w);
      afr[ks] = af;
    }
  }
  f32x4 accW[4], accB[4];
#pragma unroll
  for (int nf = 0; nf < 4; ++nf){ accW[nf] = z; accB[nf] = z; }
  {
    const short8v* bpe = (const short8v*)BpE;
#pragma unroll
    for (int ks = 0; ks < 2; ++ks){
#pragma unroll
      for (int nf = 0; nf < 4; ++nf){
        short8v BW = bpe[(ks * 8 + nf) * 64 + l];
        short8v BB = bpe[(ks * 8 + 4 + nf) * 64 + l];
        accW[nf] = __builtin_amdgcn_mfma_f32_16x16x32_bf16(afr[ks], BW, accW[nf], 0, 0, 0);
        accB[nf] = __builtin_amdgcn_mfma_f32_16x16x32_bf16(afr[ks], BB, accB[nf], 0, 0, 0);
      }
    }
  }

  // --- pointwise: conn_pre (D-layout: row=lg*4+r, col=nf*16+li) ---
  int dnv[4], snv[4], eidv[4];
#pragma unroll
  for (int r = 0; r < 4; ++r){
    int4 rec = pack[pos0 + lg * 4 + r];
    eidv[r] = rec.x; dnv[r] = rec.y; snv[r] = rec.z;
  }
  float cp[4][4];
#pragma unroll
  for (int nf = 0; nf < 4; ++nf){
    int dim = nf * 16 + li;
    float eb0 = E_b[dim], eb1 = E_b[64 + dim];
#pragma unroll
    for (int r = 0; r < 4; ++r){
      float qv = Q[(size_t)dnv[r] * 64 + dim];
      float kv = K[(size_t)snv[r] * 64 + dim];
      float ew  = accW[nf][r] + eb0;
      float ebv = accB[nf][r] + eb1;
      float c1 = (qv + kv) * ew;
      float c2 = copysignf(sqrtf(fabsf(c1)), c1);
      cp[nf][r] = fmaxf(c2 + ebv, 0.f);
    }
  }

  // --- transpose #1: cp D-layout -> LDS -> A-frags ---
#pragma unroll
  for (int nf = 0; nf < 4; ++nf)
#pragma unroll
    for (int r = 0; r < 4; ++r)
      T[(lg * 4 + r) * 72 + nf * 16 + li] = f2bf(cp[nf][r]);
  __builtin_amdgcn_wave_barrier();
  short8v a1f[2];
  a1f[0] = *(const short8v*)&T[li * 72 + 0 * 32 + lg * 8];
  a1f[1] = *(const short8v*)&T[li * 72 + 1 * 32 + lg * 8];

  // --- score MFMA + exp + store ---
  {
    const short8v* bpa = (const short8v*)BpA;
    f32x4 sacc = z;
    sacc = __builtin_amdgcn_mfma_f32_16x16x32_bf16(a1f[0], bpa[0 * 64 + l], sacc, 0, 0, 0);
    sacc = __builtin_amdgcn_mfma_f32_16x16x32_bf16(a1f[1], bpa[1 * 64 + l], sacc, 0, 0, 0);
    if (li < 4){
#pragma unroll
      for (int r = 0; r < 4; ++r){
        float sc = fminf(fmaxf(sacc[r], -5.f), 5.f);
        sexp[(size_t)(pos0 + lg * 4 + r) * 4 + li] = __expf(sc);
      }
    }
  }

  // --- conn1 MFMA -> cmv (D-layout, f32) ---
  float cmv[4][4];
  {
    const short8v* bp1 = (const short8v*)Bp1;
#pragma unroll
    for (int nf = 0; nf < 4; ++nf){
      f32x4 acc = z;
      acc = __builtin_amdgcn_mfma_f32_16x16x32_bf16(a1f[0], bp1[(0 * 4 + nf) * 64 + l], acc, 0, 0, 0);
      acc = __builtin_amdgcn_mfma_f32_16x16x32_bf16(a1f[1], bp1[(1 * 4 + nf) * 64 + l], acc, 0, 0, 0);
      float c1b = conn1_b[nf * 16 + li];
#pragma unroll
      for (int r = 0; r < 4; ++r){
        float v = acc[r] + c1b;
        cmv[nf][r] = v;
        cm[(size_t)(pos0 + lg * 4 + r) * 64 + nf * 16 + li] = f2bf(v);
      }
    }
  }

  // --- LN1c stats (wave-local) ---
  float mu1r[4], rs1r[4];
#pragma unroll
  for (int r = 0; r < 4; ++r){
    float s = cmv[0][r] + cmv[1][r] + cmv[2][r] + cmv[3][r];
    float q = cmv[0][r]*cmv[0][r] + cmv[1][r]*cmv[1][r] + cmv[2][r]*cmv[2][r] + cmv[3][r]*cmv[3][r];
    s += __shfl_xor(s, 1); s += __shfl_xor(s, 2); s += __shfl_xor(s, 4); s += __shfl_xor(s, 8);
    q += __shfl_xor(q, 1); q += __shfl_xor(q, 2); q += __shfl_xor(q, 4); q += __shfl_xor(q, 8);
    float mu = s * (1.f / 64.f);
    float var = q * (1.f / 64.f) - mu * mu;
    mu1r[r] = mu;
    rs1r[r] = rsqrtf(fmaxf(var, 0.f) + 1e-5f);
  }

  // --- LN1c normalize + relu -> transpose #2 (reuse T) ---
  __builtin_amdgcn_wave_barrier();
#pragma unroll
  for (int nf = 0; nf < 4; ++nf){
    int dim = nf * 16 + li;
    float g1v = g1c[dim], b1v = b1c[dim];
#pragma unroll
    for (int r = 0; r < 4; ++r){
      float cn = fmaxf((cmv[nf][r] - mu1r[r]) * rs1r[r] * g1v + b1v, 0.f);
      T[(lg * 4 + r) * 72 + dim] = f2bf(cn);
    }
  }
  __builtin_amdgcn_wave_barrier();
  short8v a2f[2];
  a2f[0] = *(const short8v*)&T[li * 72 + 0 * 32 + lg * 8];
  a2f[1] = *(const short8v*)&T[li * 72 + 1 * 32 + lg * 8];

  // --- conn2 MFMA + residual -> rv (f32 regs) ---
  float rv[4][4];
  {
    const short8v* bp2 = (const short8v*)Bp2;
#pragma unroll
    for (int nf = 0; nf < 4; ++nf){
      f32x4 acc = z;
      acc = __builtin_amdgcn_mfma_f32_16x16x32_bf16(a2f[0], bp2[(0 * 4 + nf) * 64 + l], acc, 0, 0, 0);
      acc = __builtin_amdgcn_mfma_f32_16x16x32_bf16(a2f[1], bp2[(1 * 4 + nf) * 64 + l], acc, 0, 0, 0);
      int dim = nf * 16 + li;
      float c2b = conn2_b[dim];
#pragma unroll
      for (int r = 0; r < 4; ++r)
        rv[nf][r] = acc[r] + c2b + e[(size_t)eidv[r] * 64 + dim];
    }
  }

  // --- LN2c stats (wave-local) + store out_conn ---
#pragma unroll
  for (int r = 0; r < 4; ++r){
    float s = rv[0][r] + rv[1][r] + rv[2][r] + rv[3][r];
    float q = rv[0][r]*rv[0][r] + rv[1][r]*rv[1][r] + rv[2][r]*rv[2][r] + rv[3][r]*rv[3][r];
    s += __shfl_xor(s, 1); s += __shfl_xor(s, 2); s += __shfl_xor(s, 4); s += __shfl_xor(s, 8);
    q += __shfl_xor(q, 1); q += __shfl_xor(q, 2); q += __shfl_xor(q, 4); q += __shfl_xor(q, 8);
    float mu = s * (1.f / 64.f);
    float var = q * (1.f / 64.f) - mu * mu;
    float rs = rsqrtf(fmaxf(var, 0.f) + 1e-5f);
#pragma unroll
    for (int nf = 0; nf < 4; ++nf){
      int dim = nf * 16 + li;
      out_conn[(size_t)eidv[r] * 64 + dim] = (rv[nf][r] - mu) * rs * g2c[dim] + b2c[dim];
    }
  }
}

// ---------- K_agg: wave per node; 2-way ILP over edge list ----------
__global__ __launch_bounds__(256) void k_agg(
    const int* __restrict__ start, const int4* __restrict__ pack,
    const float* __restrict__ sexp, const bf16u* __restrict__ cm, const float* __restrict__ V,
    const float* __restrict__ x, float* __restrict__ hpre){
  int wid = (blockIdx.x * 256 + threadIdx.x) >> 6;
  int lane = threadIdx.x & 63;
  if (wid >= NN) return;
  int s0 = start[wid], s1 = start[wid + 1];
  int h = lane >> 4;
  float num0 = 0.f, den0 = 0.f, num1 = 0.f, den1 = 0.f;
  int i = s0;
  for (; i + 1 < s1; i += 2){
    float sxa = sexp[(size_t)i * 4 + h];
    float sxb = sexp[(size_t)(i + 1) * 4 + h];
    int sna = pack[i].z, snb = pack[i + 1].z;
    float va = V[(size_t)sna * 64 + lane];
    float vb = V[(size_t)snb * 64 + lane];
    float ca = bf2f(cm[(size_t)i * 64 + lane]);
    float cb = bf2f(cm[(size_t)(i + 1) * 64 + lane]);
    num0 += sxa * (va + ca); den0 += sxa;
    num1 += sxb * (vb + cb); den1 += sxb;
  }
  if (i < s1){
    float sx = sexp[(size_t)i * 4 + h];
    int sn = pack[i].z;
    float v  = V[(size_t)sn * 64 + lane];
    float cc = bf2f(cm[(size_t)i * 64 + lane]);
    num0 += sx * (v + cc); den0 += sx;
  }
  float num = num0 + num1, den = den0 + den1;
  hpre[(size_t)wid * 64 + lane] = x[(size_t)wid * 64 + lane] + num / (den + 1e-16f);
}

// ---------- K5: node final — LN1h + FFN (MFMA) + LN2h ----------
__global__ __launch_bounds__(256) void k5_node(
    const float* __restrict__ hpre,
    const float* __restrict__ g1, const float* __restrict__ b1,
    const bf16u* __restrict__ BpF1, const float* __restrict__ ffn1_b,
    const bf16u* __restrict__ BpF2, const float* __restrict__ ffn2_b,
    const float* __restrict__ g2, const float* __restrict__ b2,
    float* __restrict__ out_h){
  __shared__ bf16u hlhi[64 * 72];
  __shared__ bf16u hllo[64 * 72];
  __shared__ bf16u g1o[64 * 136];
  __shared__ float reds[64][4];
  __shared__ float redq[64][4];
  int tile = blockIdx.x * 64;
  int t = threadIdx.x;
  {
    int el = t >> 2, q = t & 3;
    int row = tile + el;
    bool g = row < NN;
    float v[16];
    if (g){
      const float4* hp = (const float4*)(hpre + (size_t)row * 64 + q * 16);
#pragma unroll
      for (int c = 0; c < 4; ++c){
        float4 tv = hp[c];
        v[c*4+0]=tv.x; v[c*4+1]=tv.y; v[c*4+2]=tv.z; v[c*4+3]=tv.w;
      }
    } else {
#pragma unroll
      for (int i = 0; i < 16; ++i) v[i] = 0.f;
    }
    float s = 0.f, sq = 0.f;
#pragma unroll
    for (int i = 0; i < 16; ++i){ s += v[i]; sq += v[i]*v[i]; }
    s  += __shfl_xor(s, 1);  s  += __shfl_xor(s, 2);
    sq += __shfl_xor(sq, 1); sq += __shfl_xor(sq, 2);
    float mu = s * (1.f/64.f);
    float var = sq * (1.f/64.f) - mu * mu;
    float rs = rsqrtf(fmaxf(var, 0.f) + 1e-5f);
#pragma unroll
    for (int i = 0; i < 16; ++i){
      int d = q * 16 + i;
      float hv = (v[i] - mu) * rs * g1[d] + b1[d];
      bf16u hb = f2bf(hv);
      hlhi[el * 72 + d] = hb;
      hllo[el * 72 + d] = f2bf(hv - bf2f(hb));
    }
  }
  __syncthreads();
  int w = t >> 6, l = t & 63;
  int lg = l >> 4, li = l & 15;
  const short8v* bpf1 = (const short8v*)BpF1;
  short8v B1f[2][2];
#pragma unroll
  for (int f = 0; f < 2; ++f)
#pragma unroll
    for (int ks = 0; ks < 2; ++ks)
      B1f[f][ks] = bpf1[(ks * 8 + f * 4 + w) * 64 + l];
  f32x4 z = {0.f, 0.f, 0.f, 0.f};
  f32x4 acc1[2][4];
#pragma unroll
  for (int f = 0; f < 2; ++f)
#pragma unroll
    for (int mf = 0; mf < 4; ++mf) acc1[f][mf] = z;
#pragma unroll
  for (int mf = 0; mf < 4; ++mf){
#pragma unroll
    for (int ks = 0; ks < 2; ++ks){
      const bf16u* ah = &hlhi[(mf * 16 + li) * 72 + ks * 32 + lg * 8];
      const bf16u* al = &hllo[(mf * 16 + li) * 72 + ks * 32 + lg * 8];
      short8v Ahi = *(const short8v*)ah;
      short8v Alo = *(const short8v*)al;
#pragma unroll
      for (int f = 0; f < 2; ++f){
        acc1[f][mf] = __builtin_amdgcn_mfma_f32_16x16x32_bf16(Ahi, B1f[f][ks], acc1[f][mf], 0, 0, 0);
        acc1[f][mf] = __builtin_amdgcn_mfma_f32_16x16x32_bf16(Alo, B1f[f][ks], acc1[f][mf], 0, 0, 0);
      }
    }
  }
  float fb[2] = {ffn1_b[w*16+li], ffn1_b[64+w*16+li]};
#pragma unroll
  for (int f = 0; f < 2; ++f)
#pragma unroll
    for (int mf = 0; mf < 4; ++mf)
#pragma unroll
      for (int r = 0; r < 4; ++r){
        int rowl = mf * 16 + lg * 4 + r;
        int col = f * 64 + w * 16 + li;
        g1o[rowl * 136 + col] = f2bf(fmaxf(acc1[f][mf][r] + fb[f], 0.f));
      }
  __syncthreads();
  const short8v* bpf2 = (const short8v*)BpF2;
  short8v B2f[4];
#pragma unroll
  for (int ks = 0; ks < 4; ++ks) B2f[ks] = bpf2[(ks * 4 + w) * 64 + l];
  int o = w * 16 + li;
  float f2b_ = ffn2_b[o];
  float racc[4][4];
#pragma unroll
  for (int mf = 0; mf < 4; ++mf){
    f32x4 acc = z;
#pragma unroll
    for (int ks = 0; ks < 4; ++ks){
      short8v A2 = *(const short8v*)&g1o[(mf * 16 + li) * 136 + ks * 32 + lg * 8];
      acc = __builtin_amdgcn_mfma_f32_16x16x32_bf16(A2, B2f[ks], acc, 0, 0, 0);
    }
#pragma unroll
    for (int r = 0; r < 4; ++r){
      int rowl = mf * 16 + lg * 4 + r;
      int row = tile + rowl;
      float hres = (row < NN) ? hpre[(size_t)row * 64 + o] : 0.f;
      float rvv = acc[r] + f2b_ + hres;
      racc[mf][r] = rvv;
      float s = rvv, q2 = rvv * rvv;
      s  += __shfl_xor(s, 1);  s  += __shfl_xor(s, 2);  s  += __shfl_xor(s, 4);  s  += __shfl_xor(s, 8);
      q2 += __shfl_xor(q2, 1); q2 += __shfl_xor(q2, 2); q2 += __shfl_xor(q2, 4); q2 += __shfl_xor(q2, 8);
      if (li == 0){ reds[rowl][w] = s; redq[rowl][w] = q2; }
    }
  }
  __syncthreads();
  float g2v = g2[o], b2v = b2[o];
#pragma unroll
  for (int mf = 0; mf < 4; ++mf){
#pragma unroll
    for (int r = 0; r < 4; ++r){
      int rowl = mf * 16 + lg * 4 + r;
      int row = tile + rowl;
      if (row < NN){
        float S  = reds[rowl][0] + reds[rowl][1] + reds[rowl][2] + reds[rowl][3];
        float Qq = redq[rowl][0] + redq[rowl][1] + redq[rowl][2] + redq[rowl][3];
        float mu2 = S * (1.f/64.f);
        float var2 = Qq * (1.f/64.f) - mu2 * mu2;
        float rs2 = rsqrtf(fmaxf(var2, 0.f) + 1e-5f);
        out_h[(size_t)row * 64 + o] = (racc[mf][r] - mu2) * rs2 * g2v + b2v;
      }
    }
  }
}

extern "C" void kernel_launch(void* const* d_in, const int* in_sizes, int n_in,
                              void* d_out, int out_size, void* d_ws, size_t ws_size,
                              hipStream_t stream){
  const float* x       = (const float*)d_in[0];
  const float* e       = (const float*)d_in[1];
  const int*   dst     = (const int*)d_in[2];
  const int*   src     = (const int*)d_in[3];
  const float* qkv_w   = (const float*)d_in[4];
  const float* qkv_b   = (const float*)d_in[5];
  const float* E_w     = (const float*)d_in[6];
  const float* E_b     = (const float*)d_in[7];
  const float* Aw      = (const float*)d_in[8];
  const float* conn1_w = (const float*)d_in[9];
  const float* conn1_b = (const float*)d_in[10];
  const float* conn2_w = (const float*)d_in[11];
  const float* conn2_b = (const float*)d_in[12];
  const float* ffn1_w  = (const float*)d_in[13];
  const float* ffn1_b  = (const float*)d_in[14];
  const float* ffn2_w  = (const float*)d_in[15];
  const float* ffn2_b  = (const float*)d_in[16];
  const float* ln1h_g  = (const float*)d_in[17];
  const float* ln1h_b  = (const float*)d_in[18];
  const float* ln2h_g  = (const float*)d_in[19];
  const float* ln2h_b  = (const float*)d_in[20];
  const float* ln1c_g  = (const float*)d_in[21];
  const float* ln1c_b  = (const float*)d_in[22];
  const float* ln2c_g  = (const float*)d_in[23];
  const float* ln2c_b  = (const float*)d_in[24];

  char* ws = (char*)d_ws;
  size_t off = 0;
  auto alloc = [&](size_t bytes) -> void* {
    void* p = ws + off;
    off += (bytes + 255) & ~(size_t)255;
    return p;
  };
  float* Q     = (float*)alloc((size_t)NN * 64 * 4);
  float* Kq    = (float*)alloc((size_t)NN * 64 * 4);
  float* V     = (float*)alloc((size_t)NN * 64 * 4);
  bf16u* cmb   = (bf16u*)alloc((size_t)NE * 64 * 2);
  float* sexp  = (float*)alloc((size_t)NE * 4 * 4);
  float* hpre  = (float*)alloc((size_t)NN * 64 * 4);
  bf16u* BpE   = (bf16u*)alloc(8192 * 2);
  bf16u* Bp1   = (bf16u*)alloc(4096 * 2);
  bf16u* Bp2   = (bf16u*)alloc(4096 * 2);
  bf16u* BpQ   = (bf16u*)alloc(12288 * 2);
  bf16u* BpF1  = (bf16u*)alloc(8192 * 2);
  bf16u* BpF2  = (bf16u*)alloc(8192 * 2);
  bf16u* BpA   = (bf16u*)alloc(1024 * 2);
  int*   cnt   = (int*)alloc((size_t)NN * 4);
  int*   startp= (int*)alloc(((size_t)NN + 1) * 4);
  int*   cursor= (int*)alloc((size_t)NN * 4);
  int4*  pack  = (int4*)alloc((size_t)NE * 16);

  float* out_h    = (float*)d_out;
  float* out_conn = out_h + (size_t)NN * 64;

  hipMemsetAsync(cnt, 0, (size_t)NN * 4, stream);

  k0_pack<<<48, 256, 0, stream>>>(E_w, conn1_w, conn2_w, qkv_w, ffn1_w, ffn2_w, Aw,
                                  BpE, Bp1, Bp2, BpQ, BpF1, BpF2, BpA);
  k_hist<<<NE / 256, 256, 0, stream>>>(dst, cnt);
  k_scan<<<1, SCAN_T, 0, stream>>>(cnt, startp, cursor);
  k_scatter<<<NE / 256, 256, 0, stream>>>(dst, src, cursor, pack);
  k1_qkv<<<(NN + 63) / 64, 256, 0, stream>>>(x, BpQ, qkv_b, Q, Kq, V);
  k2_edge<<<NE / 64, 256, 0, stream>>>(e, pack, BpE, E_b, BpA, Bp1, conn1_b,
                                       Q, Kq, ln1c_g, ln1c_b, Bp2, conn2_b,
                                       ln2c_g, ln2c_b, cmb, sexp, out_conn);
  k_agg<<<(NN * 64 + 255) / 256, 256, 0, stream>>>(startp, pack, sexp, cmb, V, x, hpre);
  k5_node<<<(NN + 63) / 64, 256, 0, stream>>>(hpre, ln1h_g, ln1h_b, BpF1, ffn1_b,
                                              BpF2, ffn2_b, ln2h_g, ln2h_b, out_h);
}

// Round 17
// 392.454 us; speedup vs baseline: 1.3909x; 1.0279x over previous
//
#include <hip/hip_runtime.h>
#include <cstdint>

#define NN 50000
#define NE 512000

typedef unsigned short bf16u;
typedef __attribute__((ext_vector_type(8))) short short8v;
typedef __attribute__((ext_vector_type(4))) float f32x4;

__device__ __forceinline__ bf16u f2bf(float f){
  union { float f; unsigned int u; } v; v.f = f;
  unsigned int r = v.u + 0x7FFFu + ((v.u >> 16) & 1u);
  return (bf16u)(r >> 16);
}
__device__ __forceinline__ float bf2f(bf16u s){
  union { unsigned int u; float f; } v; v.u = ((unsigned int)s) << 16;
  return v.f;
}

// ---------- K0: weight packing into MFMA B-fragments ----------
__global__ void k0_pack(const float* __restrict__ E_w, const float* __restrict__ conn1_w,
                        const float* __restrict__ conn2_w, const float* __restrict__ qkv_w,
                        const float* __restrict__ ffn1_w, const float* __restrict__ ffn2_w,
                        const float* __restrict__ Aw,
                        bf16u* __restrict__ BpE, bf16u* __restrict__ Bp1,
                        bf16u* __restrict__ Bp2, bf16u* __restrict__ BpQ,
                        bf16u* __restrict__ BpF1, bf16u* __restrict__ BpF2,
                        bf16u* __restrict__ BpA){
  int i = blockIdx.x * 256 + threadIdx.x;   // 0..12287
  int j = i & 7, l = (i >> 3) & 63;
  int nl = l & 15, kl = (l >> 4) << 3;
  if (i < 8192){   // E_w: (128,64), NF=8, KS=2
    int rest = i >> 9, nf = rest & 7, ks = rest >> 3;
    int n = nf * 16 + nl, k = ks * 32 + kl + j;
    BpE[i] = f2bf(E_w[n * 64 + k]);
  }
  if (i < 4096){   // conn1_w/conn2_w: (64,64), NF=4, KS=2
    int rest = i >> 9, nf = rest & 3, ks = rest >> 2;
    int n = nf * 16 + nl, k = ks * 32 + kl + j;
    Bp1[i] = f2bf(conn1_w[n * 64 + k]);
    Bp2[i] = f2bf(conn2_w[n * 64 + k]);
  }
  if (i < 12288){  // qkv_w: (192,64), NF=12, KS=2
    int rest = i >> 9, nf = rest % 12, ks = rest / 12;
    int n = nf * 16 + nl, k = ks * 32 + kl + j;
    BpQ[i] = f2bf(qkv_w[n * 64 + k]);
  }
  if (i < 8192){   // ffn1_w: (128,64), NF=8, KS=2
    int rest = i >> 9, nf = rest & 7, ks = rest >> 3;
    int n = nf * 16 + nl, k = ks * 32 + kl + j;
    BpF1[i] = f2bf(ffn1_w[n * 64 + k]);
  }
  if (i < 8192){   // ffn2_w: (64,128), NF=4, KS=4
    int rest = i >> 9, nf = rest & 3, ks = rest >> 2;
    int n = nf * 16 + nl, k = ks * 32 + kl + j;
    BpF2[i] = f2bf(ffn2_w[n * 128 + k]);
  }
  if (i < 1024){   // Aw score B-frag: col n<4 = head, B[k][n]=Aw[(k&15)*4+n] iff k>>4==n
    int ks = i >> 9;
    int n = nl, k = ks * 32 + kl + j;
    float v = (n < 4 && (k >> 4) == n) ? Aw[(k & 15) * 4 + n] : 0.f;
    BpA[i] = f2bf(v);
  }
}

// ---------- CSR build ----------
__global__ void k_hist(const int* __restrict__ dst, int* __restrict__ cnt){
  int e = blockIdx.x * 256 + threadIdx.x;
  if (e < NE) atomicAdd(&cnt[dst[e]], 1);
}

#define SCAN_T 1024
#define PER_T 52   // 1024*52 >= NN; 16B-aligned -> int4 loads
__global__ __launch_bounds__(SCAN_T) void k_scan(const int* __restrict__ cnt,
                                                 int* __restrict__ start, int* __restrict__ cursor){
  __shared__ int ls[SCAN_T];
  int t = threadIdx.x;
  int base = t * PER_T;
  int4 vs[13];
  int s = 0;
  const int4* cp = (const int4*)(cnt + base);
#pragma unroll
  for (int c = 0; c < 13; ++c){
    int4 v = cp[c];
    int n0 = base + c * 4;
    if (n0 + 0 >= NN) v.x = 0;
    if (n0 + 1 >= NN) v.y = 0;
    if (n0 + 2 >= NN) v.z = 0;
    if (n0 + 3 >= NN) v.w = 0;
    vs[c] = v;
    s += v.x + v.y + v.z + v.w;
  }
  ls[t] = s; __syncthreads();
  for (int off = 1; off < SCAN_T; off <<= 1){
    int v = ls[t];
    int add = (t >= off) ? ls[t - off] : 0;
    __syncthreads();
    ls[t] = v + add;
    __syncthreads();
  }
  int run = (t > 0) ? ls[t - 1] : 0;
#pragma unroll
  for (int c = 0; c < 13; ++c){
    int vv[4] = {vs[c].x, vs[c].y, vs[c].z, vs[c].w};
#pragma unroll
    for (int j = 0; j < 4; ++j){
      int n = base + c * 4 + j;
      if (n < NN){ start[n] = run; cursor[n] = run; run += vv[j]; }
    }
  }
  if (t == SCAN_T - 1) start[NN] = run;
}

// packed record per CSR position: {eid, dst_node, src_node, 0}
__global__ void k_scatter(const int* __restrict__ dst, const int* __restrict__ src,
                          int* __restrict__ cursor, int4* __restrict__ pack){
  int e = blockIdx.x * 256 + threadIdx.x;
  if (e < NE){
    int dn = dst[e];
    int p = atomicAdd(&cursor[dn], 1);
    int4 rec; rec.x = e; rec.y = dn; rec.z = src[e]; rec.w = 0;
    pack[p] = rec;
  }
}

// ---------- K1: node QKV — MFMA, split-bf16 A ----------
__global__ __launch_bounds__(256) void k1_qkv(const float* __restrict__ x,
    const bf16u* __restrict__ BpQ, const float* __restrict__ qkv_b,
    float* __restrict__ Q, float* __restrict__ K, float* __restrict__ V){
  int tile = blockIdx.x * 64;
  int w = threadIdx.x >> 6, l = threadIdx.x & 63;
  int lg = l >> 4, li = l & 15;
  const short8v* bpq = (const short8v*)BpQ;
  short8v Bq[3][2];
#pragma unroll
  for (int p = 0; p < 3; ++p)
#pragma unroll
    for (int ks = 0; ks < 2; ++ks)
      Bq[p][ks] = bpq[(ks * 12 + p * 4 + w) * 64 + l];
  f32x4 z = {0.f, 0.f, 0.f, 0.f};
  f32x4 acc[3][4];
#pragma unroll
  for (int p = 0; p < 3; ++p)
#pragma unroll
    for (int mf = 0; mf < 4; ++mf) acc[p][mf] = z;
#pragma unroll
  for (int mf = 0; mf < 4; ++mf){
    int row = tile + mf * 16 + li;
    bool g = row < NN;
    const float* xp = x + (size_t)row * 64 + lg * 8;
#pragma unroll
    for (int ks = 0; ks < 2; ++ks){
      float v[8];
      if (g){
        float4 t0 = *(const float4*)(xp + ks * 32);
        float4 t1 = *(const float4*)(xp + ks * 32 + 4);
        v[0]=t0.x; v[1]=t0.y; v[2]=t0.z; v[3]=t0.w;
        v[4]=t1.x; v[5]=t1.y; v[6]=t1.z; v[7]=t1.w;
      } else {
#pragma unroll
        for (int j = 0; j < 8; ++j) v[j] = 0.f;
      }
      short8v hi, lo;
#pragma unroll
      for (int j = 0; j < 8; ++j){
        bf16u h = f2bf(v[j]);
        hi[j] = (short)h;
        lo[j] = (short)f2bf(v[j] - bf2f(h));
      }
#pragma unroll
      for (int p = 0; p < 3; ++p){
        acc[p][mf] = __builtin_amdgcn_mfma_f32_16x16x32_bf16(hi, Bq[p][ks], acc[p][mf], 0, 0, 0);
        acc[p][mf] = __builtin_amdgcn_mfma_f32_16x16x32_bf16(lo, Bq[p][ks], acc[p][mf], 0, 0, 0);
      }
    }
  }
  float bias[3] = {qkv_b[w*16+li], qkv_b[64+w*16+li], qkv_b[128+w*16+li]};
  float* outs[3] = {Q, K, V};
#pragma unroll
  for (int p = 0; p < 3; ++p)
#pragma unroll
    for (int mf = 0; mf < 4; ++mf)
#pragma unroll
      for (int r = 0; r < 4; ++r){
        int row = tile + mf * 16 + lg * 4 + r;
        if (row < NN) outs[p][(size_t)row * 64 + w * 16 + li] = acc[p][mf][r] + bias[p];
      }
}

// ---------- K2: fused edge kernel — wave-autonomous, split-bf16 cp ----------
__global__ __launch_bounds__(256, 5) void k2_edge(
    const float* __restrict__ e, const int4* __restrict__ pack,
    const bf16u* __restrict__ BpE, const float* __restrict__ E_b,
    const bf16u* __restrict__ BpA, const bf16u* __restrict__ Bp1, const float* __restrict__ conn1_b,
    const float* __restrict__ Q, const float* __restrict__ K,
    const float* __restrict__ g1c, const float* __restrict__ b1c,
    const bf16u* __restrict__ Bp2, const float* __restrict__ conn2_b,
    const float* __restrict__ g2c, const float* __restrict__ b2c,
    bf16u* __restrict__ cm, float* __restrict__ sexp, float* __restrict__ out_conn){
  __shared__ bf16u ldsT[4 * 16 * 72];     // per-wave 16x72 bf16 hi buffer
  __shared__ bf16u ldsTlo[4 * 16 * 72];   // per-wave 16x72 bf16 lo-residual buffer
  int t = threadIdx.x;
  int w = t >> 6, l = t & 63;
  int lg = l >> 4, li = l & 15;
  int pos0 = blockIdx.x * 64 + w * 16;
  bf16u* T   = &ldsT[w * (16 * 72)];
  bf16u* Tlo = &ldsTlo[w * (16 * 72)];
  f32x4 z = {0.f, 0.f, 0.f, 0.f};

  // --- phase A: Eh MFMA (16 edges x 128 outs, this wave) ---
  short8v afr[2];
  {
    int eidA = pack[pos0 + li].x;
    const float* ep = e + (size_t)eidA * 64 + lg * 8;
#pragma unroll
    for (int ks = 0; ks < 2; ++ks){
      float4 a0 = *(const float4*)(ep + ks * 32);
      float4 a1 = *(const float4*)(ep + ks * 32 + 4);
      short8v af;
      af[0]=(short)f2bf(a0.x); af[1]=(short)f2bf(a0.y); af[2]=(short)f2bf(a0.z); af[3]=(short)f2bf(a0.w);
      af[4]=(short)f2bf(a1.x); af[5]=(short)f2bf(a1.y); af[6]=(short)f2bf(a1.z); af[7]=(short)f2bf(a1.w);
      afr[ks] = af;
    }
  }
  f32x4 accW[4], accB[4];
#pragma unroll
  for (int nf = 0; nf < 4; ++nf){ accW[nf] = z; accB[nf] = z; }
  {
    const short8v* bpe = (const short8v*)BpE;
#pragma unroll
    for (int ks = 0; ks < 2; ++ks){
#pragma unroll
      for (int nf = 0; nf < 4; ++nf){
        short8v BW = bpe[(ks * 8 + nf) * 64 + l];
        short8v BB = bpe[(ks * 8 + 4 + nf) * 64 + l];
        accW[nf] = __builtin_amdgcn_mfma_f32_16x16x32_bf16(afr[ks], BW, accW[nf], 0, 0, 0);
        accB[nf] = __builtin_amdgcn_mfma_f32_16x16x32_bf16(afr[ks], BB, accB[nf], 0, 0, 0);
      }
    }
  }

  // --- pointwise: conn_pre (D-layout: row=lg*4+r, col=nf*16+li) ---
  int dnv[4], snv[4], eidv[4];
#pragma unroll
  for (int r = 0; r < 4; ++r){
    int4 rec = pack[pos0 + lg * 4 + r];
    eidv[r] = rec.x; dnv[r] = rec.y; snv[r] = rec.z;
  }
  float cp[4][4];
#pragma unroll
  for (int nf = 0; nf < 4; ++nf){
    int dim = nf * 16 + li;
    float eb0 = E_b[dim], eb1 = E_b[64 + dim];
#pragma unroll
    for (int r = 0; r < 4; ++r){
      float qv = Q[(size_t)dnv[r] * 64 + dim];
      float kv = K[(size_t)snv[r] * 64 + dim];
      float ew  = accW[nf][r] + eb0;
      float ebv = accB[nf][r] + eb1;
      float c1 = (qv + kv) * ew;
      float c2 = copysignf(sqrtf(fabsf(c1)), c1);
      cp[nf][r] = fmaxf(c2 + ebv, 0.f);
    }
  }

  // --- transpose #1: cp D-layout -> LDS hi+lo -> A-frags ---
#pragma unroll
  for (int nf = 0; nf < 4; ++nf)
#pragma unroll
    for (int r = 0; r < 4; ++r){
      int idx = (lg * 4 + r) * 72 + nf * 16 + li;
      bf16u hb = f2bf(cp[nf][r]);
      T[idx] = hb;
      Tlo[idx] = f2bf(cp[nf][r] - bf2f(hb));
    }
  __builtin_amdgcn_wave_barrier();
  short8v a1f[2], a1lo[2];
  a1f[0]  = *(const short8v*)&T[li * 72 + 0 * 32 + lg * 8];
  a1f[1]  = *(const short8v*)&T[li * 72 + 1 * 32 + lg * 8];
  a1lo[0] = *(const short8v*)&Tlo[li * 72 + 0 * 32 + lg * 8];
  a1lo[1] = *(const short8v*)&Tlo[li * 72 + 1 * 32 + lg * 8];

  // --- score MFMA (hi+lo) + exp + store ---
  {
    const short8v* bpa = (const short8v*)BpA;
    f32x4 sacc = z;
    sacc = __builtin_amdgcn_mfma_f32_16x16x32_bf16(a1f[0],  bpa[0 * 64 + l], sacc, 0, 0, 0);
    sacc = __builtin_amdgcn_mfma_f32_16x16x32_bf16(a1lo[0], bpa[0 * 64 + l], sacc, 0, 0, 0);
    sacc = __builtin_amdgcn_mfma_f32_16x16x32_bf16(a1f[1],  bpa[1 * 64 + l], sacc, 0, 0, 0);
    sacc = __builtin_amdgcn_mfma_f32_16x16x32_bf16(a1lo[1], bpa[1 * 64 + l], sacc, 0, 0, 0);
    if (li < 4){
#pragma unroll
      for (int r = 0; r < 4; ++r){
        float sc = fminf(fmaxf(sacc[r], -5.f), 5.f);
        sexp[(size_t)(pos0 + lg * 4 + r) * 4 + li] = __expf(sc);
      }
    }
  }

  // --- conn1 MFMA (hi+lo) -> cmv (D-layout, near-f32) ---
  float cmv[4][4];
  {
    const short8v* bp1 = (const short8v*)Bp1;
#pragma unroll
    for (int nf = 0; nf < 4; ++nf){
      f32x4 acc = z;
      acc = __builtin_amdgcn_mfma_f32_16x16x32_bf16(a1f[0],  bp1[(0 * 4 + nf) * 64 + l], acc, 0, 0, 0);
      acc = __builtin_amdgcn_mfma_f32_16x16x32_bf16(a1lo[0], bp1[(0 * 4 + nf) * 64 + l], acc, 0, 0, 0);
      acc = __builtin_amdgcn_mfma_f32_16x16x32_bf16(a1f[1],  bp1[(1 * 4 + nf) * 64 + l], acc, 0, 0, 0);
      acc = __builtin_amdgcn_mfma_f32_16x16x32_bf16(a1lo[1], bp1[(1 * 4 + nf) * 64 + l], acc, 0, 0, 0);
      float c1b = conn1_b[nf * 16 + li];
#pragma unroll
      for (int r = 0; r < 4; ++r){
        float v = acc[r] + c1b;
        cmv[nf][r] = v;
        cm[(size_t)(pos0 + lg * 4 + r) * 64 + nf * 16 + li] = f2bf(v);
      }
    }
  }

  // --- LN1c stats (wave-local) ---
  float mu1r[4], rs1r[4];
#pragma unroll
  for (int r = 0; r < 4; ++r){
    float s = cmv[0][r] + cmv[1][r] + cmv[2][r] + cmv[3][r];
    float q = cmv[0][r]*cmv[0][r] + cmv[1][r]*cmv[1][r] + cmv[2][r]*cmv[2][r] + cmv[3][r]*cmv[3][r];
    s += __shfl_xor(s, 1); s += __shfl_xor(s, 2); s += __shfl_xor(s, 4); s += __shfl_xor(s, 8);
    q += __shfl_xor(q, 1); q += __shfl_xor(q, 2); q += __shfl_xor(q, 4); q += __shfl_xor(q, 8);
    float mu = s * (1.f / 64.f);
    float var = q * (1.f / 64.f) - mu * mu;
    mu1r[r] = mu;
    rs1r[r] = rsqrtf(fmaxf(var, 0.f) + 1e-5f);
  }

  // --- LN1c normalize + relu -> transpose #2 (reuse T) ---
  __builtin_amdgcn_wave_barrier();
#pragma unroll
  for (int nf = 0; nf < 4; ++nf){
    int dim = nf * 16 + li;
    float g1v = g1c[dim], b1v = b1c[dim];
#pragma unroll
    for (int r = 0; r < 4; ++r){
      float cn = fmaxf((cmv[nf][r] - mu1r[r]) * rs1r[r] * g1v + b1v, 0.f);
      T[(lg * 4 + r) * 72 + dim] = f2bf(cn);
    }
  }
  __builtin_amdgcn_wave_barrier();
  short8v a2f[2];
  a2f[0] = *(const short8v*)&T[li * 72 + 0 * 32 + lg * 8];
  a2f[1] = *(const short8v*)&T[li * 72 + 1 * 32 + lg * 8];

  // --- conn2 MFMA + residual -> rv (f32 regs) ---
  float rv[4][4];
  {
    const short8v* bp2 = (const short8v*)Bp2;
#pragma unroll
    for (int nf = 0; nf < 4; ++nf){
      f32x4 acc = z;
      acc = __builtin_amdgcn_mfma_f32_16x16x32_bf16(a2f[0], bp2[(0 * 4 + nf) * 64 + l], acc, 0, 0, 0);
      acc = __builtin_amdgcn_mfma_f32_16x16x32_bf16(a2f[1], bp2[(1 * 4 + nf) * 64 + l], acc, 0, 0, 0);
      int dim = nf * 16 + li;
      float c2b = conn2_b[dim];
#pragma unroll
      for (int r = 0; r < 4; ++r)
        rv[nf][r] = acc[r] + c2b + e[(size_t)eidv[r] * 64 + dim];
    }
  }

  // --- LN2c stats (wave-local) + store out_conn ---
#pragma unroll
  for (int r = 0; r < 4; ++r){
    float s = rv[0][r] + rv[1][r] + rv[2][r] + rv[3][r];
    float q = rv[0][r]*rv[0][r] + rv[1][r]*rv[1][r] + rv[2][r]*rv[2][r] + rv[3][r]*rv[3][r];
    s += __shfl_xor(s, 1); s += __shfl_xor(s, 2); s += __shfl_xor(s, 4); s += __shfl_xor(s, 8);
    q += __shfl_xor(q, 1); q += __shfl_xor(q, 2); q += __shfl_xor(q, 4); q += __shfl_xor(q, 8);
    float mu = s * (1.f / 64.f);
    float var = q * (1.f / 64.f) - mu * mu;
    float rs = rsqrtf(fmaxf(var, 0.f) + 1e-5f);
#pragma unroll
    for (int nf = 0; nf < 4; ++nf){
      int dim = nf * 16 + li;
      out_conn[(size_t)eidv[r] * 64 + dim] = (rv[nf][r] - mu) * rs * g2c[dim] + b2c[dim];
    }
  }
}

// ---------- K_agg5: fused gather + LN1h + FFN (MFMA) + LN2h ----------
__global__ __launch_bounds__(256) void k_agg5(
    const int* __restrict__ start, const int4* __restrict__ pack,
    const float* __restrict__ sexp, const bf16u* __restrict__ cm, const float* __restrict__ V,
    const float* __restrict__ x,
    const float* __restrict__ g1, const float* __restrict__ b1,
    const bf16u* __restrict__ BpF1, const float* __restrict__ ffn1_b,
    const bf16u* __restrict__ BpF2, const float* __restrict__ ffn2_b,
    const float* __restrict__ g2, const float* __restrict__ b2,
    float* __restrict__ out_h){
  __shared__ float hpreS[64 * 68];
  __shared__ bf16u buf1[64 * 72 * 2];   // hlhi|hllo; g1o (stride 136) overlays after GEMM1
  __shared__ float reds[64][4];
  __shared__ float redq[64][4];
  bf16u* hlhi = buf1;
  bf16u* hllo = buf1 + 64 * 72;
  bf16u* g1o  = buf1;
  int tile = blockIdx.x * 64;
  int t = threadIdx.x;
  int w = t >> 6, l = t & 63;
  int lg = l >> 4, li = l & 15;

  // --- gather phase: wave w handles 16 nodes sequentially ---
  for (int nl = w * 16; nl < w * 16 + 16; ++nl){
    int node = tile + nl;
    float hp = 0.f;
    if (node < NN){
      int s0 = start[node], s1 = start[node + 1];
      int h = l >> 4;
      float num0 = 0.f, den0 = 0.f, num1 = 0.f, den1 = 0.f;
      int i = s0;
      for (; i + 1 < s1; i += 2){
        float sxa = sexp[(size_t)i * 4 + h];
        float sxb = sexp[(size_t)(i + 1) * 4 + h];
        int sna = pack[i].z, snb = pack[i + 1].z;
        float va = V[(size_t)sna * 64 + l];
        float vb = V[(size_t)snb * 64 + l];
        float ca = bf2f(cm[(size_t)i * 64 + l]);
        float cb = bf2f(cm[(size_t)(i + 1) * 64 + l]);
        num0 += sxa * (va + ca); den0 += sxa;
        num1 += sxb * (vb + cb); den1 += sxb;
      }
      if (i < s1){
        float sx = sexp[(size_t)i * 4 + h];
        int sn = pack[i].z;
        float v  = V[(size_t)sn * 64 + l];
        float cc = bf2f(cm[(size_t)i * 64 + l]);
        num0 += sx * (v + cc); den0 += sx;
      }
      hp = x[(size_t)node * 64 + l] + (num0 + num1) / (den0 + den1 + 1e-16f);
    }
    hpreS[nl * 68 + l] = hp;
  }
  __syncthreads();

  // --- LN1h phase (thread = (row, quarter)) from hpreS ---
  {
    int el = t >> 2, q = t & 3;
    const float4* hp = (const float4*)&hpreS[el * 68 + q * 16];
    float v[16];
#pragma unroll
    for (int c = 0; c < 4; ++c){
      float4 tv = hp[c];
      v[c*4+0]=tv.x; v[c*4+1]=tv.y; v[c*4+2]=tv.z; v[c*4+3]=tv.w;
    }
    float s = 0.f, sq = 0.f;
#pragma unroll
    for (int i = 0; i < 16; ++i){ s += v[i]; sq += v[i]*v[i]; }
    s  += __shfl_xor(s, 1);  s  += __shfl_xor(s, 2);
    sq += __shfl_xor(sq, 1); sq += __shfl_xor(sq, 2);
    float mu = s * (1.f/64.f);
    float var = sq * (1.f/64.f) - mu * mu;
    float rs = rsqrtf(fmaxf(var, 0.f) + 1e-5f);
#pragma unroll
    for (int i = 0; i < 16; ++i){
      int d = q * 16 + i;
      float hv = (v[i] - mu) * rs * g1[d] + b1[d];
      bf16u hb = f2bf(hv);
      hlhi[el * 72 + d] = hb;
      hllo[el * 72 + d] = f2bf(hv - bf2f(hb));
    }
  }
  __syncthreads();

  // --- GEMM1 ---
  const short8v* bpf1 = (const short8v*)BpF1;
  short8v B1f[2][2];
#pragma unroll
  for (int f = 0; f < 2; ++f)
#pragma unroll
    for (int ks = 0; ks < 2; ++ks)
      B1f[f][ks] = bpf1[(ks * 8 + f * 4 + w) * 64 + l];
  f32x4 z = {0.f, 0.f, 0.f, 0.f};
  f32x4 acc1[2][4];
#pragma unroll
  for (int f = 0; f < 2; ++f)
#pragma unroll
    for (int mf = 0; mf < 4; ++mf) acc1[f][mf] = z;
#pragma unroll
  for (int mf = 0; mf < 4; ++mf){
#pragma unroll
    for (int ks = 0; ks < 2; ++ks){
      const bf16u* ah = &hlhi[(mf * 16 + li) * 72 + ks * 32 + lg * 8];
      const bf16u* al = &hllo[(mf * 16 + li) * 72 + ks * 32 + lg * 8];
      short8v Ahi = *(const short8v*)ah;
      short8v Alo = *(const short8v*)al;
#pragma unroll
      for (int f = 0; f < 2; ++f){
        acc1[f][mf] = __builtin_amdgcn_mfma_f32_16x16x32_bf16(Ahi, B1f[f][ks], acc1[f][mf], 0, 0, 0);
        acc1[f][mf] = __builtin_amdgcn_mfma_f32_16x16x32_bf16(Alo, B1f[f][ks], acc1[f][mf], 0, 0, 0);
      }
    }
  }
  __syncthreads();   // hlhi/hllo reads complete; g1o may overlay
  float fb[2] = {ffn1_b[w*16+li], ffn1_b[64+w*16+li]};
#pragma unroll
  for (int f = 0; f < 2; ++f)
#pragma unroll
    for (int mf = 0; mf < 4; ++mf)
#pragma unroll
      for (int r = 0; r < 4; ++r){
        int rowl = mf * 16 + lg * 4 + r;
        int col = f * 64 + w * 16 + li;
        g1o[rowl * 136 + col] = f2bf(fmaxf(acc1[f][mf][r] + fb[f], 0.f));
      }
  __syncthreads();

  // --- GEMM2 + residual (hpreS) + LN2h ---
  const short8v* bpf2 = (const short8v*)BpF2;
  short8v B2f[4];
#pragma unroll
  for (int ks = 0; ks < 4; ++ks) B2f[ks] = bpf2[(ks * 4 + w) * 64 + l];
  int o = w * 16 + li;
  float f2b_ = ffn2_b[o];
  float racc[4][4];
#pragma unroll
  for (int mf = 0; mf < 4; ++mf){
    f32x4 acc = z;
#pragma unroll
    for (int ks = 0; ks < 4; ++ks){
      short8v A2 = *(const short8v*)&g1o[(mf * 16 + li) * 136 + ks * 32 + lg * 8];
      acc = __builtin_amdgcn_mfma_f32_16x16x32_bf16(A2, B2f[ks], acc, 0, 0, 0);
    }
#pragma unroll
    for (int r = 0; r < 4; ++r){
      int rowl = mf * 16 + lg * 4 + r;
      float hres = hpreS[rowl * 68 + o];
      float rvv = acc[r] + f2b_ + hres;
      racc[mf][r] = rvv;
      float s = rvv, q2 = rvv * rvv;
      s  += __shfl_xor(s, 1);  s  += __shfl_xor(s, 2);  s  += __shfl_xor(s, 4);  s  += __shfl_xor(s, 8);
      q2 += __shfl_xor(q2, 1); q2 += __shfl_xor(q2, 2); q2 += __shfl_xor(q2, 4); q2 += __shfl_xor(q2, 8);
      if (li == 0){ reds[rowl][w] = s; redq[rowl][w] = q2; }
    }
  }
  __syncthreads();
  float g2v = g2[o], b2v = b2[o];
#pragma unroll
  for (int mf = 0; mf < 4; ++mf){
#pragma unroll
    for (int r = 0; r < 4; ++r){
      int rowl = mf * 16 + lg * 4 + r;
      int row = tile + rowl;
      if (row < NN){
        float S  = reds[rowl][0] + reds[rowl][1] + reds[rowl][2] + reds[rowl][3];
        float Qq = redq[rowl][0] + redq[rowl][1] + redq[rowl][2] + redq[rowl][3];
        float mu2 = S * (1.f/64.f);
        float var2 = Qq * (1.f/64.f) - mu2 * mu2;
        float rs2 = rsqrtf(fmaxf(var2, 0.f) + 1e-5f);
        out_h[(size_t)row * 64 + o] = (racc[mf][r] - mu2) * rs2 * g2v + b2v;
      }
    }
  }
}

extern "C" void kernel_launch(void* const* d_in, const int* in_sizes, int n_in,
                              void* d_out, int out_size, void* d_ws, size_t ws_size,
                              hipStream_t stream){
  const float* x       = (const float*)d_in[0];
  const float* e       = (const float*)d_in[1];
  const int*   dst     = (const int*)d_in[2];
  const int*   src     = (const int*)d_in[3];
  const float* qkv_w   = (const float*)d_in[4];
  const float* qkv_b   = (const float*)d_in[5];
  const float* E_w     = (const float*)d_in[6];
  const float* E_b     = (const float*)d_in[7];
  const float* Aw      = (const float*)d_in[8];
  const float* conn1_w = (const float*)d_in[9];
  const float* conn1_b = (const float*)d_in[10];
  const float* conn2_w = (const float*)d_in[11];
  const float* conn2_b = (const float*)d_in[12];
  const float* ffn1_w  = (const float*)d_in[13];
  const float* ffn1_b  = (const float*)d_in[14];
  const float* ffn2_w  = (const float*)d_in[15];
  const float* ffn2_b  = (const float*)d_in[16];
  const float* ln1h_g  = (const float*)d_in[17];
  const float* ln1h_b  = (const float*)d_in[18];
  const float* ln2h_g  = (const float*)d_in[19];
  const float* ln2h_b  = (const float*)d_in[20];
  const float* ln1c_g  = (const float*)d_in[21];
  const float* ln1c_b  = (const float*)d_in[22];
  const float* ln2c_g  = (const float*)d_in[23];
  const float* ln2c_b  = (const float*)d_in[24];

  char* ws = (char*)d_ws;
  size_t off = 0;
  auto alloc = [&](size_t bytes) -> void* {
    void* p = ws + off;
    off += (bytes + 255) & ~(size_t)255;
    return p;
  };
  float* Q     = (float*)alloc((size_t)NN * 64 * 4);
  float* Kq    = (float*)alloc((size_t)NN * 64 * 4);
  float* V     = (float*)alloc((size_t)NN * 64 * 4);
  bf16u* cmb   = (bf16u*)alloc((size_t)NE * 64 * 2);
  float* sexp  = (float*)alloc((size_t)NE * 4 * 4);
  bf16u* BpE   = (bf16u*)alloc(8192 * 2);
  bf16u* Bp1   = (bf16u*)alloc(4096 * 2);
  bf16u* Bp2   = (bf16u*)alloc(4096 * 2);
  bf16u* BpQ   = (bf16u*)alloc(12288 * 2);
  bf16u* BpF1  = (bf16u*)alloc(8192 * 2);
  bf16u* BpF2  = (bf16u*)alloc(8192 * 2);
  bf16u* BpA   = (bf16u*)alloc(1024 * 2);
  int*   cnt   = (int*)alloc((size_t)NN * 4);
  int*   startp= (int*)alloc(((size_t)NN + 1) * 4);
  int*   cursor= (int*)alloc((size_t)NN * 4);
  int4*  pack  = (int4*)alloc((size_t)NE * 16);

  float* out_h    = (float*)d_out;
  float* out_conn = out_h + (size_t)NN * 64;

  hipMemsetAsync(cnt, 0, (size_t)NN * 4, stream);

  k0_pack<<<48, 256, 0, stream>>>(E_w, conn1_w, conn2_w, qkv_w, ffn1_w, ffn2_w, Aw,
                                  BpE, Bp1, Bp2, BpQ, BpF1, BpF2, BpA);
  k_hist<<<NE / 256, 256, 0, stream>>>(dst, cnt);
  k_scan<<<1, SCAN_T, 0, stream>>>(cnt, startp, cursor);
  k_scatter<<<NE / 256, 256, 0, stream>>>(dst, src, cursor, pack);
  k1_qkv<<<(NN + 63) / 64, 256, 0, stream>>>(x, BpQ, qkv_b, Q, Kq, V);
  k2_edge<<<NE / 64, 256, 0, stream>>>(e, pack, BpE, E_b, BpA, Bp1, conn1_b,
                                       Q, Kq, ln1c_g, ln1c_b, Bp2, conn2_b,
                                       ln2c_g, ln2c_b, cmb, sexp, out_conn);
  k_agg5<<<(NN + 63) / 64, 256, 0, stream>>>(startp, pack, sexp, cmb, V, x,
                                             ln1h_g, ln1h_b, BpF1, ffn1_b,
                                             BpF2, ffn2_b, ln2h_g, ln2h_b, out_h);
}

// Round 21
// 359.002 us; speedup vs baseline: 1.5205x; 1.0932x over previous
//
#include <hip/hip_runtime.h>
#include <cstdint>

#define NN 50000
#define NE 512000

typedef unsigned short bf16u;
typedef __attribute__((ext_vector_type(8))) short short8v;
typedef __attribute__((ext_vector_type(4))) float f32x4;

__device__ __forceinline__ bf16u f2bf(float f){
  union { float f; unsigned int u; } v; v.f = f;
  unsigned int r = v.u + 0x7FFFu + ((v.u >> 16) & 1u);
  return (bf16u)(r >> 16);
}
__device__ __forceinline__ float bf2f(bf16u s){
  union { unsigned int u; float f; } v; v.u = ((unsigned int)s) << 16;
  return v.f;
}

// ---------- K0: weight packing into MFMA B-fragments ----------
__global__ void k0_pack(const float* __restrict__ E_w, const float* __restrict__ conn1_w,
                        const float* __restrict__ conn2_w, const float* __restrict__ qkv_w,
                        const float* __restrict__ ffn1_w, const float* __restrict__ ffn2_w,
                        const float* __restrict__ Aw,
                        bf16u* __restrict__ BpE, bf16u* __restrict__ Bp1,
                        bf16u* __restrict__ Bp2, bf16u* __restrict__ BpQ,
                        bf16u* __restrict__ BpF1, bf16u* __restrict__ BpF2,
                        bf16u* __restrict__ BpA){
  int i = blockIdx.x * 256 + threadIdx.x;   // 0..12287
  int j = i & 7, l = (i >> 3) & 63;
  int nl = l & 15, kl = (l >> 4) << 3;
  if (i < 8192){   // E_w: (128,64), NF=8, KS=2
    int rest = i >> 9, nf = rest & 7, ks = rest >> 3;
    int n = nf * 16 + nl, k = ks * 32 + kl + j;
    BpE[i] = f2bf(E_w[n * 64 + k]);
  }
  if (i < 4096){   // conn1_w/conn2_w: (64,64), NF=4, KS=2
    int rest = i >> 9, nf = rest & 3, ks = rest >> 2;
    int n = nf * 16 + nl, k = ks * 32 + kl + j;
    Bp1[i] = f2bf(conn1_w[n * 64 + k]);
    Bp2[i] = f2bf(conn2_w[n * 64 + k]);
  }
  if (i < 12288){  // qkv_w: (192,64), NF=12, KS=2
    int rest = i >> 9, nf = rest % 12, ks = rest / 12;
    int n = nf * 16 + nl, k = ks * 32 + kl + j;
    BpQ[i] = f2bf(qkv_w[n * 64 + k]);
  }
  if (i < 8192){   // ffn1_w: (128,64), NF=8, KS=2
    int rest = i >> 9, nf = rest & 7, ks = rest >> 3;
    int n = nf * 16 + nl, k = ks * 32 + kl + j;
    BpF1[i] = f2bf(ffn1_w[n * 64 + k]);
  }
  if (i < 8192){   // ffn2_w: (64,128), NF=4, KS=4
    int rest = i >> 9, nf = rest & 3, ks = rest >> 2;
    int n = nf * 16 + nl, k = ks * 32 + kl + j;
    BpF2[i] = f2bf(ffn2_w[n * 128 + k]);
  }
  if (i < 1024){   // Aw score B-frag: col n<4 = head, B[k][n]=Aw[(k&15)*4+n] iff k>>4==n
    int ks = i >> 9;
    int n = nl, k = ks * 32 + kl + j;
    float v = (n < 4 && (k >> 4) == n) ? Aw[(k & 15) * 4 + n] : 0.f;
    BpA[i] = f2bf(v);
  }
}

// ---------- CSR build ----------
__global__ void k_hist(const int* __restrict__ dst, int* __restrict__ cnt){
  int e = blockIdx.x * 256 + threadIdx.x;
  if (e < NE) atomicAdd(&cnt[dst[e]], 1);
}

#define SCAN_T 1024
#define PER_T 52   // 1024*52 >= NN; 16B-aligned -> int4 loads
__global__ __launch_bounds__(SCAN_T) void k_scan(const int* __restrict__ cnt,
                                                 int* __restrict__ start, int* __restrict__ cursor){
  __shared__ int ls[SCAN_T];
  int t = threadIdx.x;
  int base = t * PER_T;
  int4 vs[13];
  int s = 0;
  const int4* cp = (const int4*)(cnt + base);
#pragma unroll
  for (int c = 0; c < 13; ++c){
    int4 v = cp[c];
    int n0 = base + c * 4;
    if (n0 + 0 >= NN) v.x = 0;
    if (n0 + 1 >= NN) v.y = 0;
    if (n0 + 2 >= NN) v.z = 0;
    if (n0 + 3 >= NN) v.w = 0;
    vs[c] = v;
    s += v.x + v.y + v.z + v.w;
  }
  ls[t] = s; __syncthreads();
  for (int off = 1; off < SCAN_T; off <<= 1){
    int v = ls[t];
    int add = (t >= off) ? ls[t - off] : 0;
    __syncthreads();
    ls[t] = v + add;
    __syncthreads();
  }
  int run = (t > 0) ? ls[t - 1] : 0;
#pragma unroll
  for (int c = 0; c < 13; ++c){
    int vv[4] = {vs[c].x, vs[c].y, vs[c].z, vs[c].w};
#pragma unroll
    for (int j = 0; j < 4; ++j){
      int n = base + c * 4 + j;
      if (n < NN){ start[n] = run; cursor[n] = run; run += vv[j]; }
    }
  }
  if (t == SCAN_T - 1) start[NN] = run;
}

// packed record per CSR position: {eid, dst_node, src_node, 0}
__global__ void k_scatter(const int* __restrict__ dst, const int* __restrict__ src,
                          int* __restrict__ cursor, int4* __restrict__ pack){
  int e = blockIdx.x * 256 + threadIdx.x;
  if (e < NE){
    int dn = dst[e];
    int p = atomicAdd(&cursor[dn], 1);
    int4 rec; rec.x = e; rec.y = dn; rec.z = src[e]; rec.w = 0;
    pack[p] = rec;
  }
}

// ---------- K1: node QKV — MFMA, split-bf16 A ----------
__global__ __launch_bounds__(256) void k1_qkv(const float* __restrict__ x,
    const bf16u* __restrict__ BpQ, const float* __restrict__ qkv_b,
    float* __restrict__ Q, float* __restrict__ K, float* __restrict__ V){
  int tile = blockIdx.x * 64;
  int w = threadIdx.x >> 6, l = threadIdx.x & 63;
  int lg = l >> 4, li = l & 15;
  const short8v* bpq = (const short8v*)BpQ;
  short8v Bq[3][2];
#pragma unroll
  for (int p = 0; p < 3; ++p)
#pragma unroll
    for (int ks = 0; ks < 2; ++ks)
      Bq[p][ks] = bpq[(ks * 12 + p * 4 + w) * 64 + l];
  f32x4 z = {0.f, 0.f, 0.f, 0.f};
  f32x4 acc[3][4];
#pragma unroll
  for (int p = 0; p < 3; ++p)
#pragma unroll
    for (int mf = 0; mf < 4; ++mf) acc[p][mf] = z;
#pragma unroll
  for (int mf = 0; mf < 4; ++mf){
    int row = tile + mf * 16 + li;
    bool g = row < NN;
    const float* xp = x + (size_t)row * 64 + lg * 8;
#pragma unroll
    for (int ks = 0; ks < 2; ++ks){
      float v[8];
      if (g){
        float4 t0 = *(const float4*)(xp + ks * 32);
        float4 t1 = *(const float4*)(xp + ks * 32 + 4);
        v[0]=t0.x; v[1]=t0.y; v[2]=t0.z; v[3]=t0.w;
        v[4]=t1.x; v[5]=t1.y; v[6]=t1.z; v[7]=t1.w;
      } else {
#pragma unroll
        for (int j = 0; j < 8; ++j) v[j] = 0.f;
      }
      short8v hi, lo;
#pragma unroll
      for (int j = 0; j < 8; ++j){
        bf16u h = f2bf(v[j]);
        hi[j] = (short)h;
        lo[j] = (short)f2bf(v[j] - bf2f(h));
      }
#pragma unroll
      for (int p = 0; p < 3; ++p){
        acc[p][mf] = __builtin_amdgcn_mfma_f32_16x16x32_bf16(hi, Bq[p][ks], acc[p][mf], 0, 0, 0);
        acc[p][mf] = __builtin_amdgcn_mfma_f32_16x16x32_bf16(lo, Bq[p][ks], acc[p][mf], 0, 0, 0);
      }
    }
  }
  float bias[3] = {qkv_b[w*16+li], qkv_b[64+w*16+li], qkv_b[128+w*16+li]};
  float* outs[3] = {Q, K, V};
#pragma unroll
  for (int p = 0; p < 3; ++p)
#pragma unroll
    for (int mf = 0; mf < 4; ++mf)
#pragma unroll
      for (int r = 0; r < 4; ++r){
        int row = tile + mf * 16 + lg * 4 + r;
        if (row < NN) outs[p][(size_t)row * 64 + w * 16 + li] = acc[p][mf][r] + bias[p];
      }
}

// ---------- K2: fused edge kernel — wave-autonomous, split-bf16 cp ----------
__global__ __launch_bounds__(256, 5) void k2_edge(
    const float* __restrict__ e, const int4* __restrict__ pack,
    const bf16u* __restrict__ BpE, const float* __restrict__ E_b,
    const bf16u* __restrict__ BpA, const bf16u* __restrict__ Bp1, const float* __restrict__ conn1_b,
    const float* __restrict__ Q, const float* __restrict__ K,
    const float* __restrict__ g1c, const float* __restrict__ b1c,
    const bf16u* __restrict__ Bp2, const float* __restrict__ conn2_b,
    const float* __restrict__ g2c, const float* __restrict__ b2c,
    bf16u* __restrict__ cm, float* __restrict__ sexp, float* __restrict__ out_conn){
  __shared__ bf16u ldsT[4 * 16 * 72];     // per-wave 16x72 bf16 hi buffer
  __shared__ bf16u ldsTlo[4 * 16 * 72];   // per-wave 16x72 bf16 lo-residual buffer
  int t = threadIdx.x;
  int w = t >> 6, l = t & 63;
  int lg = l >> 4, li = l & 15;
  int pos0 = blockIdx.x * 64 + w * 16;
  bf16u* T   = &ldsT[w * (16 * 72)];
  bf16u* Tlo = &ldsTlo[w * (16 * 72)];
  f32x4 z = {0.f, 0.f, 0.f, 0.f};

  // --- phase A: Eh MFMA (16 edges x 128 outs, this wave) ---
  short8v afr[2];
  {
    int eidA = pack[pos0 + li].x;
    const float* ep = e + (size_t)eidA * 64 + lg * 8;
#pragma unroll
    for (int ks = 0; ks < 2; ++ks){
      float4 a0 = *(const float4*)(ep + ks * 32);
      float4 a1 = *(const float4*)(ep + ks * 32 + 4);
      short8v af;
      af[0]=(short)f2bf(a0.x); af[1]=(short)f2bf(a0.y); af[2]=(short)f2bf(a0.z); af[3]=(short)f2bf(a0.w);
      af[4]=(short)f2bf(a1.x); af[5]=(short)f2bf(a1.y); af[6]=(short)f2bf(a1.z); af[7]=(short)f2bf(a1.w);
      afr[ks] = af;
    }
  }
  f32x4 accW[4], accB[4];
#pragma unroll
  for (int nf = 0; nf < 4; ++nf){ accW[nf] = z; accB[nf] = z; }
  {
    const short8v* bpe = (const short8v*)BpE;
#pragma unroll
    for (int ks = 0; ks < 2; ++ks){
#pragma unroll
      for (int nf = 0; nf < 4; ++nf){
        short8v BW = bpe[(ks * 8 + nf) * 64 + l];
        short8v BB = bpe[(ks * 8 + 4 + nf) * 64 + l];
        accW[nf] = __builtin_amdgcn_mfma_f32_16x16x32_bf16(afr[ks], BW, accW[nf], 0, 0, 0);
        accB[nf] = __builtin_amdgcn_mfma_f32_16x16x32_bf16(afr[ks], BB, accB[nf], 0, 0, 0);
      }
    }
  }

  // --- pointwise: conn_pre (D-layout: row=lg*4+r, col=nf*16+li) ---
  int dnv[4], snv[4], eidv[4];
#pragma unroll
  for (int r = 0; r < 4; ++r){
    int4 rec = pack[pos0 + lg * 4 + r];
    eidv[r] = rec.x; dnv[r] = rec.y; snv[r] = rec.z;
  }
  float cp[4][4];
#pragma unroll
  for (int nf = 0; nf < 4; ++nf){
    int dim = nf * 16 + li;
    float eb0 = E_b[dim], eb1 = E_b[64 + dim];
#pragma unroll
    for (int r = 0; r < 4; ++r){
      float qv = Q[(size_t)dnv[r] * 64 + dim];
      float kv = K[(size_t)snv[r] * 64 + dim];
      float ew  = accW[nf][r] + eb0;
      float ebv = accB[nf][r] + eb1;
      float c1 = (qv + kv) * ew;
      float c2 = copysignf(sqrtf(fabsf(c1)), c1);
      cp[nf][r] = fmaxf(c2 + ebv, 0.f);
    }
  }

  // --- transpose #1: cp D-layout -> LDS hi+lo -> A-frags ---
#pragma unroll
  for (int nf = 0; nf < 4; ++nf)
#pragma unroll
    for (int r = 0; r < 4; ++r){
      int idx = (lg * 4 + r) * 72 + nf * 16 + li;
      bf16u hb = f2bf(cp[nf][r]);
      T[idx] = hb;
      Tlo[idx] = f2bf(cp[nf][r] - bf2f(hb));
    }
  __builtin_amdgcn_wave_barrier();
  short8v a1f[2], a1lo[2];
  a1f[0]  = *(const short8v*)&T[li * 72 + 0 * 32 + lg * 8];
  a1f[1]  = *(const short8v*)&T[li * 72 + 1 * 32 + lg * 8];
  a1lo[0] = *(const short8v*)&Tlo[li * 72 + 0 * 32 + lg * 8];
  a1lo[1] = *(const short8v*)&Tlo[li * 72 + 1 * 32 + lg * 8];

  // --- score MFMA (hi+lo) + exp + store ---
  {
    const short8v* bpa = (const short8v*)BpA;
    f32x4 sacc = z;
    sacc = __builtin_amdgcn_mfma_f32_16x16x32_bf16(a1f[0],  bpa[0 * 64 + l], sacc, 0, 0, 0);
    sacc = __builtin_amdgcn_mfma_f32_16x16x32_bf16(a1lo[0], bpa[0 * 64 + l], sacc, 0, 0, 0);
    sacc = __builtin_amdgcn_mfma_f32_16x16x32_bf16(a1f[1],  bpa[1 * 64 + l], sacc, 0, 0, 0);
    sacc = __builtin_amdgcn_mfma_f32_16x16x32_bf16(a1lo[1], bpa[1 * 64 + l], sacc, 0, 0, 0);
    if (li < 4){
#pragma unroll
      for (int r = 0; r < 4; ++r){
        float sc = fminf(fmaxf(sacc[r], -5.f), 5.f);
        sexp[(size_t)(pos0 + lg * 4 + r) * 4 + li] = __expf(sc);
      }
    }
  }

  // --- conn1 MFMA (hi+lo) -> cmv (D-layout, near-f32) ---
  float cmv[4][4];
  {
    const short8v* bp1 = (const short8v*)Bp1;
#pragma unroll
    for (int nf = 0; nf < 4; ++nf){
      f32x4 acc = z;
      acc = __builtin_amdgcn_mfma_f32_16x16x32_bf16(a1f[0],  bp1[(0 * 4 + nf) * 64 + l], acc, 0, 0, 0);
      acc = __builtin_amdgcn_mfma_f32_16x16x32_bf16(a1lo[0], bp1[(0 * 4 + nf) * 64 + l], acc, 0, 0, 0);
      acc = __builtin_amdgcn_mfma_f32_16x16x32_bf16(a1f[1],  bp1[(1 * 4 + nf) * 64 + l], acc, 0, 0, 0);
      acc = __builtin_amdgcn_mfma_f32_16x16x32_bf16(a1lo[1], bp1[(1 * 4 + nf) * 64 + l], acc, 0, 0, 0);
      float c1b = conn1_b[nf * 16 + li];
#pragma unroll
      for (int r = 0; r < 4; ++r){
        float v = acc[r] + c1b;
        cmv[nf][r] = v;
        cm[(size_t)(pos0 + lg * 4 + r) * 64 + nf * 16 + li] = f2bf(v);
      }
    }
  }

  // --- LN1c stats (wave-local) ---
  float mu1r[4], rs1r[4];
#pragma unroll
  for (int r = 0; r < 4; ++r){
    float s = cmv[0][r] + cmv[1][r] + cmv[2][r] + cmv[3][r];
    float q = cmv[0][r]*cmv[0][r] + cmv[1][r]*cmv[1][r] + cmv[2][r]*cmv[2][r] + cmv[3][r]*cmv[3][r];
    s += __shfl_xor(s, 1); s += __shfl_xor(s, 2); s += __shfl_xor(s, 4); s += __shfl_xor(s, 8);
    q += __shfl_xor(q, 1); q += __shfl_xor(q, 2); q += __shfl_xor(q, 4); q += __shfl_xor(q, 8);
    float mu = s * (1.f / 64.f);
    float var = q * (1.f / 64.f) - mu * mu;
    mu1r[r] = mu;
    rs1r[r] = rsqrtf(fmaxf(var, 0.f) + 1e-5f);
  }

  // --- LN1c normalize + relu -> transpose #2 (reuse T) ---
  __builtin_amdgcn_wave_barrier();
#pragma unroll
  for (int nf = 0; nf < 4; ++nf){
    int dim = nf * 16 + li;
    float g1v = g1c[dim], b1v = b1c[dim];
#pragma unroll
    for (int r = 0; r < 4; ++r){
      float cn = fmaxf((cmv[nf][r] - mu1r[r]) * rs1r[r] * g1v + b1v, 0.f);
      T[(lg * 4 + r) * 72 + dim] = f2bf(cn);
    }
  }
  __builtin_amdgcn_wave_barrier();
  short8v a2f[2];
  a2f[0] = *(const short8v*)&T[li * 72 + 0 * 32 + lg * 8];
  a2f[1] = *(const short8v*)&T[li * 72 + 1 * 32 + lg * 8];

  // --- conn2 MFMA + residual -> rv (f32 regs) ---
  float rv[4][4];
  {
    const short8v* bp2 = (const short8v*)Bp2;
#pragma unroll
    for (int nf = 0; nf < 4; ++nf){
      f32x4 acc = z;
      acc = __builtin_amdgcn_mfma_f32_16x16x32_bf16(a2f[0], bp2[(0 * 4 + nf) * 64 + l], acc, 0, 0, 0);
      acc = __builtin_amdgcn_mfma_f32_16x16x32_bf16(a2f[1], bp2[(1 * 4 + nf) * 64 + l], acc, 0, 0, 0);
      int dim = nf * 16 + li;
      float c2b = conn2_b[dim];
#pragma unroll
      for (int r = 0; r < 4; ++r)
        rv[nf][r] = acc[r] + c2b + e[(size_t)eidv[r] * 64 + dim];
    }
  }

  // --- LN2c stats (wave-local) + store out_conn ---
#pragma unroll
  for (int r = 0; r < 4; ++r){
    float s = rv[0][r] + rv[1][r] + rv[2][r] + rv[3][r];
    float q = rv[0][r]*rv[0][r] + rv[1][r]*rv[1][r] + rv[2][r]*rv[2][r] + rv[3][r]*rv[3][r];
    s += __shfl_xor(s, 1); s += __shfl_xor(s, 2); s += __shfl_xor(s, 4); s += __shfl_xor(s, 8);
    q += __shfl_xor(q, 1); q += __shfl_xor(q, 2); q += __shfl_xor(q, 4); q += __shfl_xor(q, 8);
    float mu = s * (1.f / 64.f);
    float var = q * (1.f / 64.f) - mu * mu;
    float rs = rsqrtf(fmaxf(var, 0.f) + 1e-5f);
#pragma unroll
    for (int nf = 0; nf < 4; ++nf){
      int dim = nf * 16 + li;
      out_conn[(size_t)eidv[r] * 64 + dim] = (rv[nf][r] - mu) * rs * g2c[dim] + b2c[dim];
    }
  }
}

// ---------- K_agg: wave per node; 2-way ILP over edge list ----------
__global__ __launch_bounds__(256) void k_agg(
    const int* __restrict__ start, const int4* __restrict__ pack,
    const float* __restrict__ sexp, const bf16u* __restrict__ cm, const float* __restrict__ V,
    const float* __restrict__ x, float* __restrict__ hpre){
  int wid = (blockIdx.x * 256 + threadIdx.x) >> 6;
  int lane = threadIdx.x & 63;
  if (wid >= NN) return;
  int s0 = start[wid], s1 = start[wid + 1];
  int h = lane >> 4;
  float num0 = 0.f, den0 = 0.f, num1 = 0.f, den1 = 0.f;
  int i = s0;
  for (; i + 1 < s1; i += 2){
    float sxa = sexp[(size_t)i * 4 + h];
    float sxb = sexp[(size_t)(i + 1) * 4 + h];
    int sna = pack[i].z, snb = pack[i + 1].z;
    float va = V[(size_t)sna * 64 + lane];
    float vb = V[(size_t)snb * 64 + lane];
    float ca = bf2f(cm[(size_t)i * 64 + lane]);
    float cb = bf2f(cm[(size_t)(i + 1) * 64 + lane]);
    num0 += sxa * (va + ca); den0 += sxa;
    num1 += sxb * (vb + cb); den1 += sxb;
  }
  if (i < s1){
    float sx = sexp[(size_t)i * 4 + h];
    int sn = pack[i].z;
    float v  = V[(size_t)sn * 64 + lane];
    float cc = bf2f(cm[(size_t)i * 64 + lane]);
    num0 += sx * (v + cc); den0 += sx;
  }
  float num = num0 + num1, den = den0 + den1;
  hpre[(size_t)wid * 64 + lane] = x[(size_t)wid * 64 + lane] + num / (den + 1e-16f);
}

// ---------- K5: node final — LN1h + FFN (MFMA) + LN2h ----------
__global__ __launch_bounds__(256) void k5_node(
    const float* __restrict__ hpre,
    const float* __restrict__ g1, const float* __restrict__ b1,
    const bf16u* __restrict__ BpF1, const float* __restrict__ ffn1_b,
    const bf16u* __restrict__ BpF2, const float* __restrict__ ffn2_b,
    const float* __restrict__ g2, const float* __restrict__ b2,
    float* __restrict__ out_h){
  __shared__ bf16u hlhi[64 * 72];
  __shared__ bf16u hllo[64 * 72];
  __shared__ bf16u g1o[64 * 136];
  __shared__ float reds[64][4];
  __shared__ float redq[64][4];
  int tile = blockIdx.x * 64;
  int t = threadIdx.x;
  {
    int el = t >> 2, q = t & 3;
    int row = tile + el;
    bool g = row < NN;
    float v[16];
    if (g){
      const float4* hp = (const float4*)(hpre + (size_t)row * 64 + q * 16);
#pragma unroll
      for (int c = 0; c < 4; ++c){
        float4 tv = hp[c];
        v[c*4+0]=tv.x; v[c*4+1]=tv.y; v[c*4+2]=tv.z; v[c*4+3]=tv.w;
      }
    } else {
#pragma unroll
      for (int i = 0; i < 16; ++i) v[i] = 0.f;
    }
    float s = 0.f, sq = 0.f;
#pragma unroll
    for (int i = 0; i < 16; ++i){ s += v[i]; sq += v[i]*v[i]; }
    s  += __shfl_xor(s, 1);  s  += __shfl_xor(s, 2);
    sq += __shfl_xor(sq, 1); sq += __shfl_xor(sq, 2);
    float mu = s * (1.f/64.f);
    float var = sq * (1.f/64.f) - mu * mu;
    float rs = rsqrtf(fmaxf(var, 0.f) + 1e-5f);
#pragma unroll
    for (int i = 0; i < 16; ++i){
      int d = q * 16 + i;
      float hv = (v[i] - mu) * rs * g1[d] + b1[d];
      bf16u hb = f2bf(hv);
      hlhi[el * 72 + d] = hb;
      hllo[el * 72 + d] = f2bf(hv - bf2f(hb));
    }
  }
  __syncthreads();
  int w = t >> 6, l = t & 63;
  int lg = l >> 4, li = l & 15;
  const short8v* bpf1 = (const short8v*)BpF1;
  short8v B1f[2][2];
#pragma unroll
  for (int f = 0; f < 2; ++f)
#pragma unroll
    for (int ks = 0; ks < 2; ++ks)
      B1f[f][ks] = bpf1[(ks * 8 + f * 4 + w) * 64 + l];
  f32x4 z = {0.f, 0.f, 0.f, 0.f};
  f32x4 acc1[2][4];
#pragma unroll
  for (int f = 0; f < 2; ++f)
#pragma unroll
    for (int mf = 0; mf < 4; ++mf) acc1[f][mf] = z;
#pragma unroll
  for (int mf = 0; mf < 4; ++mf){
#pragma unroll
    for (int ks = 0; ks < 2; ++ks){
      const bf16u* ah = &hlhi[(mf * 16 + li) * 72 + ks * 32 + lg * 8];
      const bf16u* al = &hllo[(mf * 16 + li) * 72 + ks * 32 + lg * 8];
      short8v Ahi = *(const short8v*)ah;
      short8v Alo = *(const short8v*)al;
#pragma unroll
      for (int f = 0; f < 2; ++f){
        acc1[f][mf] = __builtin_amdgcn_mfma_f32_16x16x32_bf16(Ahi, B1f[f][ks], acc1[f][mf], 0, 0, 0);
        acc1[f][mf] = __builtin_amdgcn_mfma_f32_16x16x32_bf16(Alo, B1f[f][ks], acc1[f][mf], 0, 0, 0);
      }
    }
  }
  float fb[2] = {ffn1_b[w*16+li], ffn1_b[64+w*16+li]};
#pragma unroll
  for (int f = 0; f < 2; ++f)
#pragma unroll
    for (int mf = 0; mf < 4; ++mf)
#pragma unroll
      for (int r = 0; r < 4; ++r){
        int rowl = mf * 16 + lg * 4 + r;
        int col = f * 64 + w * 16 + li;
        g1o[rowl * 136 + col] = f2bf(fmaxf(acc1[f][mf][r] + fb[f], 0.f));
      }
  __syncthreads();
  const short8v* bpf2 = (const short8v*)BpF2;
  short8v B2f[4];
#pragma unroll
  for (int ks = 0; ks < 4; ++ks) B2f[ks] = bpf2[(ks * 4 + w) * 64 + l];
  int o = w * 16 + li;
  float f2b_ = ffn2_b[o];
  float racc[4][4];
#pragma unroll
  for (int mf = 0; mf < 4; ++mf){
    f32x4 acc = z;
#pragma unroll
    for (int ks = 0; ks < 4; ++ks){
      short8v A2 = *(const short8v*)&g1o[(mf * 16 + li) * 136 + ks * 32 + lg * 8];
      acc = __builtin_amdgcn_mfma_f32_16x16x32_bf16(A2, B2f[ks], acc, 0, 0, 0);
    }
#pragma unroll
    for (int r = 0; r < 4; ++r){
      int rowl = mf * 16 + lg * 4 + r;
      int row = tile + rowl;
      float hres = (row < NN) ? hpre[(size_t)row * 64 + o] : 0.f;
      float rvv = acc[r] + f2b_ + hres;
      racc[mf][r] = rvv;
      float s = rvv, q2 = rvv * rvv;
      s  += __shfl_xor(s, 1);  s  += __shfl_xor(s, 2);  s  += __shfl_xor(s, 4);  s  += __shfl_xor(s, 8);
      q2 += __shfl_xor(q2, 1); q2 += __shfl_xor(q2, 2); q2 += __shfl_xor(q2, 4); q2 += __shfl_xor(q2, 8);
      if (li == 0){ reds[rowl][w] = s; redq[rowl][w] = q2; }
    }
  }
  __syncthreads();
  float g2v = g2[o], b2v = b2[o];
#pragma unroll
  for (int mf = 0; mf < 4; ++mf){
#pragma unroll
    for (int r = 0; r < 4; ++r){
      int rowl = mf * 16 + lg * 4 + r;
      int row = tile + rowl;
      if (row < NN){
        float S  = reds[rowl][0] + reds[rowl][1] + reds[rowl][2] + reds[rowl][3];
        float Qq = redq[rowl][0] + redq[rowl][1] + redq[rowl][2] + redq[rowl][3];
        float mu2 = S * (1.f/64.f);
        float var2 = Qq * (1.f/64.f) - mu2 * mu2;
        float rs2 = rsqrtf(fmaxf(var2, 0.f) + 1e-5f);
        out_h[(size_t)row * 64 + o] = (racc[mf][r] - mu2) * rs2 * g2v + b2v;
      }
    }
  }
}

extern "C" void kernel_launch(void* const* d_in, const int* in_sizes, int n_in,
                              void* d_out, int out_size, void* d_ws, size_t ws_size,
                              hipStream_t stream){
  const float* x       = (const float*)d_in[0];
  const float* e       = (const float*)d_in[1];
  const int*   dst     = (const int*)d_in[2];
  const int*   src     = (const int*)d_in[3];
  const float* qkv_w   = (const float*)d_in[4];
  const float* qkv_b   = (const float*)d_in[5];
  const float* E_w     = (const float*)d_in[6];
  const float* E_b     = (const float*)d_in[7];
  const float* Aw      = (const float*)d_in[8];
  const float* conn1_w = (const float*)d_in[9];
  const float* conn1_b = (const float*)d_in[10];
  const float* conn2_w = (const float*)d_in[11];
  const float* conn2_b = (const float*)d_in[12];
  const float* ffn1_w  = (const float*)d_in[13];
  const float* ffn1_b  = (const float*)d_in[14];
  const float* ffn2_w  = (const float*)d_in[15];
  const float* ffn2_b  = (const float*)d_in[16];
  const float* ln1h_g  = (const float*)d_in[17];
  const float* ln1h_b  = (const float*)d_in[18];
  const float* ln2h_g  = (const float*)d_in[19];
  const float* ln2h_b  = (const float*)d_in[20];
  const float* ln1c_g  = (const float*)d_in[21];
  const float* ln1c_b  = (const float*)d_in[22];
  const float* ln2c_g  = (const float*)d_in[23];
  const float* ln2c_b  = (const float*)d_in[24];

  char* ws = (char*)d_ws;
  size_t off = 0;
  auto alloc = [&](size_t bytes) -> void* {
    void* p = ws + off;
    off += (bytes + 255) & ~(size_t)255;
    return p;
  };
  float* Q     = (float*)alloc((size_t)NN * 64 * 4);
  float* Kq    = (float*)alloc((size_t)NN * 64 * 4);
  float* V     = (float*)alloc((size_t)NN * 64 * 4);
  bf16u* cmb   = (bf16u*)alloc((size_t)NE * 64 * 2);
  float* sexp  = (float*)alloc((size_t)NE * 4 * 4);
  float* hpre  = (float*)alloc((size_t)NN * 64 * 4);
  bf16u* BpE   = (bf16u*)alloc(8192 * 2);
  bf16u* Bp1   = (bf16u*)alloc(4096 * 2);
  bf16u* Bp2   = (bf16u*)alloc(4096 * 2);
  bf16u* BpQ   = (bf16u*)alloc(12288 * 2);
  bf16u* BpF1  = (bf16u*)alloc(8192 * 2);
  bf16u* BpF2  = (bf16u*)alloc(8192 * 2);
  bf16u* BpA   = (bf16u*)alloc(1024 * 2);
  int*   cnt   = (int*)alloc((size_t)NN * 4);
  int*   startp= (int*)alloc(((size_t)NN + 1) * 4);
  int*   cursor= (int*)alloc((size_t)NN * 4);
  int4*  pack  = (int4*)alloc((size_t)NE * 16);

  float* out_h    = (float*)d_out;
  float* out_conn = out_h + (size_t)NN * 64;

  hipMemsetAsync(cnt, 0, (size_t)NN * 4, stream);

  k0_pack<<<48, 256, 0, stream>>>(E_w, conn1_w, conn2_w, qkv_w, ffn1_w, ffn2_w, Aw,
                                  BpE, Bp1, Bp2, BpQ, BpF1, BpF2, BpA);
  k_hist<<<NE / 256, 256, 0, stream>>>(dst, cnt);
  k_scan<<<1, SCAN_T, 0, stream>>>(cnt, startp, cursor);
  k_scatter<<<NE / 256, 256, 0, stream>>>(dst, src, cursor, pack);
  k1_qkv<<<(NN + 63) / 64, 256, 0, stream>>>(x, BpQ, qkv_b, Q, Kq, V);
  k2_edge<<<NE / 64, 256, 0, stream>>>(e, pack, BpE, E_b, BpA, Bp1, conn1_b,
                                       Q, Kq, ln1c_g, ln1c_b, Bp2, conn2_b,
                                       ln2c_g, ln2c_b, cmb, sexp, out_conn);
  k_agg<<<(NN * 64 + 255) / 256, 256, 0, stream>>>(startp, pack, sexp, cmb, V, x, hpre);
  k5_node<<<(NN + 63) / 64, 256, 0, stream>>>(hpre, ln1h_g, ln1h_b, BpF1, ffn1_b,
                                              BpF2, ffn2_b, ln2h_g, ln2h_b, out_h);
}